// Round 3
// baseline (739.975 us; speedup 1.0000x reference)
//
#include <hip/hip_runtime.h>
#include <hip/hip_bf16.h>
#include <math.h>

#define NROWS 8192
#define INDIM 768
#define TD    72
#define DM    24
#define MKEYS 8192
#define KSEL  32
#define HN    256
#define K3CAND 128

#define TWO_PI_F 6.283185307179586f

__device__ __forceinline__ float gelu_exact(float v){
  return 0.5f * v * (1.0f + erff(v * 0.7071067811865476f));
}

// async global->LDS (gfx950): LDS dest = uniform base + lane*size, global src per-lane
__device__ __forceinline__ void gl_lds16(const float* g, float* l) {
  __builtin_amdgcn_global_load_lds((const __attribute__((address_space(1))) unsigned int*)g,
                                   (__attribute__((address_space(3))) unsigned int*)l, 16, 0, 0);
}
__device__ __forceinline__ void gl_lds4(const float* g, float* l) {
  __builtin_amdgcn_global_load_lds((const __attribute__((address_space(1))) unsigned int*)g,
                                   (__attribute__((address_space(3))) unsigned int*)l, 4, 0, 0);
}

// ---------------------------------------------------------------------------
// K1: y = x@W_in.T + b_in ; LN(72); GELU; ricci einsum + mean over 3 -> q(24)
// ---------------------------------------------------------------------------
__global__ __launch_bounds__(256) void k1_encode(
    const float* __restrict__ x, const float* __restrict__ Wi,
    const float* __restrict__ bi, const float* __restrict__ gi,
    const float* __restrict__ bbi, const float* __restrict__ ricci,
    float* __restrict__ qvec, float* __restrict__ qnorm)
{
  __shared__ float xs[16][132];
  __shared__ float Ws[TD][132];
  __shared__ float zs[16][73];
  __shared__ float zb[16][25];
  const int t = threadIdx.x;
  const int r2 = t >> 4, ks = (t >> 3) & 1, u = t & 7;
  const int row0 = blockIdx.x * 16;

  float acc[9];
#pragma unroll
  for (int j = 0; j < 9; j++) acc[j] = 0.f;

  for (int kc = 0; kc < 6; kc++) {
    __syncthreads();
#pragma unroll
    for (int i = 0; i < 2; i++) {
      int idx = t + 256 * i;
      int rr = idx >> 5, kk = (idx & 31) << 2;
      *(float4*)&xs[rr][kk] = *(const float4*)&x[(size_t)(row0 + rr) * INDIM + kc * 128 + kk];
    }
#pragma unroll
    for (int i = 0; i < 9; i++) {
      int idx = t + 256 * i;
      int rr = idx >> 5, kk = (idx & 31) << 2;
      *(float4*)&Ws[rr][kk] = *(const float4*)&Wi[(size_t)rr * INDIM + kc * 128 + kk];
    }
    __syncthreads();
    const int kb = ks * 64;
#pragma unroll 4
    for (int kq = 0; kq < 16; kq++) {
      const float4 xv = *(const float4*)&xs[r2][kb + kq * 4];
#pragma unroll
      for (int j = 0; j < 9; j++) {
        const float4 wv = *(const float4*)&Ws[u + 8 * j][kb + kq * 4];
        acc[j] = fmaf(xv.x, wv.x, fmaf(xv.y, wv.y, fmaf(xv.z, wv.z, fmaf(xv.w, wv.w, acc[j]))));
      }
    }
  }
#pragma unroll
  for (int j = 0; j < 9; j++) acc[j] += __shfl_xor(acc[j], 8);

  float yv[9];
  float ps = 0.f, pq = 0.f;
#pragma unroll
  for (int j = 0; j < 9; j++) {
    const int o = u + 8 * j;
    yv[j] = acc[j] + bi[o];
    ps += yv[j]; pq += yv[j] * yv[j];
  }
#pragma unroll
  for (int m = 1; m < 8; m <<= 1) { ps += __shfl_xor(ps, m); pq += __shfl_xor(pq, m); }
  const float mean = ps * (1.f / 72.f);
  const float var  = pq * (1.f / 72.f) - mean * mean;
  const float rstd = rsqrtf(var + 1e-5f);
#pragma unroll
  for (int j = 0; j < 9; j++) {
    const int o = u + 8 * j;
    const float z = gelu_exact((yv[j] - mean) * rstd * gi[o] + bbi[o]);
    if (ks == 0) zs[r2][o] = z;
  }
  __syncthreads();
  {
    const int kt = t & 15;
    for (int e = kt; e < 24; e += 16)
      zb[r2][e] = (zs[r2][3 * e] + zs[r2][3 * e + 1] + zs[r2][3 * e + 2]) * (1.f / 3.f);
  }
  __syncthreads();
  {
    const int kt = t & 15;
    float qnp = 0.f;
    for (int d = kt; d < 24; d += 16) {
      float qd = 0.f;
#pragma unroll
      for (int e = 0; e < 24; e++) qd = fmaf(zb[r2][e], ricci[e * 24 + d], qd);
      qvec[(size_t)(row0 + r2) * DM + d] = qd;
      qnp = fmaf(qd, qd, qnp);
    }
#pragma unroll
    for (int m = 1; m < 16; m <<= 1) qnp += __shfl_xor(qnp, m, 16);
    if (kt == 0) qnorm[row0 + r2] = qnp;
  }
}

// ---------------------------------------------------------------------------
// K2: key norms + quantum-phase means
// ---------------------------------------------------------------------------
__global__ __launch_bounds__(256) void k2_prep(
    const float* __restrict__ keys, const float* __restrict__ qp,
    float* __restrict__ kn, float* __restrict__ pm)
{
  const int m = blockIdx.x * 256 + threadIdx.x;
  float s = 0.f;
#pragma unroll
  for (int d = 0; d < DM; d++) { const float v = keys[(size_t)m * DM + d]; s = fmaf(v, v, s); }
  kn[m] = s;
  float p = 0.f;
#pragma unroll
  for (int q = 0; q < 8; q++) p += tanhf(qp[(size_t)m * 8 + q]);
  pm[m] = p * 0.125f;
}

// ---------------------------------------------------------------------------
// K3 v3: distances + exact top-32 + softmax + gain.
// 256 thr / 32 rows per block (8 rows per wave), grid 256 (1 block/CU).
// Keys staged CHUNK-MAJOR float4 in LDS: slot [i][k] = float4 #i of key k,
// so ds_read_b128 across lanes is contiguous (conflict-free). Staged via
// global_load_lds with per-lane pre-swizzled GLOBAL addresses, linear LDS
// dest (m173 pattern). Double-buffered, counted vmcnt(7).
// Same arithmetic chain as round-1 (identical d2 -> identical top-32 set).
// ---------------------------------------------------------------------------
__global__ __launch_bounds__(256, 1) void k3_topk(
    const float* __restrict__ qvec, const float* __restrict__ qnorm,
    const float* __restrict__ keys, const float* __restrict__ kn,
    const float* __restrict__ fw,  const float* __restrict__ pm,
    float* __restrict__ w_out, int* __restrict__ itop_out, float* __restrict__ gain_out)
{
  __shared__ __align__(16) float ks[2][256 * 24];   // 48 KB, chunk-major float4
  __shared__ float knch[2][256];                    // 2 KB
  __shared__ float qsm[32][24];
  __shared__ float qnsm[32];
  __shared__ float gmins[64][33];                   // [group][row]
  __shared__ float Ts[32];
  __shared__ unsigned flg[2][32];                   // [word][row] live-group bits
  __shared__ unsigned candV[32][K3CAND];
  __shared__ int      candI[32][K3CAND];
  __shared__ int cnt[32];
  __shared__ float wV[32][KSEL];
  __shared__ int   wI[32][KSEL];

  const int t = threadIdx.x;
  const int wv = t >> 6, lane = t & 63;
  const int row0 = blockIdx.x * 32;
  const int wv8 = wv * 8;

  // stage chunk c_ (256 keys) into buffer b_, chunk-major:
  // float4 slot s = j*64+lane holds float4 #(s>>8) of key (s&255).
#define K3_STAGE(c_, b_) do {                                                  \
    _Pragma("unroll")                                                          \
    for (int i_ = 0; i_ < 6; i_++) {                                           \
      const int s_ = (wv * 6 + i_) * 64 + lane;                                \
      const int k_ = s_ & 255, ch_ = s_ >> 8;                                  \
      gl_lds16(keys + ((size_t)(c_) * 256 + k_) * 24 + ch_ * 4,                \
               &ks[b_][(wv * 6 + i_) * 256]);                                  \
    }                                                                          \
    gl_lds4(kn + (size_t)(c_) * 256 + wv * 64 + lane, &knch[b_][wv * 64]);     \
  } while (0)

  // one-time: q rows to LDS then regs; init cnt/flg
  for (int idx = t; idx < 32 * DM; idx += 256) qsm[idx / DM][idx % DM] = qvec[(size_t)row0 * DM + idx];
  if (t < 32) { qnsm[t] = qnorm[row0 + t]; cnt[t] = 0; }
  if (t < 64) ((unsigned*)flg)[t] = 0;
  K3_STAGE(0, 0);
  __syncthreads();

  float q[8][24];
  float qn[8];
#pragma unroll
  for (int r = 0; r < 8; r++) {
    qn[r] = qnsm[wv8 + r];
#pragma unroll
    for (int d = 0; d < DM; d++) q[r][d] = qsm[wv8 + r][d];
  }

  // ---------------- pass A: group minima ----------------
  for (int c = 0; c < 32; c++) {
    const int buf = c & 1;
    if (c < 31) {
      K3_STAGE(c + 1, buf ^ 1);
      asm volatile("s_waitcnt vmcnt(7)" ::: "memory");
    } else {
      asm volatile("s_waitcnt vmcnt(0)" ::: "memory");
    }
    __syncthreads();
    const float4* kb4 = (const float4*)&ks[buf][0];
    const float* knb = &knch[buf][0];
    float mcur[8];
#pragma unroll
    for (int il = 0; il < 4; il++) {
      const int kk = lane + 64 * il;
      float kv[24];
      {
        const float4 a0 = kb4[0 * 256 + kk];
        const float4 a1 = kb4[1 * 256 + kk];
        const float4 a2 = kb4[2 * 256 + kk];
        const float4 a3 = kb4[3 * 256 + kk];
        const float4 a4 = kb4[4 * 256 + kk];
        const float4 a5 = kb4[5 * 256 + kk];
        kv[0]=a0.x; kv[1]=a0.y; kv[2]=a0.z; kv[3]=a0.w;
        kv[4]=a1.x; kv[5]=a1.y; kv[6]=a1.z; kv[7]=a1.w;
        kv[8]=a2.x; kv[9]=a2.y; kv[10]=a2.z; kv[11]=a2.w;
        kv[12]=a3.x; kv[13]=a3.y; kv[14]=a3.z; kv[15]=a3.w;
        kv[16]=a4.x; kv[17]=a4.y; kv[18]=a4.z; kv[19]=a4.w;
        kv[20]=a5.x; kv[21]=a5.y; kv[22]=a5.z; kv[23]=a5.w;
      }
      const float knn = knb[kk];
#pragma unroll
      for (int r = 0; r < 8; r++) {
        float dot = 0.f;
#pragma unroll
        for (int d = 0; d < DM; d++) dot = fmaf(kv[d], q[r][d], dot);
        const float d2 = fmaf(-2.f, dot, qn[r] + knn);
        if ((il & 1) == 0) mcur[r] = d2;
        else               mcur[r] = fminf(mcur[r], d2);
      }
      if (il & 1) {
        const int g = 2 * c + (il >> 1);
#pragma unroll
        for (int r = 0; r < 8; r++) {
          float gm = mcur[r];
#pragma unroll
          for (int m = 1; m < 64; m <<= 1) gm = fminf(gm, __shfl_xor(gm, m));
          if (lane == 0) gmins[g][wv8 + r] = gm;
        }
      }
    }
    __syncthreads();
  }

  // overlap: start staging chunk 0 for pass B while doing threshold work
  K3_STAGE(0, 0);

  // ---------------- threshold: 32nd smallest group-min per row ----------------
  float vloc[8];
  {
    const int r = t & 31, i = t >> 5;       // i in 0..7, each handles 8 groups
#pragma unroll
    for (int u = 0; u < 8; u++) vloc[u] = gmins[i * 8 + u][r];
    int rk[8], eq[8];
#pragma unroll
    for (int u = 0; u < 8; u++) { rk[u] = 0; eq[u] = 0; }
    for (int g = 0; g < 64; g++) {
      const float gv = gmins[g][r];
#pragma unroll
      for (int u = 0; u < 8; u++) { rk[u] += (gv < vloc[u]); eq[u] += (gv == vloc[u]); }
    }
#pragma unroll
    for (int u = 0; u < 8; u++)
      if (rk[u] <= 31 && rk[u] + eq[u] > 31) Ts[r] = vloc[u];
  }
  __syncthreads();
  {
    const int r = t & 31, i = t >> 5;
    const float T = Ts[r];
    const float Tm = T + fabsf(T) * 1e-6f + 1e-20f;
    unsigned bits = 0;
#pragma unroll
    for (int u = 0; u < 8; u++) bits |= (vloc[u] <= Tm) ? (1u << u) : 0u;
    atomicOr(&flg[i >> 2][r], bits << ((i & 3) * 8));
  }
  __syncthreads();

  float TmA[8];
#pragma unroll
  for (int r = 0; r < 8; r++) {
    const float T = Ts[wv8 + r];
    TmA[r] = T + fabsf(T) * 1e-6f + 1e-20f;
  }

  // ---------------- pass B: recompute live groups, compact candidates ----------------
  for (int c = 0; c < 32; c++) {
    const int buf = c & 1;
    if (c < 31) {
      K3_STAGE(c + 1, buf ^ 1);
      asm volatile("s_waitcnt vmcnt(7)" ::: "memory");
    } else {
      asm volatile("s_waitcnt vmcnt(0)" ::: "memory");
    }
    __syncthreads();
    const float4* kb4 = (const float4*)&ks[buf][0];
    const float* knb = &knch[buf][0];
    const int wc = c >> 4;
    unsigned fm[8];
#pragma unroll
    for (int r = 0; r < 8; r++) fm[r] = flg[wc][wv8 + r];
    unsigned anym = 0;
#pragma unroll
    for (int r = 0; r < 8; r++) anym |= fm[r];
#pragma unroll
    for (int il = 0; il < 4; il++) {
      const int g = 2 * c + (il >> 1);
      const unsigned gb = 1u << (g & 31);
      if (!(anym & gb)) continue;          // wave-uniform skip
      const int kk = lane + 64 * il;
      float kv[24];
      {
        const float4 a0 = kb4[0 * 256 + kk];
        const float4 a1 = kb4[1 * 256 + kk];
        const float4 a2 = kb4[2 * 256 + kk];
        const float4 a3 = kb4[3 * 256 + kk];
        const float4 a4 = kb4[4 * 256 + kk];
        const float4 a5 = kb4[5 * 256 + kk];
        kv[0]=a0.x; kv[1]=a0.y; kv[2]=a0.z; kv[3]=a0.w;
        kv[4]=a1.x; kv[5]=a1.y; kv[6]=a1.z; kv[7]=a1.w;
        kv[8]=a2.x; kv[9]=a2.y; kv[10]=a2.z; kv[11]=a2.w;
        kv[12]=a3.x; kv[13]=a3.y; kv[14]=a3.z; kv[15]=a3.w;
        kv[16]=a4.x; kv[17]=a4.y; kv[18]=a4.z; kv[19]=a4.w;
        kv[20]=a5.x; kv[21]=a5.y; kv[22]=a5.z; kv[23]=a5.w;
      }
      const float knn = knb[kk];
#pragma unroll
      for (int r = 0; r < 8; r++) {
        if (fm[r] & gb) {                  // wave-uniform per row
          float dot = 0.f;
#pragma unroll
          for (int d = 0; d < DM; d++) dot = fmaf(kv[d], q[r][d], dot);
          const float d2 = fmaf(-2.f, dot, qn[r] + knn);
          if (d2 <= TmA[r]) {
            const int pos = atomicAdd(&cnt[wv8 + r], 1);
            if (pos < K3CAND) {
              candV[wv8 + r][pos] = __float_as_uint(fmaxf(d2, 0.f));
              candI[wv8 + r][pos] = c * 256 + kk;
            }
          }
        }
      }
    }
    __syncthreads();
  }

  for (int idx = t; idx < 32 * KSEL; idx += 256) { wV[idx >> 5][idx & 31] = 1e30f; wI[idx >> 5][idx & 31] = 0; }
  __syncthreads();

  // ---------------- exact rank-select top-32 ----------------
  {
    const int r = t >> 3, kt = t & 7;      // 32 rows x 8 threads
    const int C = min(cnt[r], K3CAND);
    for (int ci = kt; ci < C; ci += 8) {
      const unsigned v = candV[r][ci];
      const unsigned key = (unsigned)candI[r][ci];
      int rk = 0;
      for (int j = 0; j < C; j++) {
        const unsigned vj = candV[r][j];
        rk += (vj < v) || (vj == v && (unsigned)candI[r][j] < key);
      }
      if (rk < KSEL) { wV[r][rk] = __uint_as_float(v); wI[r][rk] = (int)key; }
    }
  }
  __syncthreads();

  // ---------------- softmax over -dist, gain ----------------
  float sc;
  {
    const float f0 = fw[0], f1 = fw[1], f2 = fw[2], f3 = fw[3];
    const float mx = fmaxf(fmaxf(f0, f1), fmaxf(f2, f3));
    const float e0 = expf(f0 - mx), e1 = expf(f1 - mx), e2 = expf(f2 - mx), e3 = expf(f3 - mx);
    sc = (e0 + 0.5f * e1 + 0.25f * e2 + 0.125f * e3) / (e0 + e1 + e2 + e3);
  }
  {
    const int r = t >> 3, kt = t & 7;
    const float dA = sqrtf(wV[r][kt]) * sc;
    const float dB = sqrtf(wV[r][kt + 8]) * sc;
    const float dC = sqrtf(wV[r][kt + 16]) * sc;
    const float dD = sqrtf(wV[r][kt + 24]) * sc;
    float mn = fminf(fminf(dA, dB), fminf(dC, dD));
#pragma unroll
    for (int m = 1; m < 8; m <<= 1) mn = fminf(mn, __shfl_xor(mn, m, 8));
    const float eA = expf(mn - dA), eB = expf(mn - dB), eC = expf(mn - dC), eD = expf(mn - dD);
    float s = eA + eB + eC + eD;
#pragma unroll
    for (int m = 1; m < 8; m <<= 1) s += __shfl_xor(s, m, 8);
    const float w0 = eA / s, w1 = eB / s, w2 = eC / s, w3 = eD / s;
    const int k0 = wI[r][kt], k1 = wI[r][kt + 8], k2 = wI[r][kt + 16], k3 = wI[r][kt + 24];
    float gp = w0 * pm[k0] + w1 * pm[k1] + w2 * pm[k2] + w3 * pm[k3];
#pragma unroll
    for (int m = 1; m < 8; m <<= 1) gp += __shfl_xor(gp, m, 8);
    const size_t row = (size_t)(row0 + r);
    w_out[row * KSEL + kt] = w0;       w_out[row * KSEL + kt + 8] = w1;
    w_out[row * KSEL + kt + 16] = w2;  w_out[row * KSEL + kt + 24] = w3;
    itop_out[row * KSEL + kt] = k0;    itop_out[row * KSEL + kt + 8] = k1;
    itop_out[row * KSEL + kt + 16] = k2; itop_out[row * KSEL + kt + 24] = k3;
    if (kt == 0) gain_out[row] = 1.f + 0.02f * gp;
  }
#undef K3_STAGE
}

// ---------------------------------------------------------------------------
// K4: p = x@key_phase_W.T + b ; Kf = FFT(e^{i 2pi sigmoid(p)}) * e^{i ek}
// ---------------------------------------------------------------------------
__global__ __launch_bounds__(256) void k4_phase(
    const float* __restrict__ x, const float* __restrict__ Wp,
    const float* __restrict__ bp, const float* __restrict__ ek,
    float* __restrict__ kf_re, float* __restrict__ kf_im)
{
  __shared__ float xs[16][36];
  __shared__ float Ws[HN][36];
  __shared__ float sre[16][260];
  __shared__ float sim_[16][260];
  __shared__ float twc[HN], tws[HN];
  const int t = threadIdx.x;
  const int row0 = blockIdx.x * 16;
  {
    const float a = (float)t * (TWO_PI_F / 256.f);
    twc[t] = cosf(a); tws[t] = sinf(a);
  }
  const int r = t >> 4, cg = t & 15;
  float acc[16];
#pragma unroll
  for (int j = 0; j < 16; j++) acc[j] = bp[cg + 16 * j];

  for (int kc = 0; kc < 24; kc++) {
    __syncthreads();
    if (t < 128) {
      const int rr = t >> 3, kk = (t & 7) << 2;
      *(float4*)&xs[rr][kk] = *(const float4*)&x[(size_t)(row0 + rr) * INDIM + kc * 32 + kk];
    }
#pragma unroll
    for (int i = 0; i < 8; i++) {
      const int idx = t + 256 * i;
      const int rr = idx >> 3, kk = (idx & 7) << 2;
      *(float4*)&Ws[rr][kk] = *(const float4*)&Wp[(size_t)rr * INDIM + kc * 32 + kk];
    }
    __syncthreads();
#pragma unroll
    for (int kq = 0; kq < 8; kq++) {
      const float4 xv = *(const float4*)&xs[r][kq * 4];
#pragma unroll
      for (int j = 0; j < 16; j++) {
        const float4 wv = *(const float4*)&Ws[cg + 16 * j][kq * 4];
        acc[j] = fmaf(xv.x, wv.x, fmaf(xv.y, wv.y, fmaf(xv.z, wv.z, fmaf(xv.w, wv.w, acc[j]))));
      }
    }
  }
  __syncthreads();
#pragma unroll
  for (int j = 0; j < 16; j++) {
    const int c = cg + 16 * j;
    const float sg = 1.f / (1.f + expf(-acc[j]));
    float sn, cs;
    __sincosf(TWO_PI_F * sg, &sn, &cs);
    const int hb = __brev((unsigned)c) >> 24;
    sre[r][hb] = cs; sim_[r][hb] = sn;
  }
  __syncthreads();
  const int t16 = t & 15;
  for (int s = 0; s < 8; s++) {
    const int half = 1 << s;
#pragma unroll
    for (int p = 0; p < 8; p++) {
      const int bi = t16 + 16 * p;
      const int jj = bi & (half - 1);
      const int base = (bi >> s) << (s + 1);
      const int i0 = base + jj, i1 = i0 + half;
      const int tw = jj << (7 - s);
      const float wr = twc[tw], wi = -tws[tw];
      const float ar = sre[r][i0], ai = sim_[r][i0];
      const float br = sre[r][i1], b2 = sim_[r][i1];
      const float tr = wr * br - wi * b2, ti = wr * b2 + wi * br;
      sre[r][i0] = ar + tr; sim_[r][i0] = ai + ti;
      sre[r][i1] = ar - tr; sim_[r][i1] = ai - ti;
    }
    __syncthreads();
  }
#pragma unroll
  for (int p = 0; p < 16; p++) {
    const int h = t16 + 16 * p;
    float sn, cs;
    __sincosf(ek[h], &sn, &cs);
    const float xr = sre[r][h], xi = sim_[r][h];
    const size_t o = (size_t)(row0 + r) * HN + h;
    kf_re[o] = xr * cs - xi * sn;
    kf_im[o] = xr * sn + xi * cs;
  }
}

// ---------------------------------------------------------------------------
// K5: Hmix gather + conj(Kf)*Hmix ; IFFT-256 ; readout GEMM (512->72)
// ---------------------------------------------------------------------------
__global__ __launch_bounds__(256) void k5_holo(
    const float* __restrict__ holo_re, const float* __restrict__ holo_im,
    const float* __restrict__ kf_re, const float* __restrict__ kf_im,
    const float* __restrict__ w_ws, const int* __restrict__ itop_ws,
    const float* __restrict__ RW, const float* __restrict__ rb,
    float* __restrict__ triplet)
{
  __shared__ float wsm[16][KSEL];
  __shared__ int   ism[16][KSEL];
  __shared__ float sre[16][260];
  __shared__ float sim_[16][260];
  __shared__ float twc[HN], tws[HN];
  const int t = threadIdx.x;
  const int row0 = blockIdx.x * 16;
  {
    const float a = (float)t * (TWO_PI_F / 256.f);
    twc[t] = cosf(a); tws[t] = sinf(a);
  }
  for (int idx = t; idx < 16 * KSEL; idx += 256) {
    wsm[idx >> 5][idx & 31] = w_ws[(size_t)row0 * KSEL + idx];
    ism[idx >> 5][idx & 31] = itop_ws[(size_t)row0 * KSEL + idx];
  }
  __syncthreads();
  {
    const int h = t;
    const int hb = __brev((unsigned)h) >> 24;
    for (int r = 0; r < 16; r++) {
      float hr = 0.f, hi = 0.f;
#pragma unroll 8
      for (int k2 = 0; k2 < KSEL; k2++) {
        const int m = ism[r][k2];
        const float wk = wsm[r][k2];
        hr = fmaf(wk, holo_re[(size_t)m * HN + h], hr);
        hi = fmaf(wk, holo_im[(size_t)m * HN + h], hi);
      }
      const size_t o = (size_t)(row0 + r) * HN + h;
      const float kr = kf_re[o], ki = kf_im[o];
      sre[r][hb] = kr * hr + ki * hi;
      sim_[r][hb] = kr * hi - ki * hr;
    }
  }
  __syncthreads();
  const int r = t >> 4, t16 = t & 15;
  for (int s = 0; s < 8; s++) {
    const int half = 1 << s;
#pragma unroll
    for (int p = 0; p < 8; p++) {
      const int bi = t16 + 16 * p;
      const int jj = bi & (half - 1);
      const int base = (bi >> s) << (s + 1);
      const int i0 = base + jj, i1 = i0 + half;
      const int tw = jj << (7 - s);
      const float wr = twc[tw], wi = tws[tw];
      const float ar = sre[r][i0], ai = sim_[r][i0];
      const float br = sre[r][i1], b2 = sim_[r][i1];
      const float tr = wr * br - wi * b2, ti = wr * b2 + wi * br;
      sre[r][i0] = ar + tr; sim_[r][i0] = ai + ti;
      sre[r][i1] = ar - tr; sim_[r][i1] = ai - ti;
    }
    __syncthreads();
  }
  float dac[5] = {0.f, 0.f, 0.f, 0.f, 0.f};
  for (int h4 = 0; h4 < 256; h4 += 4) {
    const float4 vr = *(const float4*)&sre[r][h4];
#pragma unroll
    for (int u = 0; u < 5; u++) {
      const int o = t16 + 16 * u;
      if (o < TD) {
        const float4 wv = *(const float4*)&RW[(size_t)o * 512 + h4];
        dac[u] = fmaf(vr.x, wv.x, fmaf(vr.y, wv.y, fmaf(vr.z, wv.z, fmaf(vr.w, wv.w, dac[u]))));
      }
    }
  }
  for (int h4 = 0; h4 < 256; h4 += 4) {
    const float4 vi = *(const float4*)&sim_[r][h4];
#pragma unroll
    for (int u = 0; u < 5; u++) {
      const int o = t16 + 16 * u;
      if (o < TD) {
        const float4 wv = *(const float4*)&RW[(size_t)o * 512 + 256 + h4];
        dac[u] = fmaf(vi.x, wv.x, fmaf(vi.y, wv.y, fmaf(vi.z, wv.z, fmaf(vi.w, wv.w, dac[u]))));
      }
    }
  }
#pragma unroll
  for (int u = 0; u < 5; u++) {
    const int o = t16 + 16 * u;
    if (o < TD) triplet[(size_t)(row0 + r) * TD + o] = rb[o] + dac[u] * (1.f / 256.f);
  }
}

// ---------------------------------------------------------------------------
// K6: out = gelu(LN(triplet@W_out.T + b_out)) * gain
// ---------------------------------------------------------------------------
__global__ __launch_bounds__(256) void k6_out(
    const float* __restrict__ triplet, const float* __restrict__ Wo,
    const float* __restrict__ bo, const float* __restrict__ go,
    const float* __restrict__ bbo, const float* __restrict__ gain,
    float* __restrict__ out)
{
  __shared__ float ts[16][76];
  __shared__ float ys[16][772];
  const int t = threadIdx.x;
  const int row0 = blockIdx.x * 16;
  for (int idx = t; idx < 16 * TD; idx += 256) ts[idx / TD][idx % TD] = triplet[(size_t)row0 * TD + idx];
  __syncthreads();
  float acc[16][3];
#pragma unroll
  for (int rr = 0; rr < 16; rr++) { acc[rr][0] = 0.f; acc[rr][1] = 0.f; acc[rr][2] = 0.f; }
  for (int e = 0; e < TD; e++) {
    float wv[3];
#pragma unroll
    for (int j = 0; j < 3; j++) wv[j] = Wo[(size_t)(t + 256 * j) * TD + e];
#pragma unroll
    for (int rr = 0; rr < 16; rr++) {
      const float tv = ts[rr][e];
      acc[rr][0] = fmaf(tv, wv[0], acc[rr][0]);
      acc[rr][1] = fmaf(tv, wv[1], acc[rr][1]);
      acc[rr][2] = fmaf(tv, wv[2], acc[rr][2]);
    }
  }
  {
    const float b0 = bo[t], b1 = bo[t + 256], b2 = bo[t + 512];
#pragma unroll
    for (int rr = 0; rr < 16; rr++) {
      ys[rr][t] = acc[rr][0] + b0;
      ys[rr][t + 256] = acc[rr][1] + b1;
      ys[rr][t + 512] = acc[rr][2] + b2;
    }
  }
  __syncthreads();
  const int r = t >> 4, kt = t & 15;
  float s = 0.f, sq = 0.f;
  for (int u = 0; u < 48; u++) {
    const float v = ys[r][kt + 16 * u];
    s += v; sq = fmaf(v, v, sq);
  }
#pragma unroll
  for (int m = 1; m < 16; m <<= 1) { s += __shfl_xor(s, m, 16); sq += __shfl_xor(sq, m, 16); }
  const float mean = s * (1.f / 768.f);
  const float var  = sq * (1.f / 768.f) - mean * mean;
  const float rstd = rsqrtf(var + 1e-5f);
  const float gn = gain[row0 + r];
  for (int u = 0; u < 48; u++) {
    const int e = kt + 16 * u;
    const float v = (ys[r][e] - mean) * rstd * go[e] + bbo[e];
    out[(size_t)(row0 + r) * INDIM + e] = gelu_exact(v) * gn;
  }
}

// ---------------------------------------------------------------------------
extern "C" void kernel_launch(void* const* d_in, const int* in_sizes, int n_in,
                              void* d_out, int out_size, void* d_ws, size_t ws_size,
                              hipStream_t stream)
{
  (void)in_sizes; (void)n_in; (void)out_size; (void)ws_size;
  const float* x     = (const float*)d_in[0];
  const float* Wi    = (const float*)d_in[1];
  const float* bi    = (const float*)d_in[2];
  const float* gi    = (const float*)d_in[3];
  const float* bbi   = (const float*)d_in[4];
  const float* ricci = (const float*)d_in[5];
  const float* fw    = (const float*)d_in[6];
  const float* keys  = (const float*)d_in[7];
  const float* Wp    = (const float*)d_in[8];
  const float* bp    = (const float*)d_in[9];
  const float* ek    = (const float*)d_in[10];
  const float* hre   = (const float*)d_in[11];
  const float* him   = (const float*)d_in[12];
  const float* RW    = (const float*)d_in[13];
  const float* rb    = (const float*)d_in[14];
  const float* Wo    = (const float*)d_in[15];
  const float* bo    = (const float*)d_in[16];
  const float* go    = (const float*)d_in[17];
  const float* bbo   = (const float*)d_in[18];
  const float* qp    = (const float*)d_in[19];
  float* out = (float*)d_out;

  char* ws = (char*)d_ws;
  float* qvec    = (float*)(ws + 0);
  float* qnorm   = (float*)(ws + 786432);
  float* kn      = (float*)(ws + 819200);
  float* pm      = (float*)(ws + 851968);
  float* gain    = (float*)(ws + 884736);
  float* w_ws    = (float*)(ws + 917504);
  int*   itop    = (int*)  (ws + 1966080);
  float* triplet = (float*)(ws + 3014656);
  float* kf_re   = (float*)(ws + 5373952);
  float* kf_im   = (float*)(ws + 13762560);

  k1_encode<<<dim3(NROWS / 16), dim3(256), 0, stream>>>(x, Wi, bi, gi, bbi, ricci, qvec, qnorm);
  k2_prep<<<dim3(MKEYS / 256), dim3(256), 0, stream>>>(keys, qp, kn, pm);
  k4_phase<<<dim3(NROWS / 16), dim3(256), 0, stream>>>(x, Wp, bp, ek, kf_re, kf_im);
  k3_topk<<<dim3(NROWS / 32), dim3(256), 0, stream>>>(qvec, qnorm, keys, kn, fw, pm, w_ws, itop, gain);
  k5_holo<<<dim3(NROWS / 16), dim3(256), 0, stream>>>(hre, him, kf_re, kf_im, w_ws, itop, RW, rb, triplet);
  k6_out<<<dim3(NROWS / 16), dim3(256), 0, stream>>>(triplet, Wo, bo, go, bbo, gain, out);
}

// Round 4
// 588.197 us; speedup vs baseline: 1.2580x; 1.2580x over previous
//
#include <hip/hip_runtime.h>
#include <hip/hip_bf16.h>
#include <math.h>

#define NROWS 8192
#define INDIM 768
#define TD    72
#define DM    24
#define MKEYS 8192
#define KSEL  32
#define HN    256
#define K3CAND 128

#define TWO_PI_F 6.283185307179586f

__device__ __forceinline__ float gelu_exact(float v){
  return 0.5f * v * (1.0f + erff(v * 0.7071067811865476f));
}

// async global->LDS (gfx950): LDS dest = uniform base + lane*size, global src per-lane
__device__ __forceinline__ void gl_lds16(const float* g, float* l) {
  __builtin_amdgcn_global_load_lds((const __attribute__((address_space(1))) unsigned int*)g,
                                   (__attribute__((address_space(3))) unsigned int*)l, 16, 0, 0);
}
__device__ __forceinline__ void gl_lds4(const float* g, float* l) {
  __builtin_amdgcn_global_load_lds((const __attribute__((address_space(1))) unsigned int*)g,
                                   (__attribute__((address_space(3))) unsigned int*)l, 4, 0, 0);
}

// full-wave (64-lane) min via DPP on the VALU pipe; lane 63 holds the result.
__device__ __forceinline__ float wave_min64(float v) {
  int s, p;
  s = __float_as_int(v); p = __builtin_amdgcn_update_dpp(s, s, 0x111, 0xF, 0xF, false);
  v = fminf(v, __int_as_float(p));
  s = __float_as_int(v); p = __builtin_amdgcn_update_dpp(s, s, 0x112, 0xF, 0xF, false);
  v = fminf(v, __int_as_float(p));
  s = __float_as_int(v); p = __builtin_amdgcn_update_dpp(s, s, 0x114, 0xF, 0xF, false);
  v = fminf(v, __int_as_float(p));
  s = __float_as_int(v); p = __builtin_amdgcn_update_dpp(s, s, 0x118, 0xF, 0xF, false);
  v = fminf(v, __int_as_float(p));
  s = __float_as_int(v); p = __builtin_amdgcn_update_dpp(s, s, 0x142, 0xA, 0xF, false);
  v = fminf(v, __int_as_float(p));
  s = __float_as_int(v); p = __builtin_amdgcn_update_dpp(s, s, 0x143, 0xC, 0xF, false);
  v = fminf(v, __int_as_float(p));
  return v;
}

// ---------------------------------------------------------------------------
// K1: y = x@W_in.T + b_in ; LN(72); GELU; ricci einsum + mean over 3 -> q(24)
// ---------------------------------------------------------------------------
__global__ __launch_bounds__(256) void k1_encode(
    const float* __restrict__ x, const float* __restrict__ Wi,
    const float* __restrict__ bi, const float* __restrict__ gi,
    const float* __restrict__ bbi, const float* __restrict__ ricci,
    float* __restrict__ qvec, float* __restrict__ qnorm)
{
  __shared__ float xs[16][132];
  __shared__ float Ws[TD][132];
  __shared__ float zs[16][73];
  __shared__ float zb[16][25];
  const int t = threadIdx.x;
  const int r2 = t >> 4, ks = (t >> 3) & 1, u = t & 7;
  const int row0 = blockIdx.x * 16;

  float acc[9];
#pragma unroll
  for (int j = 0; j < 9; j++) acc[j] = 0.f;

  for (int kc = 0; kc < 6; kc++) {
    __syncthreads();
#pragma unroll
    for (int i = 0; i < 2; i++) {
      int idx = t + 256 * i;
      int rr = idx >> 5, kk = (idx & 31) << 2;
      *(float4*)&xs[rr][kk] = *(const float4*)&x[(size_t)(row0 + rr) * INDIM + kc * 128 + kk];
    }
#pragma unroll
    for (int i = 0; i < 9; i++) {
      int idx = t + 256 * i;
      int rr = idx >> 5, kk = (idx & 31) << 2;
      *(float4*)&Ws[rr][kk] = *(const float4*)&Wi[(size_t)rr * INDIM + kc * 128 + kk];
    }
    __syncthreads();
    const int kb = ks * 64;
#pragma unroll 4
    for (int kq = 0; kq < 16; kq++) {
      const float4 xv = *(const float4*)&xs[r2][kb + kq * 4];
#pragma unroll
      for (int j = 0; j < 9; j++) {
        const float4 wv = *(const float4*)&Ws[u + 8 * j][kb + kq * 4];
        acc[j] = fmaf(xv.x, wv.x, fmaf(xv.y, wv.y, fmaf(xv.z, wv.z, fmaf(xv.w, wv.w, acc[j]))));
      }
    }
  }
#pragma unroll
  for (int j = 0; j < 9; j++) acc[j] += __shfl_xor(acc[j], 8);

  float yv[9];
  float ps = 0.f, pq = 0.f;
#pragma unroll
  for (int j = 0; j < 9; j++) {
    const int o = u + 8 * j;
    yv[j] = acc[j] + bi[o];
    ps += yv[j]; pq += yv[j] * yv[j];
  }
#pragma unroll
  for (int m = 1; m < 8; m <<= 1) { ps += __shfl_xor(ps, m); pq += __shfl_xor(pq, m); }
  const float mean = ps * (1.f / 72.f);
  const float var  = pq * (1.f / 72.f) - mean * mean;
  const float rstd = rsqrtf(var + 1e-5f);
#pragma unroll
  for (int j = 0; j < 9; j++) {
    const int o = u + 8 * j;
    const float z = gelu_exact((yv[j] - mean) * rstd * gi[o] + bbi[o]);
    if (ks == 0) zs[r2][o] = z;
  }
  __syncthreads();
  {
    const int kt = t & 15;
    for (int e = kt; e < 24; e += 16)
      zb[r2][e] = (zs[r2][3 * e] + zs[r2][3 * e + 1] + zs[r2][3 * e + 2]) * (1.f / 3.f);
  }
  __syncthreads();
  {
    const int kt = t & 15;
    float qnp = 0.f;
    for (int d = kt; d < 24; d += 16) {
      float qd = 0.f;
#pragma unroll
      for (int e = 0; e < 24; e++) qd = fmaf(zb[r2][e], ricci[e * 24 + d], qd);
      qvec[(size_t)(row0 + r2) * DM + d] = qd;
      qnp = fmaf(qd, qd, qnp);
    }
#pragma unroll
    for (int m = 1; m < 16; m <<= 1) qnp += __shfl_xor(qnp, m, 16);
    if (kt == 0) qnorm[row0 + r2] = qnp;
  }
}

// ---------------------------------------------------------------------------
// K2: key norms + quantum-phase means
// ---------------------------------------------------------------------------
__global__ __launch_bounds__(256) void k2_prep(
    const float* __restrict__ keys, const float* __restrict__ qp,
    float* __restrict__ kn, float* __restrict__ pm)
{
  const int m = blockIdx.x * 256 + threadIdx.x;
  float s = 0.f;
#pragma unroll
  for (int d = 0; d < DM; d++) { const float v = keys[(size_t)m * DM + d]; s = fmaf(v, v, s); }
  kn[m] = s;
  float p = 0.f;
#pragma unroll
  for (int q = 0; q < 8; q++) p += tanhf(qp[(size_t)m * 8 + q]);
  pm[m] = p * 0.125f;
}

// ---------------------------------------------------------------------------
// K3 v4: distances + exact top-32 + softmax + gain.
// 512 thr / 32 rows per block (4 rows per wave, 8 waves), grid 256.
// Keys staged chunk-major float4 in LDS (128-key half-chunks, 24 KB dbuf ->
// ~79 KB LDS total -> 8 waves/CU = 2/SIMD). q[4][24] register-resident
// (~160 VGPRs, no spill). Group-min reduction via DPP on the VALU pipe
// (zero DS shuffles). Same arithmetic chain as rounds 1-3 -> identical
// top-32 selection -> identical output.
// ---------------------------------------------------------------------------
__global__ __launch_bounds__(512, 2) void k3_topk(
    const float* __restrict__ qvec, const float* __restrict__ qnorm,
    const float* __restrict__ keys, const float* __restrict__ kn,
    const float* __restrict__ fw,  const float* __restrict__ pm,
    float* __restrict__ w_out, int* __restrict__ itop_out, float* __restrict__ gain_out)
{
  __shared__ __align__(16) float ks[2][128 * 24];   // 24 KB, chunk-major float4
  __shared__ float knch[2][128];                    // 1 KB
  __shared__ float qsm[32][24];
  __shared__ float qnsm[32];
  __shared__ float gmins[64][33];                   // [group][row]
  __shared__ float Ts[32];
  __shared__ unsigned flg[32][2];                   // [row][word] live-group bits
  __shared__ unsigned candV[32][K3CAND];
  __shared__ int      candI[32][K3CAND];
  __shared__ int cnt[32];
  __shared__ float wV[32][KSEL];
  __shared__ int   wI[32][KSEL];

  const int t = threadIdx.x;
  const int wv = t >> 6, lane = t & 63;
  const int row0 = blockIdx.x * 32;
  const int wr0 = wv * 4;                           // wave's first row slot

  // stage half-chunk c_ (128 keys) into buffer b_, chunk-major:
  // float4 slot s holds float4 #(s>>7) of key (s&127). Every wave issues
  // exactly 2 VMEM ops (waves 6,7 duplicate the kn stage -> uniform vmcnt).
#define K3_STAGE(c_, b_) do {                                                  \
    if (wv < 6) {                                                              \
      _Pragma("unroll")                                                        \
      for (int i_ = 0; i_ < 2; i_++) {                                         \
        const int sl_ = wv * 2 + i_;                                           \
        const int ch_ = sl_ >> 1, k_ = (sl_ & 1) * 64 + lane;                  \
        gl_lds16(keys + ((size_t)(c_) * 128 + k_) * 24 + ch_ * 4,              \
                 &ks[b_][sl_ * 256]);                                          \
      }                                                                        \
    } else {                                                                   \
      _Pragma("unroll")                                                        \
      for (int i_ = 0; i_ < 2; i_++) {                                         \
        gl_lds4(kn + (size_t)(c_) * 128 + i_ * 64 + lane, &knch[b_][i_ * 64]); \
      }                                                                        \
    }                                                                          \
  } while (0)

  // one-time: q rows to LDS then regs; init cnt/flg
  for (int idx = t; idx < 32 * DM; idx += 512) qsm[idx / DM][idx % DM] = qvec[(size_t)row0 * DM + idx];
  if (t < 32) { qnsm[t] = qnorm[row0 + t]; cnt[t] = 0; flg[t][0] = 0u; flg[t][1] = 0u; }
  asm volatile("s_waitcnt vmcnt(0)" ::: "memory");  // drain prologue loads before counted staging
  K3_STAGE(0, 0);
  __syncthreads();

  float q[4][24];
  float qn4[4];
#pragma unroll
  for (int r = 0; r < 4; r++) {
    qn4[r] = qnsm[wr0 + r];
#pragma unroll
    for (int d = 0; d < DM; d++) q[r][d] = qsm[wr0 + r][d];
  }

  // ---------------- pass A: group minima (64 groups of 128 keys) ----------------
  for (int hc = 0; hc < 64; hc++) {
    const int buf = hc & 1;
    if (hc < 63) {
      K3_STAGE(hc + 1, buf ^ 1);
      asm volatile("s_waitcnt vmcnt(2)" ::: "memory");
    } else {
      asm volatile("s_waitcnt vmcnt(0)" ::: "memory");
    }
    __syncthreads();
    const float4* kb4 = (const float4*)&ks[buf][0];
    const float* knb = &knch[buf][0];
    float mn[4];
#pragma unroll
    for (int il = 0; il < 2; il++) {
      const int kk = il * 64 + lane;
      float kv[24];
      {
        const float4 a0 = kb4[0 * 128 + kk];
        const float4 a1 = kb4[1 * 128 + kk];
        const float4 a2 = kb4[2 * 128 + kk];
        const float4 a3 = kb4[3 * 128 + kk];
        const float4 a4 = kb4[4 * 128 + kk];
        const float4 a5 = kb4[5 * 128 + kk];
        kv[0]=a0.x; kv[1]=a0.y; kv[2]=a0.z; kv[3]=a0.w;
        kv[4]=a1.x; kv[5]=a1.y; kv[6]=a1.z; kv[7]=a1.w;
        kv[8]=a2.x; kv[9]=a2.y; kv[10]=a2.z; kv[11]=a2.w;
        kv[12]=a3.x; kv[13]=a3.y; kv[14]=a3.z; kv[15]=a3.w;
        kv[16]=a4.x; kv[17]=a4.y; kv[18]=a4.z; kv[19]=a4.w;
        kv[20]=a5.x; kv[21]=a5.y; kv[22]=a5.z; kv[23]=a5.w;
      }
      const float knn = knb[kk];
#pragma unroll
      for (int r = 0; r < 4; r++) {
        float dot = 0.f;
#pragma unroll
        for (int d = 0; d < DM; d++) dot = fmaf(kv[d], q[r][d], dot);
        const float d2 = fmaf(-2.f, dot, qn4[r] + knn);
        mn[r] = (il == 0) ? d2 : fminf(mn[r], d2);
      }
    }
#pragma unroll
    for (int r = 0; r < 4; r++) {
      const float gm = wave_min64(mn[r]);
      if (lane == 63) gmins[hc][wr0 + r] = gm;
    }
    __syncthreads();
  }

  // overlap: start staging chunk 0 for pass B while doing threshold work
  K3_STAGE(0, 0);

  // ---------------- threshold: 32nd smallest group-min per row ----------------
  {
    const int r = t & 31, i = t >> 5;       // i in [0,16), each handles 4 groups
    float vloc[4];
#pragma unroll
    for (int u = 0; u < 4; u++) vloc[u] = gmins[i * 4 + u][r];
    int rk[4], eq[4];
#pragma unroll
    for (int u = 0; u < 4; u++) { rk[u] = 0; eq[u] = 0; }
    for (int g = 0; g < 64; g++) {
      const float gv = gmins[g][r];
#pragma unroll
      for (int u = 0; u < 4; u++) { rk[u] += (gv < vloc[u]); eq[u] += (gv == vloc[u]); }
    }
#pragma unroll
    for (int u = 0; u < 4; u++)
      if (rk[u] <= 31 && rk[u] + eq[u] > 31) Ts[r] = vloc[u];
    __syncthreads();
    const float T = Ts[r];
    const float Tm = T + fabsf(T) * 1e-6f + 1e-20f;
    unsigned bits = 0;
#pragma unroll
    for (int u = 0; u < 4; u++) bits |= (vloc[u] <= Tm) ? (1u << u) : 0u;
    atomicOr(&flg[r][i >> 3], bits << ((i & 7) * 4));
  }
  __syncthreads();

  float TmA[4];
#pragma unroll
  for (int r = 0; r < 4; r++) {
    const float T = Ts[wr0 + r];
    TmA[r] = T + fabsf(T) * 1e-6f + 1e-20f;
  }

  // ---------------- pass B: recompute live groups, compact candidates ----------------
  for (int hc = 0; hc < 64; hc++) {
    const int buf = hc & 1;
    if (hc < 63) {
      K3_STAGE(hc + 1, buf ^ 1);
      asm volatile("s_waitcnt vmcnt(2)" ::: "memory");
    } else {
      asm volatile("s_waitcnt vmcnt(0)" ::: "memory");
    }
    __syncthreads();
    const int word = hc >> 5;
    const unsigned gb = 1u << (hc & 31);
    unsigned fm[4];
#pragma unroll
    for (int r = 0; r < 4; r++) fm[r] = flg[wr0 + r][word] & gb;
    if (fm[0] | fm[1] | fm[2] | fm[3]) {
      const float4* kb4 = (const float4*)&ks[buf][0];
      const float* knb = &knch[buf][0];
#pragma unroll
      for (int il = 0; il < 2; il++) {
        const int kk = il * 64 + lane;
        float kv[24];
        {
          const float4 a0 = kb4[0 * 128 + kk];
          const float4 a1 = kb4[1 * 128 + kk];
          const float4 a2 = kb4[2 * 128 + kk];
          const float4 a3 = kb4[3 * 128 + kk];
          const float4 a4 = kb4[4 * 128 + kk];
          const float4 a5 = kb4[5 * 128 + kk];
          kv[0]=a0.x; kv[1]=a0.y; kv[2]=a0.z; kv[3]=a0.w;
          kv[4]=a1.x; kv[5]=a1.y; kv[6]=a1.z; kv[7]=a1.w;
          kv[8]=a2.x; kv[9]=a2.y; kv[10]=a2.z; kv[11]=a2.w;
          kv[12]=a3.x; kv[13]=a3.y; kv[14]=a3.z; kv[15]=a3.w;
          kv[16]=a4.x; kv[17]=a4.y; kv[18]=a4.z; kv[19]=a4.w;
          kv[20]=a5.x; kv[21]=a5.y; kv[22]=a5.z; kv[23]=a5.w;
        }
        const float knn = knb[kk];
#pragma unroll
        for (int r = 0; r < 4; r++) {
          if (fm[r]) {                     // wave-uniform per row
            float dot = 0.f;
#pragma unroll
            for (int d = 0; d < DM; d++) dot = fmaf(kv[d], q[r][d], dot);
            const float d2 = fmaf(-2.f, dot, qn4[r] + knn);
            if (d2 <= TmA[r]) {
              const int pos = atomicAdd(&cnt[wr0 + r], 1);
              if (pos < K3CAND) {
                candV[wr0 + r][pos] = __float_as_uint(fmaxf(d2, 0.f));
                candI[wr0 + r][pos] = hc * 128 + kk;
              }
            }
          }
        }
      }
    }
    __syncthreads();
  }

  for (int idx = t; idx < 32 * KSEL; idx += 512) { wV[idx >> 5][idx & 31] = 1e30f; wI[idx >> 5][idx & 31] = 0; }
  __syncthreads();

  // ---------------- exact rank-select top-32 ----------------
  {
    const int r = t >> 4, kt = t & 15;     // 32 rows x 16 threads
    const int C = min(cnt[r], K3CAND);
    for (int ci = kt; ci < C; ci += 16) {
      const unsigned v = candV[r][ci];
      const unsigned key = (unsigned)candI[r][ci];
      int rk = 0;
      for (int j = 0; j < C; j++) {
        const unsigned vj = candV[r][j];
        rk += (vj < v) || (vj == v && (unsigned)candI[r][j] < key);
      }
      if (rk < KSEL) { wV[r][rk] = __uint_as_float(v); wI[r][rk] = (int)key; }
    }
  }
  __syncthreads();

  // ---------------- softmax over -dist, gain ----------------
  float sc;
  {
    const float f0 = fw[0], f1 = fw[1], f2 = fw[2], f3 = fw[3];
    const float mx = fmaxf(fmaxf(f0, f1), fmaxf(f2, f3));
    const float e0 = expf(f0 - mx), e1 = expf(f1 - mx), e2 = expf(f2 - mx), e3 = expf(f3 - mx);
    sc = (e0 + 0.5f * e1 + 0.25f * e2 + 0.125f * e3) / (e0 + e1 + e2 + e3);
  }
  {
    const int r = t >> 4, kt = t & 15;
    const float dA = sqrtf(wV[r][kt]) * sc;
    const float dB = sqrtf(wV[r][kt + 16]) * sc;
    float mn = fminf(dA, dB);
#pragma unroll
    for (int m = 1; m < 16; m <<= 1) mn = fminf(mn, __shfl_xor(mn, m, 16));
    const float eA = expf(mn - dA), eB = expf(mn - dB);
    float s = eA + eB;
#pragma unroll
    for (int m = 1; m < 16; m <<= 1) s += __shfl_xor(s, m, 16);
    const float w0 = eA / s, w1 = eB / s;
    const int k0 = wI[r][kt], k1 = wI[r][kt + 16];
    float gp = w0 * pm[k0] + w1 * pm[k1];
#pragma unroll
    for (int m = 1; m < 16; m <<= 1) gp += __shfl_xor(gp, m, 16);
    const size_t row = (size_t)(row0 + r);
    w_out[row * KSEL + kt] = w0;      w_out[row * KSEL + kt + 16] = w1;
    itop_out[row * KSEL + kt] = k0;   itop_out[row * KSEL + kt + 16] = k1;
    if (kt == 0) gain_out[row] = 1.f + 0.02f * gp;
  }
#undef K3_STAGE
}

// ---------------------------------------------------------------------------
// K4: p = x@key_phase_W.T + b ; Kf = FFT(e^{i 2pi sigmoid(p)}) * e^{i ek}
// ---------------------------------------------------------------------------
__global__ __launch_bounds__(256) void k4_phase(
    const float* __restrict__ x, const float* __restrict__ Wp,
    const float* __restrict__ bp, const float* __restrict__ ek,
    float* __restrict__ kf_re, float* __restrict__ kf_im)
{
  __shared__ float xs[16][36];
  __shared__ float Ws[HN][36];
  __shared__ float sre[16][260];
  __shared__ float sim_[16][260];
  __shared__ float twc[HN], tws[HN];
  const int t = threadIdx.x;
  const int row0 = blockIdx.x * 16;
  {
    const float a = (float)t * (TWO_PI_F / 256.f);
    twc[t] = cosf(a); tws[t] = sinf(a);
  }
  const int r = t >> 4, cg = t & 15;
  float acc[16];
#pragma unroll
  for (int j = 0; j < 16; j++) acc[j] = bp[cg + 16 * j];

  for (int kc = 0; kc < 24; kc++) {
    __syncthreads();
    if (t < 128) {
      const int rr = t >> 3, kk = (t & 7) << 2;
      *(float4*)&xs[rr][kk] = *(const float4*)&x[(size_t)(row0 + rr) * INDIM + kc * 32 + kk];
    }
#pragma unroll
    for (int i = 0; i < 8; i++) {
      const int idx = t + 256 * i;
      const int rr = idx >> 3, kk = (idx & 7) << 2;
      *(float4*)&Ws[rr][kk] = *(const float4*)&Wp[(size_t)rr * INDIM + kc * 32 + kk];
    }
    __syncthreads();
#pragma unroll
    for (int kq = 0; kq < 8; kq++) {
      const float4 xv = *(const float4*)&xs[r][kq * 4];
#pragma unroll
      for (int j = 0; j < 16; j++) {
        const float4 wv = *(const float4*)&Ws[cg + 16 * j][kq * 4];
        acc[j] = fmaf(xv.x, wv.x, fmaf(xv.y, wv.y, fmaf(xv.z, wv.z, fmaf(xv.w, wv.w, acc[j]))));
      }
    }
  }
  __syncthreads();
#pragma unroll
  for (int j = 0; j < 16; j++) {
    const int c = cg + 16 * j;
    const float sg = 1.f / (1.f + expf(-acc[j]));
    float sn, cs;
    __sincosf(TWO_PI_F * sg, &sn, &cs);
    const int hb = __brev((unsigned)c) >> 24;
    sre[r][hb] = cs; sim_[r][hb] = sn;
  }
  __syncthreads();
  const int t16 = t & 15;
  for (int s = 0; s < 8; s++) {
    const int half = 1 << s;
#pragma unroll
    for (int p = 0; p < 8; p++) {
      const int bi = t16 + 16 * p;
      const int jj = bi & (half - 1);
      const int base = (bi >> s) << (s + 1);
      const int i0 = base + jj, i1 = i0 + half;
      const int tw = jj << (7 - s);
      const float wr = twc[tw], wi = -tws[tw];
      const float ar = sre[r][i0], ai = sim_[r][i0];
      const float br = sre[r][i1], b2 = sim_[r][i1];
      const float tr = wr * br - wi * b2, ti = wr * b2 + wi * br;
      sre[r][i0] = ar + tr; sim_[r][i0] = ai + ti;
      sre[r][i1] = ar - tr; sim_[r][i1] = ai - ti;
    }
    __syncthreads();
  }
#pragma unroll
  for (int p = 0; p < 16; p++) {
    const int h = t16 + 16 * p;
    float sn, cs;
    __sincosf(ek[h], &sn, &cs);
    const float xr = sre[r][h], xi = sim_[r][h];
    const size_t o = (size_t)(row0 + r) * HN + h;
    kf_re[o] = xr * cs - xi * sn;
    kf_im[o] = xr * sn + xi * cs;
  }
}

// ---------------------------------------------------------------------------
// K5: Hmix gather + conj(Kf)*Hmix ; IFFT-256 ; readout GEMM (512->72)
// ---------------------------------------------------------------------------
__global__ __launch_bounds__(256) void k5_holo(
    const float* __restrict__ holo_re, const float* __restrict__ holo_im,
    const float* __restrict__ kf_re, const float* __restrict__ kf_im,
    const float* __restrict__ w_ws, const int* __restrict__ itop_ws,
    const float* __restrict__ RW, const float* __restrict__ rb,
    float* __restrict__ triplet)
{
  __shared__ float wsm[16][KSEL];
  __shared__ int   ism[16][KSEL];
  __shared__ float sre[16][260];
  __shared__ float sim_[16][260];
  __shared__ float twc[HN], tws[HN];
  const int t = threadIdx.x;
  const int row0 = blockIdx.x * 16;
  {
    const float a = (float)t * (TWO_PI_F / 256.f);
    twc[t] = cosf(a); tws[t] = sinf(a);
  }
  for (int idx = t; idx < 16 * KSEL; idx += 256) {
    wsm[idx >> 5][idx & 31] = w_ws[(size_t)row0 * KSEL + idx];
    ism[idx >> 5][idx & 31] = itop_ws[(size_t)row0 * KSEL + idx];
  }
  __syncthreads();
  {
    const int h = t;
    const int hb = __brev((unsigned)h) >> 24;
    for (int r = 0; r < 16; r++) {
      float hr = 0.f, hi = 0.f;
#pragma unroll 8
      for (int k2 = 0; k2 < KSEL; k2++) {
        const int m = ism[r][k2];
        const float wk = wsm[r][k2];
        hr = fmaf(wk, holo_re[(size_t)m * HN + h], hr);
        hi = fmaf(wk, holo_im[(size_t)m * HN + h], hi);
      }
      const size_t o = (size_t)(row0 + r) * HN + h;
      const float kr = kf_re[o], ki = kf_im[o];
      sre[r][hb] = kr * hr + ki * hi;
      sim_[r][hb] = kr * hi - ki * hr;
    }
  }
  __syncthreads();
  const int r = t >> 4, t16 = t & 15;
  for (int s = 0; s < 8; s++) {
    const int half = 1 << s;
#pragma unroll
    for (int p = 0; p < 8; p++) {
      const int bi = t16 + 16 * p;
      const int jj = bi & (half - 1);
      const int base = (bi >> s) << (s + 1);
      const int i0 = base + jj, i1 = i0 + half;
      const int tw = jj << (7 - s);
      const float wr = twc[tw], wi = tws[tw];
      const float ar = sre[r][i0], ai = sim_[r][i0];
      const float br = sre[r][i1], b2 = sim_[r][i1];
      const float tr = wr * br - wi * b2, ti = wr * b2 + wi * br;
      sre[r][i0] = ar + tr; sim_[r][i0] = ai + ti;
      sre[r][i1] = ar - tr; sim_[r][i1] = ai - ti;
    }
    __syncthreads();
  }
  float dac[5] = {0.f, 0.f, 0.f, 0.f, 0.f};
  for (int h4 = 0; h4 < 256; h4 += 4) {
    const float4 vr = *(const float4*)&sre[r][h4];
#pragma unroll
    for (int u = 0; u < 5; u++) {
      const int o = t16 + 16 * u;
      if (o < TD) {
        const float4 wv = *(const float4*)&RW[(size_t)o * 512 + h4];
        dac[u] = fmaf(vr.x, wv.x, fmaf(vr.y, wv.y, fmaf(vr.z, wv.z, fmaf(vr.w, wv.w, dac[u]))));
      }
    }
  }
  for (int h4 = 0; h4 < 256; h4 += 4) {
    const float4 vi = *(const float4*)&sim_[r][h4];
#pragma unroll
    for (int u = 0; u < 5; u++) {
      const int o = t16 + 16 * u;
      if (o < TD) {
        const float4 wv = *(const float4*)&RW[(size_t)o * 512 + 256 + h4];
        dac[u] = fmaf(vi.x, wv.x, fmaf(vi.y, wv.y, fmaf(vi.z, wv.z, fmaf(vi.w, wv.w, dac[u]))));
      }
    }
  }
#pragma unroll
  for (int u = 0; u < 5; u++) {
    const int o = t16 + 16 * u;
    if (o < TD) triplet[(size_t)(row0 + r) * TD + o] = rb[o] + dac[u] * (1.f / 256.f);
  }
}

// ---------------------------------------------------------------------------
// K6: out = gelu(LN(triplet@W_out.T + b_out)) * gain
// ---------------------------------------------------------------------------
__global__ __launch_bounds__(256) void k6_out(
    const float* __restrict__ triplet, const float* __restrict__ Wo,
    const float* __restrict__ bo, const float* __restrict__ go,
    const float* __restrict__ bbo, const float* __restrict__ gain,
    float* __restrict__ out)
{
  __shared__ float ts[16][76];
  __shared__ float ys[16][772];
  const int t = threadIdx.x;
  const int row0 = blockIdx.x * 16;
  for (int idx = t; idx < 16 * TD; idx += 256) ts[idx / TD][idx % TD] = triplet[(size_t)row0 * TD + idx];
  __syncthreads();
  float acc[16][3];
#pragma unroll
  for (int rr = 0; rr < 16; rr++) { acc[rr][0] = 0.f; acc[rr][1] = 0.f; acc[rr][2] = 0.f; }
  for (int e = 0; e < TD; e++) {
    float wv[3];
#pragma unroll
    for (int j = 0; j < 3; j++) wv[j] = Wo[(size_t)(t + 256 * j) * TD + e];
#pragma unroll
    for (int rr = 0; rr < 16; rr++) {
      const float tv = ts[rr][e];
      acc[rr][0] = fmaf(tv, wv[0], acc[rr][0]);
      acc[rr][1] = fmaf(tv, wv[1], acc[rr][1]);
      acc[rr][2] = fmaf(tv, wv[2], acc[rr][2]);
    }
  }
  {
    const float b0 = bo[t], b1 = bo[t + 256], b2 = bo[t + 512];
#pragma unroll
    for (int rr = 0; rr < 16; rr++) {
      ys[rr][t] = acc[rr][0] + b0;
      ys[rr][t + 256] = acc[rr][1] + b1;
      ys[rr][t + 512] = acc[rr][2] + b2;
    }
  }
  __syncthreads();
  const int r = t >> 4, kt = t & 15;
  float s = 0.f, sq = 0.f;
  for (int u = 0; u < 48; u++) {
    const float v = ys[r][kt + 16 * u];
    s += v; sq = fmaf(v, v, sq);
  }
#pragma unroll
  for (int m = 1; m < 16; m <<= 1) { s += __shfl_xor(s, m, 16); sq += __shfl_xor(sq, m, 16); }
  const float mean = s * (1.f / 768.f);
  const float var  = sq * (1.f / 768.f) - mean * mean;
  const float rstd = rsqrtf(var + 1e-5f);
  const float gn = gain[row0 + r];
  for (int u = 0; u < 48; u++) {
    const int e = kt + 16 * u;
    const float v = (ys[r][e] - mean) * rstd * go[e] + bbo[e];
    out[(size_t)(row0 + r) * INDIM + e] = gelu_exact(v) * gn;
  }
}

// ---------------------------------------------------------------------------
extern "C" void kernel_launch(void* const* d_in, const int* in_sizes, int n_in,
                              void* d_out, int out_size, void* d_ws, size_t ws_size,
                              hipStream_t stream)
{
  (void)in_sizes; (void)n_in; (void)out_size; (void)ws_size;
  const float* x     = (const float*)d_in[0];
  const float* Wi    = (const float*)d_in[1];
  const float* bi    = (const float*)d_in[2];
  const float* gi    = (const float*)d_in[3];
  const float* bbi   = (const float*)d_in[4];
  const float* ricci = (const float*)d_in[5];
  const float* fw    = (const float*)d_in[6];
  const float* keys  = (const float*)d_in[7];
  const float* Wp    = (const float*)d_in[8];
  const float* bp    = (const float*)d_in[9];
  const float* ek    = (const float*)d_in[10];
  const float* hre   = (const float*)d_in[11];
  const float* him   = (const float*)d_in[12];
  const float* RW    = (const float*)d_in[13];
  const float* rb    = (const float*)d_in[14];
  const float* Wo    = (const float*)d_in[15];
  const float* bo    = (const float*)d_in[16];
  const float* go    = (const float*)d_in[17];
  const float* bbo   = (const float*)d_in[18];
  const float* qp    = (const float*)d_in[19];
  float* out = (float*)d_out;

  char* ws = (char*)d_ws;
  float* qvec    = (float*)(ws + 0);
  float* qnorm   = (float*)(ws + 786432);
  float* kn      = (float*)(ws + 819200);
  float* pm      = (float*)(ws + 851968);
  float* gain    = (float*)(ws + 884736);
  float* w_ws    = (float*)(ws + 917504);
  int*   itop    = (int*)  (ws + 1966080);
  float* triplet = (float*)(ws + 3014656);
  float* kf_re   = (float*)(ws + 5373952);
  float* kf_im   = (float*)(ws + 13762560);

  k1_encode<<<dim3(NROWS / 16), dim3(256), 0, stream>>>(x, Wi, bi, gi, bbi, ricci, qvec, qnorm);
  k2_prep<<<dim3(MKEYS / 256), dim3(256), 0, stream>>>(keys, qp, kn, pm);
  k4_phase<<<dim3(NROWS / 16), dim3(256), 0, stream>>>(x, Wp, bp, ek, kf_re, kf_im);
  k3_topk<<<dim3(NROWS / 32), dim3(512), 0, stream>>>(qvec, qnorm, keys, kn, fw, pm, w_ws, itop, gain);
  k5_holo<<<dim3(NROWS / 16), dim3(256), 0, stream>>>(hre, him, kf_re, kf_im, w_ws, itop, RW, rb, triplet);
  k6_out<<<dim3(NROWS / 16), dim3(256), 0, stream>>>(triplet, Wo, bo, go, bbo, gain, out);
}

// Round 5
// 459.668 us; speedup vs baseline: 1.6098x; 1.2796x over previous
//
#include <hip/hip_runtime.h>
#include <hip/hip_bf16.h>
#include <math.h>

#define NROWS 8192
#define INDIM 768
#define TD    72
#define DM    24
#define MKEYS 8192
#define KSEL  32
#define HN    256
#define K3CAND 128

#define TWO_PI_F 6.283185307179586f

typedef __attribute__((ext_vector_type(8))) short short8_t;
typedef __attribute__((ext_vector_type(4))) float f32x4;

__device__ __forceinline__ float gelu_exact(float v){
  return 0.5f * v * (1.0f + erff(v * 0.7071067811865476f));
}

// round-to-nearest-even f32 -> bf16 bits
__device__ __forceinline__ unsigned short bf16rn(float f){
  unsigned u = __float_as_uint(f);
  unsigned r = u + 0x7FFFu + ((u >> 16) & 1u);
  return (unsigned short)(r >> 16);
}

// min across each 16-lane DPP row; lane 15 (mod 16) holds the row min.
__device__ __forceinline__ float rowmin16(float v){
  int s, p;
  s = __float_as_int(v); p = __builtin_amdgcn_update_dpp(s, s, 0x111, 0xF, 0xF, false);
  v = fminf(v, __int_as_float(p));
  s = __float_as_int(v); p = __builtin_amdgcn_update_dpp(s, s, 0x112, 0xF, 0xF, false);
  v = fminf(v, __int_as_float(p));
  s = __float_as_int(v); p = __builtin_amdgcn_update_dpp(s, s, 0x114, 0xF, 0xF, false);
  v = fminf(v, __int_as_float(p));
  s = __float_as_int(v); p = __builtin_amdgcn_update_dpp(s, s, 0x118, 0xF, 0xF, false);
  v = fminf(v, __int_as_float(p));
  return v;
}

// ---------------------------------------------------------------------------
// K1: y = x@W_in.T + b_in ; LN(72); GELU; ricci einsum + mean over 3 -> q(24)
// ---------------------------------------------------------------------------
__global__ __launch_bounds__(256) void k1_encode(
    const float* __restrict__ x, const float* __restrict__ Wi,
    const float* __restrict__ bi, const float* __restrict__ gi,
    const float* __restrict__ bbi, const float* __restrict__ ricci,
    float* __restrict__ qvec, float* __restrict__ qnorm)
{
  __shared__ float xs[16][132];
  __shared__ float Ws[TD][132];
  __shared__ float zs[16][73];
  __shared__ float zb[16][25];
  const int t = threadIdx.x;
  const int r2 = t >> 4, ks = (t >> 3) & 1, u = t & 7;
  const int row0 = blockIdx.x * 16;

  float acc[9];
#pragma unroll
  for (int j = 0; j < 9; j++) acc[j] = 0.f;

  for (int kc = 0; kc < 6; kc++) {
    __syncthreads();
#pragma unroll
    for (int i = 0; i < 2; i++) {
      int idx = t + 256 * i;
      int rr = idx >> 5, kk = (idx & 31) << 2;
      *(float4*)&xs[rr][kk] = *(const float4*)&x[(size_t)(row0 + rr) * INDIM + kc * 128 + kk];
    }
#pragma unroll
    for (int i = 0; i < 9; i++) {
      int idx = t + 256 * i;
      int rr = idx >> 5, kk = (idx & 31) << 2;
      *(float4*)&Ws[rr][kk] = *(const float4*)&Wi[(size_t)rr * INDIM + kc * 128 + kk];
    }
    __syncthreads();
    const int kb = ks * 64;
#pragma unroll 4
    for (int kq = 0; kq < 16; kq++) {
      const float4 xv = *(const float4*)&xs[r2][kb + kq * 4];
#pragma unroll
      for (int j = 0; j < 9; j++) {
        const float4 wv = *(const float4*)&Ws[u + 8 * j][kb + kq * 4];
        acc[j] = fmaf(xv.x, wv.x, fmaf(xv.y, wv.y, fmaf(xv.z, wv.z, fmaf(xv.w, wv.w, acc[j]))));
      }
    }
  }
#pragma unroll
  for (int j = 0; j < 9; j++) acc[j] += __shfl_xor(acc[j], 8);

  float yv[9];
  float ps = 0.f, pq = 0.f;
#pragma unroll
  for (int j = 0; j < 9; j++) {
    const int o = u + 8 * j;
    yv[j] = acc[j] + bi[o];
    ps += yv[j]; pq += yv[j] * yv[j];
  }
#pragma unroll
  for (int m = 1; m < 8; m <<= 1) { ps += __shfl_xor(ps, m); pq += __shfl_xor(pq, m); }
  const float mean = ps * (1.f / 72.f);
  const float var  = pq * (1.f / 72.f) - mean * mean;
  const float rstd = rsqrtf(var + 1e-5f);
#pragma unroll
  for (int j = 0; j < 9; j++) {
    const int o = u + 8 * j;
    const float z = gelu_exact((yv[j] - mean) * rstd * gi[o] + bbi[o]);
    if (ks == 0) zs[r2][o] = z;
  }
  __syncthreads();
  {
    const int kt = t & 15;
    for (int e = kt; e < 24; e += 16)
      zb[r2][e] = (zs[r2][3 * e] + zs[r2][3 * e + 1] + zs[r2][3 * e + 2]) * (1.f / 3.f);
  }
  __syncthreads();
  {
    const int kt = t & 15;
    float qnp = 0.f;
    for (int d = kt; d < 24; d += 16) {
      float qd = 0.f;
#pragma unroll
      for (int e = 0; e < 24; e++) qd = fmaf(zb[r2][e], ricci[e * 24 + d], qd);
      qvec[(size_t)(row0 + r2) * DM + d] = qd;
      qnp = fmaf(qd, qd, qnp);
    }
#pragma unroll
    for (int m = 1; m < 16; m <<= 1) qnp += __shfl_xor(qnp, m, 16);
    if (kt == 0) qnorm[row0 + r2] = qnp;
  }
}

// ---------------------------------------------------------------------------
// K2: key norms + quantum-phase means + bf16 hi/lo split keys + chunk kn-max
// ---------------------------------------------------------------------------
__global__ __launch_bounds__(256) void k2_prep(
    const float* __restrict__ keys, const float* __restrict__ qp,
    float* __restrict__ kn, float* __restrict__ pm,
    unsigned short* __restrict__ khi, unsigned short* __restrict__ klo,
    float* __restrict__ kmx)
{
  __shared__ float red[256];
  const int t = threadIdx.x;
  const int m = blockIdx.x * 256 + t;
  float kv[24];
#pragma unroll
  for (int d = 0; d < DM; d += 4) {
    const float4 v = *(const float4*)&keys[(size_t)m * DM + d];
    kv[d] = v.x; kv[d + 1] = v.y; kv[d + 2] = v.z; kv[d + 3] = v.w;
  }
  float s = 0.f;
#pragma unroll
  for (int d = 0; d < DM; d++) s = fmaf(kv[d], kv[d], s);   // same chain as before
  kn[m] = s;
  float p = 0.f;
#pragma unroll
  for (int q = 0; q < 8; q++) p += tanhf(qp[(size_t)m * 8 + q]);
  pm[m] = p * 0.125f;
  // hi/lo bf16 split, padded to 32
#pragma unroll
  for (int d = 0; d < DM; d++) {
    const unsigned short h = bf16rn(kv[d]);
    const float hf = __uint_as_float(((unsigned)h) << 16);
    const unsigned short l = bf16rn(kv[d] - hf);
    khi[(size_t)m * 32 + d] = h;
    klo[(size_t)m * 32 + d] = l;
  }
#pragma unroll
  for (int d = DM; d < 32; d++) { khi[(size_t)m * 32 + d] = 0; klo[(size_t)m * 32 + d] = 0; }
  // block max of kn
  red[t] = s;
  __syncthreads();
  for (int off = 128; off > 0; off >>= 1) {
    if (t < off) red[t] = fmaxf(red[t], red[t + off]);
    __syncthreads();
  }
  if (t == 0) kmx[blockIdx.x] = red[0];
}

// ---------------------------------------------------------------------------
// K3 v5: MFMA screening + exact fp32 finish.
// 1024 thr (16 waves, 4/SIMD), 32 rows/block, grid 256.
// Phase 1: bf16 hi/lo split dots via mfma_f32_16x16x32_bf16 (3 mfma/tile/row-tile),
//   group-min per 128-key group via DPP rowmin (all-VALU, no barriers in sweep).
// Threshold: 32nd group-min + analytic margin 2*mu brackets the exact top-32.
// Phase 2: MFMA on live groups, filter d2a <= Tm2 -> candidate indices.
// Phase 3: exact fp32 recompute of candidates (round-1 chain) -> rank-select,
//   softmax, gain. Output identical to rounds 1-4.
// ---------------------------------------------------------------------------
__global__ __launch_bounds__(1024, 4) void k3_topk(
    const float* __restrict__ qvec, const float* __restrict__ qnorm,
    const float* __restrict__ keys, const float* __restrict__ kn,
    const unsigned short* __restrict__ khi, const unsigned short* __restrict__ klo,
    const float* __restrict__ kmx,
    const float* __restrict__ fw,  const float* __restrict__ pm,
    float* __restrict__ w_out, int* __restrict__ itop_out, float* __restrict__ gain_out)
{
  __shared__ float qsm[32][25];
  __shared__ float qns[32];
  __shared__ unsigned short qh_l[32][32];
  __shared__ unsigned short ql_l[32][32];
  __shared__ float gmins[64][33];
  __shared__ float Ts[32];
  __shared__ float Tm2s[32];
  __shared__ unsigned glive[2];
  __shared__ int cnt[32];
  __shared__ int      candI[32][K3CAND];
  __shared__ unsigned candV[32][K3CAND];
  __shared__ float wV[32][KSEL];
  __shared__ int   wI[32][KSEL];
  __shared__ float knmax_s;

  const int t = threadIdx.x;
  const int w = t >> 6, lane = t & 63;
  const int colid = lane & 15;     // A row index / B col index / D col index
  const int kgrp  = lane >> 4;     // k-chunk for A/B; D row quad
  const int row0 = blockIdx.x * 32;

  // ---- init ----
  if (t < 32 * DM) qsm[t / DM][t % DM] = qvec[(size_t)row0 * DM + t];
  if (t < 32) { qns[t] = qnorm[row0 + t]; cnt[t] = 0; }
  if (t < 2) glive[t] = 0u;
  if (t == 0) { float m = 0.f; for (int i = 0; i < 32; i++) m = fmaxf(m, kmx[i]); knmax_s = m; }
  __syncthreads();
  {
    const int r = t >> 5, k = t & 31;     // one slot per thread (32x32)
    const float v = (k < DM) ? qsm[r][k] : 0.f;
    const unsigned short h = bf16rn(v);
    const float hf = __uint_as_float(((unsigned)h) << 16);
    qh_l[r][k] = h;
    ql_l[r][k] = bf16rn(v - hf);
  }
  __syncthreads();

  // A fragments (rows 0-15 tile0, rows 16-31 tile1); constants per block
  const short8_t ah0 = *(const short8_t*)&qh_l[colid][kgrp * 8];
  const short8_t al0 = *(const short8_t*)&ql_l[colid][kgrp * 8];
  const short8_t ah1 = *(const short8_t*)&qh_l[16 + colid][kgrp * 8];
  const short8_t al1 = *(const short8_t*)&ql_l[16 + colid][kgrp * 8];
  float qn8[8];
#pragma unroll
  for (int reg = 0; reg < 4; reg++) {
    qn8[reg]     = qns[kgrp * 4 + reg];
    qn8[reg + 4] = qns[16 + kgrp * 4 + reg];
  }

  // ---- phase 1: approx group minima (64 groups of 128 keys) ----
  for (int u = 0; u < 4; u++) {
    const int g = w + 16 * u;
    const int nbase = g * 128;
    float mn[8];
#pragma unroll
    for (int j = 0; j < 8; j++) {
      const int key = nbase + j * 16 + colid;
      const short8_t bh = *(const short8_t*)&khi[(size_t)key * 32 + kgrp * 8];
      const short8_t bl = *(const short8_t*)&klo[(size_t)key * 32 + kgrp * 8];
      const float knv = kn[key];
      f32x4 c0 = {0.f, 0.f, 0.f, 0.f}, c1 = {0.f, 0.f, 0.f, 0.f};
      c0 = __builtin_amdgcn_mfma_f32_16x16x32_bf16(ah0, bh, c0, 0, 0, 0);
      c1 = __builtin_amdgcn_mfma_f32_16x16x32_bf16(ah1, bh, c1, 0, 0, 0);
      c0 = __builtin_amdgcn_mfma_f32_16x16x32_bf16(ah0, bl, c0, 0, 0, 0);
      c1 = __builtin_amdgcn_mfma_f32_16x16x32_bf16(ah1, bl, c1, 0, 0, 0);
      c0 = __builtin_amdgcn_mfma_f32_16x16x32_bf16(al0, bh, c0, 0, 0, 0);
      c1 = __builtin_amdgcn_mfma_f32_16x16x32_bf16(al1, bh, c1, 0, 0, 0);
#pragma unroll
      for (int reg = 0; reg < 4; reg++) {
        const float d0 = fmaf(-2.f, c0[reg], qn8[reg] + knv);
        const float d1 = fmaf(-2.f, c1[reg], qn8[reg + 4] + knv);
        if (j == 0) { mn[reg] = d0; mn[reg + 4] = d1; }
        else        { mn[reg] = fminf(mn[reg], d0); mn[reg + 4] = fminf(mn[reg + 4], d1); }
      }
    }
#pragma unroll
    for (int reg = 0; reg < 4; reg++) {
      const float v0 = rowmin16(mn[reg]);
      const float v1 = rowmin16(mn[reg + 4]);
      if (colid == 15) {
        gmins[g][kgrp * 4 + reg] = v0;
        gmins[g][16 + kgrp * 4 + reg] = v1;
      }
    }
  }
  __syncthreads();

  // ---- threshold: 32nd smallest approx group-min per row + margin ----
  {
    const int r = t & 31, i = t >> 5;    // i in [0,32): 2 groups each
    const float v0 = gmins[i * 2][r], v1 = gmins[i * 2 + 1][r];
    int rk0 = 0, eq0 = 0, rk1 = 0, eq1 = 0;
    for (int g = 0; g < 64; g++) {
      const float gv = gmins[g][r];
      rk0 += (gv < v0); eq0 += (gv == v0);
      rk1 += (gv < v1); eq1 += (gv == v1);
    }
    if (rk0 <= 31 && rk0 + eq0 > 31) Ts[r] = v0;
    if (rk1 <= 31 && rk1 + eq1 > 31) Ts[r] = v1;
  }
  __syncthreads();
  if (t < 32) {
    const float T = Ts[t];
    const float mu = 2e-4f * sqrtf(fmaxf(qns[t], 0.f) * knmax_s) + 1e-6f;
    Tm2s[t] = T + fabsf(T) * 1e-6f + 2.f * mu;
  }
  __syncthreads();
  {
    const int r = t & 31, i = t >> 5;
    const unsigned b0 = (gmins[i * 2][r]     <= Tm2s[r]) ? 1u : 0u;
    const unsigned b1 = (gmins[i * 2 + 1][r] <= Tm2s[r]) ? 2u : 0u;
    const unsigned bits = (b0 | b1) << ((i * 2) & 31);
    if (bits) atomicOr(&glive[i >> 4], bits);
  }
  __syncthreads();

  float tm8[8];
#pragma unroll
  for (int reg = 0; reg < 4; reg++) {
    tm8[reg]     = Tm2s[kgrp * 4 + reg];
    tm8[reg + 4] = Tm2s[16 + kgrp * 4 + reg];
  }

  // ---- phase 2: recompute live groups, filter, collect candidate indices ----
  for (int u = 0; u < 4; u++) {
    const int g = w + 16 * u;
    if (!((glive[g >> 5] >> (g & 31)) & 1u)) continue;
    const int nbase = g * 128;
#pragma unroll
    for (int j = 0; j < 8; j++) {
      const int key = nbase + j * 16 + colid;
      const short8_t bh = *(const short8_t*)&khi[(size_t)key * 32 + kgrp * 8];
      const short8_t bl = *(const short8_t*)&klo[(size_t)key * 32 + kgrp * 8];
      const float knv = kn[key];
      f32x4 c0 = {0.f, 0.f, 0.f, 0.f}, c1 = {0.f, 0.f, 0.f, 0.f};
      c0 = __builtin_amdgcn_mfma_f32_16x16x32_bf16(ah0, bh, c0, 0, 0, 0);
      c1 = __builtin_amdgcn_mfma_f32_16x16x32_bf16(ah1, bh, c1, 0, 0, 0);
      c0 = __builtin_amdgcn_mfma_f32_16x16x32_bf16(ah0, bl, c0, 0, 0, 0);
      c1 = __builtin_amdgcn_mfma_f32_16x16x32_bf16(ah1, bl, c1, 0, 0, 0);
      c0 = __builtin_amdgcn_mfma_f32_16x16x32_bf16(al0, bh, c0, 0, 0, 0);
      c1 = __builtin_amdgcn_mfma_f32_16x16x32_bf16(al1, bh, c1, 0, 0, 0);
#pragma unroll
      for (int reg = 0; reg < 4; reg++) {
        const float d0 = fmaf(-2.f, c0[reg], qn8[reg] + knv);
        if (d0 <= tm8[reg]) {
          const int row = kgrp * 4 + reg;
          const int pos = atomicAdd(&cnt[row], 1);
          if (pos < K3CAND) candI[row][pos] = key;
        }
        const float d1 = fmaf(-2.f, c1[reg], qn8[reg + 4] + knv);
        if (d1 <= tm8[reg + 4]) {
          const int row = 16 + kgrp * 4 + reg;
          const int pos = atomicAdd(&cnt[row], 1);
          if (pos < K3CAND) candI[row][pos] = key;
        }
      }
    }
  }
  for (int idx = t; idx < 32 * KSEL; idx += 1024) { wV[idx >> 5][idx & 31] = 1e30f; wI[idx >> 5][idx & 31] = 0; }
  __syncthreads();

  // ---- phase 3: exact fp32 recompute of candidates (round-1 chain) ----
  {
    const int r = t >> 5, kt = t & 31;
    const int C = min(cnt[r], K3CAND);
    const float qnr = qns[r];
    for (int ci = kt; ci < C; ci += 32) {
      const int key = candI[r][ci];
      float kv[24];
#pragma unroll
      for (int d = 0; d < DM; d += 4) {
        const float4 v = *(const float4*)&keys[(size_t)key * DM + d];
        kv[d] = v.x; kv[d + 1] = v.y; kv[d + 2] = v.z; kv[d + 3] = v.w;
      }
      float dot = 0.f;
#pragma unroll
      for (int d = 0; d < DM; d++) dot = fmaf(kv[d], qsm[r][d], dot);
      const float d2 = fmaf(-2.f, dot, qnr + kn[key]);
      candV[r][ci] = __float_as_uint(fmaxf(d2, 0.f));
    }
  }
  __syncthreads();

  // ---- exact rank-select top-32 ----
  {
    const int r = t >> 5, kt = t & 31;
    const int C = min(cnt[r], K3CAND);
    for (int ci = kt; ci < C; ci += 32) {
      const unsigned v = candV[r][ci];
      const unsigned key = (unsigned)candI[r][ci];
      int rk = 0;
      for (int j = 0; j < C; j++) {
        const unsigned vj = candV[r][j];
        rk += (vj < v) || (vj == v && (unsigned)candI[r][j] < key);
      }
      if (rk < KSEL) { wV[r][rk] = __uint_as_float(v); wI[r][rk] = (int)key; }
    }
  }
  __syncthreads();

  // ---- softmax over -dist, gain (threads < 512: 32 rows x 16 lanes) ----
  float sc;
  {
    const float f0 = fw[0], f1 = fw[1], f2 = fw[2], f3 = fw[3];
    const float mx = fmaxf(fmaxf(f0, f1), fmaxf(f2, f3));
    const float e0 = expf(f0 - mx), e1 = expf(f1 - mx), e2 = expf(f2 - mx), e3 = expf(f3 - mx);
    sc = (e0 + 0.5f * e1 + 0.25f * e2 + 0.125f * e3) / (e0 + e1 + e2 + e3);
  }
  if (t < 512) {
    const int r = t >> 4, kt = t & 15;
    const float dA = sqrtf(wV[r][kt]) * sc;
    const float dB = sqrtf(wV[r][kt + 16]) * sc;
    float mn = fminf(dA, dB);
#pragma unroll
    for (int m = 1; m < 16; m <<= 1) mn = fminf(mn, __shfl_xor(mn, m, 16));
    const float eA = expf(mn - dA), eB = expf(mn - dB);
    float s = eA + eB;
#pragma unroll
    for (int m = 1; m < 16; m <<= 1) s += __shfl_xor(s, m, 16);
    const float w0 = eA / s, w1 = eB / s;
    const int k0 = wI[r][kt], k1 = wI[r][kt + 16];
    float gp = w0 * pm[k0] + w1 * pm[k1];
#pragma unroll
    for (int m = 1; m < 16; m <<= 1) gp += __shfl_xor(gp, m, 16);
    const size_t row = (size_t)(row0 + r);
    w_out[row * KSEL + kt] = w0;      w_out[row * KSEL + kt + 16] = w1;
    itop_out[row * KSEL + kt] = k0;   itop_out[row * KSEL + kt + 16] = k1;
    if (kt == 0) gain_out[row] = 1.f + 0.02f * gp;
  }
}

// ---------------------------------------------------------------------------
// K4: p = x@key_phase_W.T + b ; Kf = FFT(e^{i 2pi sigmoid(p)}) * e^{i ek}
// ---------------------------------------------------------------------------
__global__ __launch_bounds__(256) void k4_phase(
    const float* __restrict__ x, const float* __restrict__ Wp,
    const float* __restrict__ bp, const float* __restrict__ ek,
    float* __restrict__ kf_re, float* __restrict__ kf_im)
{
  __shared__ float xs[16][36];
  __shared__ float Ws[HN][36];
  __shared__ float sre[16][260];
  __shared__ float sim_[16][260];
  __shared__ float twc[HN], tws[HN];
  const int t = threadIdx.x;
  const int row0 = blockIdx.x * 16;
  {
    const float a = (float)t * (TWO_PI_F / 256.f);
    twc[t] = cosf(a); tws[t] = sinf(a);
  }
  const int r = t >> 4, cg = t & 15;
  float acc[16];
#pragma unroll
  for (int j = 0; j < 16; j++) acc[j] = bp[cg + 16 * j];

  for (int kc = 0; kc < 24; kc++) {
    __syncthreads();
    if (t < 128) {
      const int rr = t >> 3, kk = (t & 7) << 2;
      *(float4*)&xs[rr][kk] = *(const float4*)&x[(size_t)(row0 + rr) * INDIM + kc * 32 + kk];
    }
#pragma unroll
    for (int i = 0; i < 8; i++) {
      const int idx = t + 256 * i;
      const int rr = idx >> 3, kk = (idx & 7) << 2;
      *(float4*)&Ws[rr][kk] = *(const float4*)&Wp[(size_t)rr * INDIM + kc * 32 + kk];
    }
    __syncthreads();
#pragma unroll
    for (int kq = 0; kq < 8; kq++) {
      const float4 xv = *(const float4*)&xs[r][kq * 4];
#pragma unroll
      for (int j = 0; j < 16; j++) {
        const float4 wv = *(const float4*)&Ws[cg + 16 * j][kq * 4];
        acc[j] = fmaf(xv.x, wv.x, fmaf(xv.y, wv.y, fmaf(xv.z, wv.z, fmaf(xv.w, wv.w, acc[j]))));
      }
    }
  }
  __syncthreads();
#pragma unroll
  for (int j = 0; j < 16; j++) {
    const int c = cg + 16 * j;
    const float sg = 1.f / (1.f + expf(-acc[j]));
    float sn, cs;
    __sincosf(TWO_PI_F * sg, &sn, &cs);
    const int hb = __brev((unsigned)c) >> 24;
    sre[r][hb] = cs; sim_[r][hb] = sn;
  }
  __syncthreads();
  const int t16 = t & 15;
  for (int s = 0; s < 8; s++) {
    const int half = 1 << s;
#pragma unroll
    for (int p = 0; p < 8; p++) {
      const int bi = t16 + 16 * p;
      const int jj = bi & (half - 1);
      const int base = (bi >> s) << (s + 1);
      const int i0 = base + jj, i1 = i0 + half;
      const int tw = jj << (7 - s);
      const float wr = twc[tw], wi = -tws[tw];
      const float ar = sre[r][i0], ai = sim_[r][i0];
      const float br = sre[r][i1], b2 = sim_[r][i1];
      const float tr = wr * br - wi * b2, ti = wr * b2 + wi * br;
      sre[r][i0] = ar + tr; sim_[r][i0] = ai + ti;
      sre[r][i1] = ar - tr; sim_[r][i1] = ai - ti;
    }
    __syncthreads();
  }
#pragma unroll
  for (int p = 0; p < 16; p++) {
    const int h = t16 + 16 * p;
    float sn, cs;
    __sincosf(ek[h], &sn, &cs);
    const float xr = sre[r][h], xi = sim_[r][h];
    const size_t o = (size_t)(row0 + r) * HN + h;
    kf_re[o] = xr * cs - xi * sn;
    kf_im[o] = xr * sn + xi * cs;
  }
}

// ---------------------------------------------------------------------------
// K5: Hmix gather + conj(Kf)*Hmix ; IFFT-256 ; readout GEMM (512->72)
// ---------------------------------------------------------------------------
__global__ __launch_bounds__(256) void k5_holo(
    const float* __restrict__ holo_re, const float* __restrict__ holo_im,
    const float* __restrict__ kf_re, const float* __restrict__ kf_im,
    const float* __restrict__ w_ws, const int* __restrict__ itop_ws,
    const float* __restrict__ RW, const float* __restrict__ rb,
    float* __restrict__ triplet)
{
  __shared__ float wsm[16][KSEL];
  __shared__ int   ism[16][KSEL];
  __shared__ float sre[16][260];
  __shared__ float sim_[16][260];
  __shared__ float twc[HN], tws[HN];
  const int t = threadIdx.x;
  const int row0 = blockIdx.x * 16;
  {
    const float a = (float)t * (TWO_PI_F / 256.f);
    twc[t] = cosf(a); tws[t] = sinf(a);
  }
  for (int idx = t; idx < 16 * KSEL; idx += 256) {
    wsm[idx >> 5][idx & 31] = w_ws[(size_t)row0 * KSEL + idx];
    ism[idx >> 5][idx & 31] = itop_ws[(size_t)row0 * KSEL + idx];
  }
  __syncthreads();
  {
    const int h = t;
    const int hb = __brev((unsigned)h) >> 24;
    for (int r = 0; r < 16; r++) {
      float hr = 0.f, hi = 0.f;
#pragma unroll 8
      for (int k2 = 0; k2 < KSEL; k2++) {
        const int m = ism[r][k2];
        const float wk = wsm[r][k2];
        hr = fmaf(wk, holo_re[(size_t)m * HN + h], hr);
        hi = fmaf(wk, holo_im[(size_t)m * HN + h], hi);
      }
      const size_t o = (size_t)(row0 + r) * HN + h;
      const float kr = kf_re[o], ki = kf_im[o];
      sre[r][hb] = kr * hr + ki * hi;
      sim_[r][hb] = kr * hi - ki * hr;
    }
  }
  __syncthreads();
  const int r = t >> 4, t16 = t & 15;
  for (int s = 0; s < 8; s++) {
    const int half = 1 << s;
#pragma unroll
    for (int p = 0; p < 8; p++) {
      const int bi = t16 + 16 * p;
      const int jj = bi & (half - 1);
      const int base = (bi >> s) << (s + 1);
      const int i0 = base + jj, i1 = i0 + half;
      const int tw = jj << (7 - s);
      const float wr = twc[tw], wi = tws[tw];
      const float ar = sre[r][i0], ai = sim_[r][i0];
      const float br = sre[r][i1], b2 = sim_[r][i1];
      const float tr = wr * br - wi * b2, ti = wr * b2 + wi * br;
      sre[r][i0] = ar + tr; sim_[r][i0] = ai + ti;
      sre[r][i1] = ar - tr; sim_[r][i1] = ai - ti;
    }
    __syncthreads();
  }
  float dac[5] = {0.f, 0.f, 0.f, 0.f, 0.f};
  for (int h4 = 0; h4 < 256; h4 += 4) {
    const float4 vr = *(const float4*)&sre[r][h4];
#pragma unroll
    for (int u = 0; u < 5; u++) {
      const int o = t16 + 16 * u;
      if (o < TD) {
        const float4 wv = *(const float4*)&RW[(size_t)o * 512 + h4];
        dac[u] = fmaf(vr.x, wv.x, fmaf(vr.y, wv.y, fmaf(vr.z, wv.z, fmaf(vr.w, wv.w, dac[u]))));
      }
    }
  }
  for (int h4 = 0; h4 < 256; h4 += 4) {
    const float4 vi = *(const float4*)&sim_[r][h4];
#pragma unroll
    for (int u = 0; u < 5; u++) {
      const int o = t16 + 16 * u;
      if (o < TD) {
        const float4 wv = *(const float4*)&RW[(size_t)o * 512 + 256 + h4];
        dac[u] = fmaf(vi.x, wv.x, fmaf(vi.y, wv.y, fmaf(vi.z, wv.z, fmaf(vi.w, wv.w, dac[u]))));
      }
    }
  }
#pragma unroll
  for (int u = 0; u < 5; u++) {
    const int o = t16 + 16 * u;
    if (o < TD) triplet[(size_t)(row0 + r) * TD + o] = rb[o] + dac[u] * (1.f / 256.f);
  }
}

// ---------------------------------------------------------------------------
// K6: out = gelu(LN(triplet@W_out.T + b_out)) * gain
// ---------------------------------------------------------------------------
__global__ __launch_bounds__(256) void k6_out(
    const float* __restrict__ triplet, const float* __restrict__ Wo,
    const float* __restrict__ bo, const float* __restrict__ go,
    const float* __restrict__ bbo, const float* __restrict__ gain,
    float* __restrict__ out)
{
  __shared__ float ts[16][76];
  __shared__ float ys[16][772];
  const int t = threadIdx.x;
  const int row0 = blockIdx.x * 16;
  for (int idx = t; idx < 16 * TD; idx += 256) ts[idx / TD][idx % TD] = triplet[(size_t)row0 * TD + idx];
  __syncthreads();
  float acc[16][3];
#pragma unroll
  for (int rr = 0; rr < 16; rr++) { acc[rr][0] = 0.f; acc[rr][1] = 0.f; acc[rr][2] = 0.f; }
  for (int e = 0; e < TD; e++) {
    float wv[3];
#pragma unroll
    for (int j = 0; j < 3; j++) wv[j] = Wo[(size_t)(t + 256 * j) * TD + e];
#pragma unroll
    for (int rr = 0; rr < 16; rr++) {
      const float tv = ts[rr][e];
      acc[rr][0] = fmaf(tv, wv[0], acc[rr][0]);
      acc[rr][1] = fmaf(tv, wv[1], acc[rr][1]);
      acc[rr][2] = fmaf(tv, wv[2], acc[rr][2]);
    }
  }
  {
    const float b0 = bo[t], b1 = bo[t + 256], b2 = bo[t + 512];
#pragma unroll
    for (int rr = 0; rr < 16; rr++) {
      ys[rr][t] = acc[rr][0] + b0;
      ys[rr][t + 256] = acc[rr][1] + b1;
      ys[rr][t + 512] = acc[rr][2] + b2;
    }
  }
  __syncthreads();
  const int r = t >> 4, kt = t & 15;
  float s = 0.f, sq = 0.f;
  for (int u = 0; u < 48; u++) {
    const float v = ys[r][kt + 16 * u];
    s += v; sq = fmaf(v, v, sq);
  }
#pragma unroll
  for (int m = 1; m < 16; m <<= 1) { s += __shfl_xor(s, m, 16); sq += __shfl_xor(sq, m, 16); }
  const float mean = s * (1.f / 768.f);
  const float var  = sq * (1.f / 768.f) - mean * mean;
  const float rstd = rsqrtf(var + 1e-5f);
  const float gn = gain[row0 + r];
  for (int u = 0; u < 48; u++) {
    const int e = kt + 16 * u;
    const float v = (ys[r][e] - mean) * rstd * go[e] + bbo[e];
    out[(size_t)(row0 + r) * INDIM + e] = gelu_exact(v) * gn;
  }
}

// ---------------------------------------------------------------------------
extern "C" void kernel_launch(void* const* d_in, const int* in_sizes, int n_in,
                              void* d_out, int out_size, void* d_ws, size_t ws_size,
                              hipStream_t stream)
{
  (void)in_sizes; (void)n_in; (void)out_size; (void)ws_size;
  const float* x     = (const float*)d_in[0];
  const float* Wi    = (const float*)d_in[1];
  const float* bi    = (const float*)d_in[2];
  const float* gi    = (const float*)d_in[3];
  const float* bbi   = (const float*)d_in[4];
  const float* ricci = (const float*)d_in[5];
  const float* fw    = (const float*)d_in[6];
  const float* keys  = (const float*)d_in[7];
  const float* Wp    = (const float*)d_in[8];
  const float* bp    = (const float*)d_in[9];
  const float* ek    = (const float*)d_in[10];
  const float* hre   = (const float*)d_in[11];
  const float* him   = (const float*)d_in[12];
  const float* RW    = (const float*)d_in[13];
  const float* rb    = (const float*)d_in[14];
  const float* Wo    = (const float*)d_in[15];
  const float* bo    = (const float*)d_in[16];
  const float* go    = (const float*)d_in[17];
  const float* bbo   = (const float*)d_in[18];
  const float* qp    = (const float*)d_in[19];
  float* out = (float*)d_out;

  char* ws = (char*)d_ws;
  float* qvec    = (float*)(ws + 0);
  float* qnorm   = (float*)(ws + 786432);
  float* kn      = (float*)(ws + 819200);
  float* pm      = (float*)(ws + 851968);
  float* gain    = (float*)(ws + 884736);
  float* w_ws    = (float*)(ws + 917504);
  int*   itop    = (int*)  (ws + 1966080);
  float* triplet = (float*)(ws + 3014656);
  float* kf_re   = (float*)(ws + 5373952);
  float* kf_im   = (float*)(ws + 13762560);
  unsigned short* khi = (unsigned short*)(ws + 22151168);  // 8192*32*2 = 524288
  unsigned short* klo = (unsigned short*)(ws + 22675456);  // 524288
  float* kmx     = (float*)(ws + 23199744);                // 32 floats

  k1_encode<<<dim3(NROWS / 16), dim3(256), 0, stream>>>(x, Wi, bi, gi, bbi, ricci, qvec, qnorm);
  k2_prep<<<dim3(MKEYS / 256), dim3(256), 0, stream>>>(keys, qp, kn, pm, khi, klo, kmx);
  k4_phase<<<dim3(NROWS / 16), dim3(256), 0, stream>>>(x, Wp, bp, ek, kf_re, kf_im);
  k3_topk<<<dim3(NROWS / 32), dim3(1024), 0, stream>>>(qvec, qnorm, keys, kn, khi, klo, kmx, fw, pm, w_ws, itop, gain);
  k5_holo<<<dim3(NROWS / 16), dim3(256), 0, stream>>>(hre, him, kf_re, kf_im, w_ws, itop, RW, rb, triplet);
  k6_out<<<dim3(NROWS / 16), dim3(256), 0, stream>>>(triplet, Wo, bo, go, bbo, gain, out);
}

// Round 6
// 338.818 us; speedup vs baseline: 2.1840x; 1.3567x over previous
//
#include <hip/hip_runtime.h>
#include <hip/hip_bf16.h>
#include <math.h>

#define NROWS 8192
#define INDIM 768
#define TD    72
#define DM    24
#define MKEYS 8192
#define KSEL  32
#define HN    256
#define K3CAND 128

#define TWO_PI_F 6.283185307179586f

typedef __attribute__((ext_vector_type(8))) short short8_t;
typedef __attribute__((ext_vector_type(4))) float f32x4;

__device__ __forceinline__ float gelu_exact(float v){
  return 0.5f * v * (1.0f + erff(v * 0.7071067811865476f));
}

// round-to-nearest-even f32 -> bf16 bits
__device__ __forceinline__ unsigned short bf16rn(float f){
  unsigned u = __float_as_uint(f);
  unsigned r = u + 0x7FFFu + ((u >> 16) & 1u);
  return (unsigned short)(r >> 16);
}

// min across each 16-lane DPP row; lane 15 (mod 16) holds the row min.
__device__ __forceinline__ float rowmin16(float v){
  int s, p;
  s = __float_as_int(v); p = __builtin_amdgcn_update_dpp(s, s, 0x111, 0xF, 0xF, false);
  v = fminf(v, __int_as_float(p));
  s = __float_as_int(v); p = __builtin_amdgcn_update_dpp(s, s, 0x112, 0xF, 0xF, false);
  v = fminf(v, __int_as_float(p));
  s = __float_as_int(v); p = __builtin_amdgcn_update_dpp(s, s, 0x114, 0xF, 0xF, false);
  v = fminf(v, __int_as_float(p));
  s = __float_as_int(v); p = __builtin_amdgcn_update_dpp(s, s, 0x118, 0xF, 0xF, false);
  v = fminf(v, __int_as_float(p));
  return v;
}

// ---------------------------------------------------------------------------
// K0: G = FFT_256(RW[o][0:256] + i*RW[o][256:512]) for o in [0,128) (o>=72 -> 0),
// stored as panels Grp/Gip[(h4*128 + o)*4 + (h&3)] for coalesced k5 reads.
// triplet[o] = rb[o] + (1/256) * sum_h Yr[h]*Gr[o][h] + Yi[h]*Gi[o][h].
// ---------------------------------------------------------------------------
__global__ __launch_bounds__(256) void k0_gprep(
    const float* __restrict__ RW, float* __restrict__ Grp, float* __restrict__ Gip)
{
  __shared__ float sre[16][260];
  __shared__ float sim_[16][260];
  __shared__ float twc[HN], tws[HN];
  const int t = threadIdx.x;
  const int o0 = blockIdx.x * 16;
  {
    const float a = (float)t * (TWO_PI_F / 256.f);
    twc[t] = cosf(a); tws[t] = sinf(a);
  }
  const int r = t >> 4, cg = t & 15;
  const int o = o0 + r;
#pragma unroll
  for (int j = 0; j < 16; j++) {
    const int n = cg + 16 * j;
    const int hb = __brev((unsigned)n) >> 24;
    float cr = 0.f, ci = 0.f;
    if (o < TD) { cr = RW[(size_t)o * 512 + n]; ci = RW[(size_t)o * 512 + 256 + n]; }
    sre[r][hb] = cr; sim_[r][hb] = ci;
  }
  __syncthreads();
  const int t16 = t & 15;
  for (int s = 0; s < 8; s++) {
    const int half = 1 << s;
#pragma unroll
    for (int p = 0; p < 8; p++) {
      const int bi = t16 + 16 * p;
      const int jj = bi & (half - 1);
      const int base = (bi >> s) << (s + 1);
      const int i0 = base + jj, i1 = i0 + half;
      const int tw = jj << (7 - s);
      const float wr = twc[tw], wi = -tws[tw];   // forward FFT
      const float ar = sre[r][i0], ai = sim_[r][i0];
      const float br = sre[r][i1], b2 = sim_[r][i1];
      const float tr = wr * br - wi * b2, ti = wr * b2 + wi * br;
      sre[r][i0] = ar + tr; sim_[r][i0] = ai + ti;
      sre[r][i1] = ar - tr; sim_[r][i1] = ai - ti;
    }
    __syncthreads();
  }
#pragma unroll
  for (int p = 0; p < 16; p++) {
    const int h = t16 + 16 * p;
    const size_t base = ((size_t)(h >> 2) * 128 + o) * 4 + (h & 3);
    Grp[base] = sre[r][h];
    Gip[base] = sim_[r][h];
  }
}

// ---------------------------------------------------------------------------
// K1: y = x@W_in.T + b_in ; LN(72); GELU; ricci einsum + mean over 3 -> q(24)
// ---------------------------------------------------------------------------
__global__ __launch_bounds__(256) void k1_encode(
    const float* __restrict__ x, const float* __restrict__ Wi,
    const float* __restrict__ bi, const float* __restrict__ gi,
    const float* __restrict__ bbi, const float* __restrict__ ricci,
    float* __restrict__ qvec, float* __restrict__ qnorm)
{
  __shared__ float xs[16][132];
  __shared__ float Ws[TD][132];
  __shared__ float zs[16][73];
  __shared__ float zb[16][25];
  const int t = threadIdx.x;
  const int r2 = t >> 4, ks = (t >> 3) & 1, u = t & 7;
  const int row0 = blockIdx.x * 16;

  float acc[9];
#pragma unroll
  for (int j = 0; j < 9; j++) acc[j] = 0.f;

  for (int kc = 0; kc < 6; kc++) {
    __syncthreads();
#pragma unroll
    for (int i = 0; i < 2; i++) {
      int idx = t + 256 * i;
      int rr = idx >> 5, kk = (idx & 31) << 2;
      *(float4*)&xs[rr][kk] = *(const float4*)&x[(size_t)(row0 + rr) * INDIM + kc * 128 + kk];
    }
#pragma unroll
    for (int i = 0; i < 9; i++) {
      int idx = t + 256 * i;
      int rr = idx >> 5, kk = (idx & 31) << 2;
      *(float4*)&Ws[rr][kk] = *(const float4*)&Wi[(size_t)rr * INDIM + kc * 128 + kk];
    }
    __syncthreads();
    const int kb = ks * 64;
#pragma unroll 4
    for (int kq = 0; kq < 16; kq++) {
      const float4 xv = *(const float4*)&xs[r2][kb + kq * 4];
#pragma unroll
      for (int j = 0; j < 9; j++) {
        const float4 wv = *(const float4*)&Ws[u + 8 * j][kb + kq * 4];
        acc[j] = fmaf(xv.x, wv.x, fmaf(xv.y, wv.y, fmaf(xv.z, wv.z, fmaf(xv.w, wv.w, acc[j]))));
      }
    }
  }
#pragma unroll
  for (int j = 0; j < 9; j++) acc[j] += __shfl_xor(acc[j], 8);

  float yv[9];
  float ps = 0.f, pq = 0.f;
#pragma unroll
  for (int j = 0; j < 9; j++) {
    const int o = u + 8 * j;
    yv[j] = acc[j] + bi[o];
    ps += yv[j]; pq += yv[j] * yv[j];
  }
#pragma unroll
  for (int m = 1; m < 8; m <<= 1) { ps += __shfl_xor(ps, m); pq += __shfl_xor(pq, m); }
  const float mean = ps * (1.f / 72.f);
  const float var  = pq * (1.f / 72.f) - mean * mean;
  const float rstd = rsqrtf(var + 1e-5f);
#pragma unroll
  for (int j = 0; j < 9; j++) {
    const int o = u + 8 * j;
    const float z = gelu_exact((yv[j] - mean) * rstd * gi[o] + bbi[o]);
    if (ks == 0) zs[r2][o] = z;
  }
  __syncthreads();
  {
    const int kt = t & 15;
    for (int e = kt; e < 24; e += 16)
      zb[r2][e] = (zs[r2][3 * e] + zs[r2][3 * e + 1] + zs[r2][3 * e + 2]) * (1.f / 3.f);
  }
  __syncthreads();
  {
    const int kt = t & 15;
    float qnp = 0.f;
    for (int d = kt; d < 24; d += 16) {
      float qd = 0.f;
#pragma unroll
      for (int e = 0; e < 24; e++) qd = fmaf(zb[r2][e], ricci[e * 24 + d], qd);
      qvec[(size_t)(row0 + r2) * DM + d] = qd;
      qnp = fmaf(qd, qd, qnp);
    }
#pragma unroll
    for (int m = 1; m < 16; m <<= 1) qnp += __shfl_xor(qnp, m, 16);
    if (kt == 0) qnorm[row0 + r2] = qnp;
  }
}

// ---------------------------------------------------------------------------
// K2: key norms + quantum-phase means + bf16 hi/lo split keys + chunk kn-max
// ---------------------------------------------------------------------------
__global__ __launch_bounds__(256) void k2_prep(
    const float* __restrict__ keys, const float* __restrict__ qp,
    float* __restrict__ kn, float* __restrict__ pm,
    unsigned short* __restrict__ khi, unsigned short* __restrict__ klo,
    float* __restrict__ kmx)
{
  __shared__ float red[256];
  const int t = threadIdx.x;
  const int m = blockIdx.x * 256 + t;
  float kv[24];
#pragma unroll
  for (int d = 0; d < DM; d += 4) {
    const float4 v = *(const float4*)&keys[(size_t)m * DM + d];
    kv[d] = v.x; kv[d + 1] = v.y; kv[d + 2] = v.z; kv[d + 3] = v.w;
  }
  float s = 0.f;
#pragma unroll
  for (int d = 0; d < DM; d++) s = fmaf(kv[d], kv[d], s);   // same chain as before
  kn[m] = s;
  float p = 0.f;
#pragma unroll
  for (int q = 0; q < 8; q++) p += tanhf(qp[(size_t)m * 8 + q]);
  pm[m] = p * 0.125f;
  // hi/lo bf16 split, padded to 32
#pragma unroll
  for (int d = 0; d < DM; d++) {
    const unsigned short h = bf16rn(kv[d]);
    const float hf = __uint_as_float(((unsigned)h) << 16);
    const unsigned short l = bf16rn(kv[d] - hf);
    khi[(size_t)m * 32 + d] = h;
    klo[(size_t)m * 32 + d] = l;
  }
#pragma unroll
  for (int d = DM; d < 32; d++) { khi[(size_t)m * 32 + d] = 0; klo[(size_t)m * 32 + d] = 0; }
  // block max of kn
  red[t] = s;
  __syncthreads();
  for (int off = 128; off > 0; off >>= 1) {
    if (t < off) red[t] = fmaxf(red[t], red[t + off]);
    __syncthreads();
  }
  if (t == 0) kmx[blockIdx.x] = red[0];
}

// ---------------------------------------------------------------------------
// K3 v5: MFMA screening + exact fp32 finish. (unchanged from round 5)
// ---------------------------------------------------------------------------
__global__ __launch_bounds__(1024, 4) void k3_topk(
    const float* __restrict__ qvec, const float* __restrict__ qnorm,
    const float* __restrict__ keys, const float* __restrict__ kn,
    const unsigned short* __restrict__ khi, const unsigned short* __restrict__ klo,
    const float* __restrict__ kmx,
    const float* __restrict__ fw,  const float* __restrict__ pm,
    float* __restrict__ w_out, int* __restrict__ itop_out, float* __restrict__ gain_out)
{
  __shared__ float qsm[32][25];
  __shared__ float qns[32];
  __shared__ unsigned short qh_l[32][32];
  __shared__ unsigned short ql_l[32][32];
  __shared__ float gmins[64][33];
  __shared__ float Ts[32];
  __shared__ float Tm2s[32];
  __shared__ unsigned glive[2];
  __shared__ int cnt[32];
  __shared__ int      candI[32][K3CAND];
  __shared__ unsigned candV[32][K3CAND];
  __shared__ float wV[32][KSEL];
  __shared__ int   wI[32][KSEL];
  __shared__ float knmax_s;

  const int t = threadIdx.x;
  const int w = t >> 6, lane = t & 63;
  const int colid = lane & 15;
  const int kgrp  = lane >> 4;
  const int row0 = blockIdx.x * 32;

  if (t < 32 * DM) qsm[t / DM][t % DM] = qvec[(size_t)row0 * DM + t];
  if (t < 32) { qns[t] = qnorm[row0 + t]; cnt[t] = 0; }
  if (t < 2) glive[t] = 0u;
  if (t == 0) { float m = 0.f; for (int i = 0; i < 32; i++) m = fmaxf(m, kmx[i]); knmax_s = m; }
  __syncthreads();
  {
    const int r = t >> 5, k = t & 31;
    const float v = (k < DM) ? qsm[r][k] : 0.f;
    const unsigned short h = bf16rn(v);
    const float hf = __uint_as_float(((unsigned)h) << 16);
    qh_l[r][k] = h;
    ql_l[r][k] = bf16rn(v - hf);
  }
  __syncthreads();

  const short8_t ah0 = *(const short8_t*)&qh_l[colid][kgrp * 8];
  const short8_t al0 = *(const short8_t*)&ql_l[colid][kgrp * 8];
  const short8_t ah1 = *(const short8_t*)&qh_l[16 + colid][kgrp * 8];
  const short8_t al1 = *(const short8_t*)&ql_l[16 + colid][kgrp * 8];
  float qn8[8];
#pragma unroll
  for (int reg = 0; reg < 4; reg++) {
    qn8[reg]     = qns[kgrp * 4 + reg];
    qn8[reg + 4] = qns[16 + kgrp * 4 + reg];
  }

  for (int u = 0; u < 4; u++) {
    const int g = w + 16 * u;
    const int nbase = g * 128;
    float mn[8];
#pragma unroll
    for (int j = 0; j < 8; j++) {
      const int key = nbase + j * 16 + colid;
      const short8_t bh = *(const short8_t*)&khi[(size_t)key * 32 + kgrp * 8];
      const short8_t bl = *(const short8_t*)&klo[(size_t)key * 32 + kgrp * 8];
      const float knv = kn[key];
      f32x4 c0 = {0.f, 0.f, 0.f, 0.f}, c1 = {0.f, 0.f, 0.f, 0.f};
      c0 = __builtin_amdgcn_mfma_f32_16x16x32_bf16(ah0, bh, c0, 0, 0, 0);
      c1 = __builtin_amdgcn_mfma_f32_16x16x32_bf16(ah1, bh, c1, 0, 0, 0);
      c0 = __builtin_amdgcn_mfma_f32_16x16x32_bf16(ah0, bl, c0, 0, 0, 0);
      c1 = __builtin_amdgcn_mfma_f32_16x16x32_bf16(ah1, bl, c1, 0, 0, 0);
      c0 = __builtin_amdgcn_mfma_f32_16x16x32_bf16(al0, bh, c0, 0, 0, 0);
      c1 = __builtin_amdgcn_mfma_f32_16x16x32_bf16(al1, bh, c1, 0, 0, 0);
#pragma unroll
      for (int reg = 0; reg < 4; reg++) {
        const float d0 = fmaf(-2.f, c0[reg], qn8[reg] + knv);
        const float d1 = fmaf(-2.f, c1[reg], qn8[reg + 4] + knv);
        if (j == 0) { mn[reg] = d0; mn[reg + 4] = d1; }
        else        { mn[reg] = fminf(mn[reg], d0); mn[reg + 4] = fminf(mn[reg + 4], d1); }
      }
    }
#pragma unroll
    for (int reg = 0; reg < 4; reg++) {
      const float v0 = rowmin16(mn[reg]);
      const float v1 = rowmin16(mn[reg + 4]);
      if (colid == 15) {
        gmins[g][kgrp * 4 + reg] = v0;
        gmins[g][16 + kgrp * 4 + reg] = v1;
      }
    }
  }
  __syncthreads();

  {
    const int r = t & 31, i = t >> 5;
    const float v0 = gmins[i * 2][r], v1 = gmins[i * 2 + 1][r];
    int rk0 = 0, eq0 = 0, rk1 = 0, eq1 = 0;
    for (int g = 0; g < 64; g++) {
      const float gv = gmins[g][r];
      rk0 += (gv < v0); eq0 += (gv == v0);
      rk1 += (gv < v1); eq1 += (gv == v1);
    }
    if (rk0 <= 31 && rk0 + eq0 > 31) Ts[r] = v0;
    if (rk1 <= 31 && rk1 + eq1 > 31) Ts[r] = v1;
  }
  __syncthreads();
  if (t < 32) {
    const float T = Ts[t];
    const float mu = 2e-4f * sqrtf(fmaxf(qns[t], 0.f) * knmax_s) + 1e-6f;
    Tm2s[t] = T + fabsf(T) * 1e-6f + 2.f * mu;
  }
  __syncthreads();
  {
    const int r = t & 31, i = t >> 5;
    const unsigned b0 = (gmins[i * 2][r]     <= Tm2s[r]) ? 1u : 0u;
    const unsigned b1 = (gmins[i * 2 + 1][r] <= Tm2s[r]) ? 2u : 0u;
    const unsigned bits = (b0 | b1) << ((i * 2) & 31);
    if (bits) atomicOr(&glive[i >> 4], bits);
  }
  __syncthreads();

  float tm8[8];
#pragma unroll
  for (int reg = 0; reg < 4; reg++) {
    tm8[reg]     = Tm2s[kgrp * 4 + reg];
    tm8[reg + 4] = Tm2s[16 + kgrp * 4 + reg];
  }

  for (int u = 0; u < 4; u++) {
    const int g = w + 16 * u;
    if (!((glive[g >> 5] >> (g & 31)) & 1u)) continue;
    const int nbase = g * 128;
#pragma unroll
    for (int j = 0; j < 8; j++) {
      const int key = nbase + j * 16 + colid;
      const short8_t bh = *(const short8_t*)&khi[(size_t)key * 32 + kgrp * 8];
      const short8_t bl = *(const short8_t*)&klo[(size_t)key * 32 + kgrp * 8];
      const float knv = kn[key];
      f32x4 c0 = {0.f, 0.f, 0.f, 0.f}, c1 = {0.f, 0.f, 0.f, 0.f};
      c0 = __builtin_amdgcn_mfma_f32_16x16x32_bf16(ah0, bh, c0, 0, 0, 0);
      c1 = __builtin_amdgcn_mfma_f32_16x16x32_bf16(ah1, bh, c1, 0, 0, 0);
      c0 = __builtin_amdgcn_mfma_f32_16x16x32_bf16(ah0, bl, c0, 0, 0, 0);
      c1 = __builtin_amdgcn_mfma_f32_16x16x32_bf16(ah1, bl, c1, 0, 0, 0);
      c0 = __builtin_amdgcn_mfma_f32_16x16x32_bf16(al0, bh, c0, 0, 0, 0);
      c1 = __builtin_amdgcn_mfma_f32_16x16x32_bf16(al1, bh, c1, 0, 0, 0);
#pragma unroll
      for (int reg = 0; reg < 4; reg++) {
        const float d0 = fmaf(-2.f, c0[reg], qn8[reg] + knv);
        if (d0 <= tm8[reg]) {
          const int row = kgrp * 4 + reg;
          const int pos = atomicAdd(&cnt[row], 1);
          if (pos < K3CAND) candI[row][pos] = key;
        }
        const float d1 = fmaf(-2.f, c1[reg], qn8[reg + 4] + knv);
        if (d1 <= tm8[reg + 4]) {
          const int row = 16 + kgrp * 4 + reg;
          const int pos = atomicAdd(&cnt[row], 1);
          if (pos < K3CAND) candI[row][pos] = key;
        }
      }
    }
  }
  for (int idx = t; idx < 32 * KSEL; idx += 1024) { wV[idx >> 5][idx & 31] = 1e30f; wI[idx >> 5][idx & 31] = 0; }
  __syncthreads();

  {
    const int r = t >> 5, kt = t & 31;
    const int C = min(cnt[r], K3CAND);
    const float qnr = qns[r];
    for (int ci = kt; ci < C; ci += 32) {
      const int key = candI[r][ci];
      float kv[24];
#pragma unroll
      for (int d = 0; d < DM; d += 4) {
        const float4 v = *(const float4*)&keys[(size_t)key * DM + d];
        kv[d] = v.x; kv[d + 1] = v.y; kv[d + 2] = v.z; kv[d + 3] = v.w;
      }
      float dot = 0.f;
#pragma unroll
      for (int d = 0; d < DM; d++) dot = fmaf(kv[d], qsm[r][d], dot);
      const float d2 = fmaf(-2.f, dot, qnr + kn[key]);
      candV[r][ci] = __float_as_uint(fmaxf(d2, 0.f));
    }
  }
  __syncthreads();

  {
    const int r = t >> 5, kt = t & 31;
    const int C = min(cnt[r], K3CAND);
    for (int ci = kt; ci < C; ci += 32) {
      const unsigned v = candV[r][ci];
      const unsigned key = (unsigned)candI[r][ci];
      int rk = 0;
      for (int j = 0; j < C; j++) {
        const unsigned vj = candV[r][j];
        rk += (vj < v) || (vj == v && (unsigned)candI[r][j] < key);
      }
      if (rk < KSEL) { wV[r][rk] = __uint_as_float(v); wI[r][rk] = (int)key; }
    }
  }
  __syncthreads();

  float sc;
  {
    const float f0 = fw[0], f1 = fw[1], f2 = fw[2], f3 = fw[3];
    const float mx = fmaxf(fmaxf(f0, f1), fmaxf(f2, f3));
    const float e0 = expf(f0 - mx), e1 = expf(f1 - mx), e2 = expf(f2 - mx), e3 = expf(f3 - mx);
    sc = (e0 + 0.5f * e1 + 0.25f * e2 + 0.125f * e3) / (e0 + e1 + e2 + e3);
  }
  if (t < 512) {
    const int r = t >> 4, kt = t & 15;
    const float dA = sqrtf(wV[r][kt]) * sc;
    const float dB = sqrtf(wV[r][kt + 16]) * sc;
    float mn = fminf(dA, dB);
#pragma unroll
    for (int m = 1; m < 16; m <<= 1) mn = fminf(mn, __shfl_xor(mn, m, 16));
    const float eA = expf(mn - dA), eB = expf(mn - dB);
    float s = eA + eB;
#pragma unroll
    for (int m = 1; m < 16; m <<= 1) s += __shfl_xor(s, m, 16);
    const float w0 = eA / s, w1 = eB / s;
    const int k0 = wI[r][kt], k1 = wI[r][kt + 16];
    float gp = w0 * pm[k0] + w1 * pm[k1];
#pragma unroll
    for (int m = 1; m < 16; m <<= 1) gp += __shfl_xor(gp, m, 16);
    const size_t row = (size_t)(row0 + r);
    w_out[row * KSEL + kt] = w0;      w_out[row * KSEL + kt + 16] = w1;
    itop_out[row * KSEL + kt] = k0;   itop_out[row * KSEL + kt + 16] = k1;
    if (kt == 0) gain_out[row] = 1.f + 0.02f * gp;
  }
}

// ---------------------------------------------------------------------------
// K4: p = x@key_phase_W.T + b ; Kf = FFT(e^{i 2pi sigmoid(p)}) * e^{i ek}
// ---------------------------------------------------------------------------
__global__ __launch_bounds__(256) void k4_phase(
    const float* __restrict__ x, const float* __restrict__ Wp,
    const float* __restrict__ bp, const float* __restrict__ ek,
    float* __restrict__ kf_re, float* __restrict__ kf_im)
{
  __shared__ float xs[16][36];
  __shared__ float Ws[HN][36];
  __shared__ float sre[16][260];
  __shared__ float sim_[16][260];
  __shared__ float twc[HN], tws[HN];
  const int t = threadIdx.x;
  const int row0 = blockIdx.x * 16;
  {
    const float a = (float)t * (TWO_PI_F / 256.f);
    twc[t] = cosf(a); tws[t] = sinf(a);
  }
  const int r = t >> 4, cg = t & 15;
  float acc[16];
#pragma unroll
  for (int j = 0; j < 16; j++) acc[j] = bp[cg + 16 * j];

  for (int kc = 0; kc < 24; kc++) {
    __syncthreads();
    if (t < 128) {
      const int rr = t >> 3, kk = (t & 7) << 2;
      *(float4*)&xs[rr][kk] = *(const float4*)&x[(size_t)(row0 + rr) * INDIM + kc * 32 + kk];
    }
#pragma unroll
    for (int i = 0; i < 8; i++) {
      const int idx = t + 256 * i;
      const int rr = idx >> 3, kk = (idx & 7) << 2;
      *(float4*)&Ws[rr][kk] = *(const float4*)&Wp[(size_t)rr * INDIM + kc * 32 + kk];
    }
    __syncthreads();
#pragma unroll
    for (int kq = 0; kq < 8; kq++) {
      const float4 xv = *(const float4*)&xs[r][kq * 4];
#pragma unroll
      for (int j = 0; j < 16; j++) {
        const float4 wv = *(const float4*)&Ws[cg + 16 * j][kq * 4];
        acc[j] = fmaf(xv.x, wv.x, fmaf(xv.y, wv.y, fmaf(xv.z, wv.z, fmaf(xv.w, wv.w, acc[j]))));
      }
    }
  }
  __syncthreads();
#pragma unroll
  for (int j = 0; j < 16; j++) {
    const int c = cg + 16 * j;
    const float sg = 1.f / (1.f + expf(-acc[j]));
    float sn, cs;
    __sincosf(TWO_PI_F * sg, &sn, &cs);
    const int hb = __brev((unsigned)c) >> 24;
    sre[r][hb] = cs; sim_[r][hb] = sn;
  }
  __syncthreads();
  const int t16 = t & 15;
  for (int s = 0; s < 8; s++) {
    const int half = 1 << s;
#pragma unroll
    for (int p = 0; p < 8; p++) {
      const int bi = t16 + 16 * p;
      const int jj = bi & (half - 1);
      const int base = (bi >> s) << (s + 1);
      const int i0 = base + jj, i1 = i0 + half;
      const int tw = jj << (7 - s);
      const float wr = twc[tw], wi = -tws[tw];
      const float ar = sre[r][i0], ai = sim_[r][i0];
      const float br = sre[r][i1], b2 = sim_[r][i1];
      const float tr = wr * br - wi * b2, ti = wr * b2 + wi * br;
      sre[r][i0] = ar + tr; sim_[r][i0] = ai + ti;
      sre[r][i1] = ar - tr; sim_[r][i1] = ai - ti;
    }
    __syncthreads();
  }
#pragma unroll
  for (int p = 0; p < 16; p++) {
    const int h = t16 + 16 * p;
    float sn, cs;
    __sincosf(ek[h], &sn, &cs);
    const float xr = sre[r][h], xi = sim_[r][h];
    const size_t o = (size_t)(row0 + r) * HN + h;
    kf_re[o] = xr * cs - xi * sn;
    kf_im[o] = xr * sn + xi * cs;
  }
}

// ---------------------------------------------------------------------------
// K5 v2: gather + Y = conj(Kf)*Hmix, then triplet = rb + (Y . G)/256.
// No IFFT (folded into precomputed G panels). 8 rows/block, grid 1024,
// float4 gather loads, conflict-free LDS, h-split readout with G panel
// read exactly once per block, cross-wave LDS reduction.
// ---------------------------------------------------------------------------
__global__ __launch_bounds__(256) void k5_holo(
    const float* __restrict__ holo_re, const float* __restrict__ holo_im,
    const float* __restrict__ kf_re, const float* __restrict__ kf_im,
    const float* __restrict__ w_ws, const int* __restrict__ itop_ws,
    const float* __restrict__ Grp, const float* __restrict__ Gip,
    const float* __restrict__ rb, float* __restrict__ triplet)
{
  __shared__ __align__(16) float ysr[8][260];
  __shared__ __align__(16) float ysi[8][260];
  __shared__ float red[4][8][128];
  __shared__ float wsm[8][KSEL];
  __shared__ int   ism[8][KSEL];
  const int t = threadIdx.x;
  const int w = t >> 6, lane = t & 63;
  const int row0 = blockIdx.x * 8;

  {
    const int rr = t >> 5, k2 = t & 31;
    wsm[rr][k2] = w_ws[(size_t)(row0 + rr) * KSEL + k2];
    ism[rr][k2] = itop_ws[(size_t)(row0 + rr) * KSEL + k2];
  }
  __syncthreads();

  // ---- gather Hmix + Y, per wave: rows w and w+4; lane covers h = 4*lane..+3
#pragma unroll
  for (int pass = 0; pass < 2; pass++) {
    const int row = w + 4 * pass;
    float4 hr4 = {0.f, 0.f, 0.f, 0.f};
    float4 hi4 = {0.f, 0.f, 0.f, 0.f};
#pragma unroll 8
    for (int k2 = 0; k2 < KSEL; k2++) {
      const int m = ism[row][k2];
      const float wk = wsm[row][k2];
      const float4 re4 = *(const float4*)&holo_re[(size_t)m * HN + lane * 4];
      const float4 im4 = *(const float4*)&holo_im[(size_t)m * HN + lane * 4];
      hr4.x = fmaf(wk, re4.x, hr4.x); hr4.y = fmaf(wk, re4.y, hr4.y);
      hr4.z = fmaf(wk, re4.z, hr4.z); hr4.w = fmaf(wk, re4.w, hr4.w);
      hi4.x = fmaf(wk, im4.x, hi4.x); hi4.y = fmaf(wk, im4.y, hi4.y);
      hi4.z = fmaf(wk, im4.z, hi4.z); hi4.w = fmaf(wk, im4.w, hi4.w);
    }
    const size_t o = (size_t)(row0 + row) * HN + lane * 4;
    const float4 kr4 = *(const float4*)&kf_re[o];
    const float4 ki4 = *(const float4*)&kf_im[o];
    float4 yr4, yi4;
    yr4.x = kr4.x * hr4.x + ki4.x * hi4.x;  yi4.x = kr4.x * hi4.x - ki4.x * hr4.x;
    yr4.y = kr4.y * hr4.y + ki4.y * hi4.y;  yi4.y = kr4.y * hi4.y - ki4.y * hr4.y;
    yr4.z = kr4.z * hr4.z + ki4.z * hi4.z;  yi4.z = kr4.z * hi4.z - ki4.z * hr4.z;
    yr4.w = kr4.w * hr4.w + ki4.w * hi4.w;  yi4.w = kr4.w * hi4.w - ki4.w * hr4.w;
    *(float4*)&ysr[row][lane * 4] = yr4;
    *(float4*)&ysi[row][lane * 4] = yi4;
  }
  __syncthreads();

  // ---- readout partials: wave w handles h4 in [w*16, w*16+16); o = lane, 64+lane
  float acc[8][2];
#pragma unroll
  for (int rr = 0; rr < 8; rr++) { acc[rr][0] = 0.f; acc[rr][1] = 0.f; }
#pragma unroll 4
  for (int i = 0; i < 16; i++) {
    const int h4 = w * 16 + i;
    const float4 gra = *(const float4*)&Grp[((size_t)h4 * 128 + lane) * 4];
    const float4 gia = *(const float4*)&Gip[((size_t)h4 * 128 + lane) * 4];
    const float4 grb = *(const float4*)&Grp[((size_t)h4 * 128 + 64 + lane) * 4];
    const float4 gib = *(const float4*)&Gip[((size_t)h4 * 128 + 64 + lane) * 4];
#pragma unroll
    for (int rr = 0; rr < 8; rr++) {
      const float4 yr4 = *(const float4*)&ysr[rr][h4 * 4];
      const float4 yi4 = *(const float4*)&ysi[rr][h4 * 4];
      acc[rr][0] = fmaf(yr4.x, gra.x, fmaf(yr4.y, gra.y, fmaf(yr4.z, gra.z, fmaf(yr4.w, gra.w, acc[rr][0]))));
      acc[rr][0] = fmaf(yi4.x, gia.x, fmaf(yi4.y, gia.y, fmaf(yi4.z, gia.z, fmaf(yi4.w, gia.w, acc[rr][0]))));
      acc[rr][1] = fmaf(yr4.x, grb.x, fmaf(yr4.y, grb.y, fmaf(yr4.z, grb.z, fmaf(yr4.w, grb.w, acc[rr][1]))));
      acc[rr][1] = fmaf(yi4.x, gib.x, fmaf(yi4.y, gib.y, fmaf(yi4.z, gib.z, fmaf(yi4.w, gib.w, acc[rr][1]))));
    }
  }
#pragma unroll
  for (int rr = 0; rr < 8; rr++) {
    red[w][rr][lane] = acc[rr][0];
    red[w][rr][64 + lane] = acc[rr][1];
  }
  __syncthreads();

  // ---- cross-wave reduce + store
  for (int idx = t; idx < 8 * 128; idx += 256) {
    const int rr = idx >> 7, o = idx & 127;
    if (o < TD) {
      const float s = red[0][rr][o] + red[1][rr][o] + red[2][rr][o] + red[3][rr][o];
      triplet[(size_t)(row0 + rr) * TD + o] = rb[o] + s * (1.f / 256.f);
    }
  }
}

// ---------------------------------------------------------------------------
// K6: out = gelu(LN(triplet@W_out.T + b_out)) * gain
// ---------------------------------------------------------------------------
__global__ __launch_bounds__(256) void k6_out(
    const float* __restrict__ triplet, const float* __restrict__ Wo,
    const float* __restrict__ bo, const float* __restrict__ go,
    const float* __restrict__ bbo, const float* __restrict__ gain,
    float* __restrict__ out)
{
  __shared__ float ts[16][76];
  __shared__ float ys[16][772];
  const int t = threadIdx.x;
  const int row0 = blockIdx.x * 16;
  for (int idx = t; idx < 16 * TD; idx += 256) ts[idx / TD][idx % TD] = triplet[(size_t)row0 * TD + idx];
  __syncthreads();
  float acc[16][3];
#pragma unroll
  for (int rr = 0; rr < 16; rr++) { acc[rr][0] = 0.f; acc[rr][1] = 0.f; acc[rr][2] = 0.f; }
  for (int e = 0; e < TD; e++) {
    float wv[3];
#pragma unroll
    for (int j = 0; j < 3; j++) wv[j] = Wo[(size_t)(t + 256 * j) * TD + e];
#pragma unroll
    for (int rr = 0; rr < 16; rr++) {
      const float tv = ts[rr][e];
      acc[rr][0] = fmaf(tv, wv[0], acc[rr][0]);
      acc[rr][1] = fmaf(tv, wv[1], acc[rr][1]);
      acc[rr][2] = fmaf(tv, wv[2], acc[rr][2]);
    }
  }
  {
    const float b0 = bo[t], b1 = bo[t + 256], b2 = bo[t + 512];
#pragma unroll
    for (int rr = 0; rr < 16; rr++) {
      ys[rr][t] = acc[rr][0] + b0;
      ys[rr][t + 256] = acc[rr][1] + b1;
      ys[rr][t + 512] = acc[rr][2] + b2;
    }
  }
  __syncthreads();
  const int r = t >> 4, kt = t & 15;
  float s = 0.f, sq = 0.f;
  for (int u = 0; u < 48; u++) {
    const float v = ys[r][kt + 16 * u];
    s += v; sq = fmaf(v, v, sq);
  }
#pragma unroll
  for (int m = 1; m < 16; m <<= 1) { s += __shfl_xor(s, m, 16); sq += __shfl_xor(sq, m, 16); }
  const float mean = s * (1.f / 768.f);
  const float var  = sq * (1.f / 768.f) - mean * mean;
  const float rstd = rsqrtf(var + 1e-5f);
  const float gn = gain[row0 + r];
  for (int u = 0; u < 48; u++) {
    const int e = kt + 16 * u;
    const float v = (ys[r][e] - mean) * rstd * go[e] + bbo[e];
    out[(size_t)(row0 + r) * INDIM + e] = gelu_exact(v) * gn;
  }
}

// ---------------------------------------------------------------------------
extern "C" void kernel_launch(void* const* d_in, const int* in_sizes, int n_in,
                              void* d_out, int out_size, void* d_ws, size_t ws_size,
                              hipStream_t stream)
{
  (void)in_sizes; (void)n_in; (void)out_size; (void)ws_size;
  const float* x     = (const float*)d_in[0];
  const float* Wi    = (const float*)d_in[1];
  const float* bi    = (const float*)d_in[2];
  const float* gi    = (const float*)d_in[3];
  const float* bbi   = (const float*)d_in[4];
  const float* ricci = (const float*)d_in[5];
  const float* fw    = (const float*)d_in[6];
  const float* keys  = (const float*)d_in[7];
  const float* Wp    = (const float*)d_in[8];
  const float* bp    = (const float*)d_in[9];
  const float* ek    = (const float*)d_in[10];
  const float* hre   = (const float*)d_in[11];
  const float* him   = (const float*)d_in[12];
  const float* RW    = (const float*)d_in[13];
  const float* rb    = (const float*)d_in[14];
  const float* Wo    = (const float*)d_in[15];
  const float* bo    = (const float*)d_in[16];
  const float* go    = (const float*)d_in[17];
  const float* bbo   = (const float*)d_in[18];
  const float* qp    = (const float*)d_in[19];
  float* out = (float*)d_out;

  char* ws = (char*)d_ws;
  float* qvec    = (float*)(ws + 0);
  float* qnorm   = (float*)(ws + 786432);
  float* kn      = (float*)(ws + 819200);
  float* pm      = (float*)(ws + 851968);
  float* gain    = (float*)(ws + 884736);
  float* w_ws    = (float*)(ws + 917504);
  int*   itop    = (int*)  (ws + 1966080);
  float* triplet = (float*)(ws + 3014656);
  float* kf_re   = (float*)(ws + 5373952);
  float* kf_im   = (float*)(ws + 13762560);
  unsigned short* khi = (unsigned short*)(ws + 22151168);  // 524288
  unsigned short* klo = (unsigned short*)(ws + 22675456);  // 524288
  float* kmx     = (float*)(ws + 23199744);                // 128 B
  float* Grp     = (float*)(ws + 23200768);                // 131072
  float* Gip     = (float*)(ws + 23331840);                // 131072

  k0_gprep<<<dim3(8), dim3(256), 0, stream>>>(RW, Grp, Gip);
  k1_encode<<<dim3(NROWS / 16), dim3(256), 0, stream>>>(x, Wi, bi, gi, bbi, ricci, qvec, qnorm);
  k2_prep<<<dim3(MKEYS / 256), dim3(256), 0, stream>>>(keys, qp, kn, pm, khi, klo, kmx);
  k4_phase<<<dim3(NROWS / 16), dim3(256), 0, stream>>>(x, Wp, bp, ek, kf_re, kf_im);
  k3_topk<<<dim3(NROWS / 32), dim3(1024), 0, stream>>>(qvec, qnorm, keys, kn, khi, klo, kmx, fw, pm, w_ws, itop, gain);
  k5_holo<<<dim3(NROWS / 8), dim3(256), 0, stream>>>(hre, him, kf_re, kf_im, w_ws, itop, Grp, Gip, rb, triplet);
  k6_out<<<dim3(NROWS / 16), dim3(256), 0, stream>>>(triplet, Wo, bo, go, bbo, gain, out);
}

// Round 7
// 309.323 us; speedup vs baseline: 2.3922x; 1.0954x over previous
//
#include <hip/hip_runtime.h>
#include <hip/hip_bf16.h>
#include <math.h>

#define NROWS 8192
#define INDIM 768
#define TD    72
#define DM    24
#define MKEYS 8192
#define KSEL  32
#define HN    256
#define K3CAND 128

#define TWO_PI_F 6.283185307179586f

typedef __attribute__((ext_vector_type(8))) short short8_t;
typedef __attribute__((ext_vector_type(4))) float f32x4;

__device__ __forceinline__ float gelu_exact(float v){
  return 0.5f * v * (1.0f + erff(v * 0.7071067811865476f));
}

// round-to-nearest-even f32 -> bf16 bits
__device__ __forceinline__ unsigned short bf16rn(float f){
  unsigned u = __float_as_uint(f);
  unsigned r = u + 0x7FFFu + ((u >> 16) & 1u);
  return (unsigned short)(r >> 16);
}

// min across each 16-lane DPP row; lane 15 (mod 16) holds the row min.
__device__ __forceinline__ float rowmin16(float v){
  int s, p;
  s = __float_as_int(v); p = __builtin_amdgcn_update_dpp(s, s, 0x111, 0xF, 0xF, false);
  v = fminf(v, __int_as_float(p));
  s = __float_as_int(v); p = __builtin_amdgcn_update_dpp(s, s, 0x112, 0xF, 0xF, false);
  v = fminf(v, __int_as_float(p));
  s = __float_as_int(v); p = __builtin_amdgcn_update_dpp(s, s, 0x114, 0xF, 0xF, false);
  v = fminf(v, __int_as_float(p));
  s = __float_as_int(v); p = __builtin_amdgcn_update_dpp(s, s, 0x118, 0xF, 0xF, false);
  v = fminf(v, __int_as_float(p));
  return v;
}

// ---------------------------------------------------------------------------
// K0: G = FFT_256(RW[o][0:256] + i*RW[o][256:512]) for o in [0,128) (o>=72 -> 0),
// stored as panels Grp/Gip[(h4*128 + o)*4 + (h&3)] for coalesced k5 reads.
// ---------------------------------------------------------------------------
__global__ __launch_bounds__(256) void k0_gprep(
    const float* __restrict__ RW, float* __restrict__ Grp, float* __restrict__ Gip)
{
  __shared__ float sre[16][260];
  __shared__ float sim_[16][260];
  __shared__ float twc[HN], tws[HN];
  const int t = threadIdx.x;
  const int o0 = blockIdx.x * 16;
  {
    const float a = (float)t * (TWO_PI_F / 256.f);
    twc[t] = cosf(a); tws[t] = sinf(a);
  }
  const int r = t >> 4, cg = t & 15;
  const int o = o0 + r;
#pragma unroll
  for (int j = 0; j < 16; j++) {
    const int n = cg + 16 * j;
    const int hb = __brev((unsigned)n) >> 24;
    float cr = 0.f, ci = 0.f;
    if (o < TD) { cr = RW[(size_t)o * 512 + n]; ci = RW[(size_t)o * 512 + 256 + n]; }
    sre[r][hb] = cr; sim_[r][hb] = ci;
  }
  __syncthreads();
  const int t16 = t & 15;
  for (int s = 0; s < 8; s++) {
    const int half = 1 << s;
#pragma unroll
    for (int p = 0; p < 8; p++) {
      const int bi = t16 + 16 * p;
      const int jj = bi & (half - 1);
      const int base = (bi >> s) << (s + 1);
      const int i0 = base + jj, i1 = i0 + half;
      const int tw = jj << (7 - s);
      const float wr = twc[tw], wi = -tws[tw];
      const float ar = sre[r][i0], ai = sim_[r][i0];
      const float br = sre[r][i1], b2 = sim_[r][i1];
      const float tr = wr * br - wi * b2, ti = wr * b2 + wi * br;
      sre[r][i0] = ar + tr; sim_[r][i0] = ai + ti;
      sre[r][i1] = ar - tr; sim_[r][i1] = ai - ti;
    }
    __syncthreads();
  }
#pragma unroll
  for (int p = 0; p < 16; p++) {
    const int h = t16 + 16 * p;
    const size_t base = ((size_t)(h >> 2) * 128 + o) * 4 + (h & 3);
    Grp[base] = sre[r][h];
    Gip[base] = sim_[r][h];
  }
}

// ---------------------------------------------------------------------------
// KW: split key_phase_W (256x768) into bf16 hi/lo panels.
// ---------------------------------------------------------------------------
__global__ __launch_bounds__(256) void kw_split(
    const float* __restrict__ Wp, unsigned short* __restrict__ Wphi,
    unsigned short* __restrict__ Wplo)
{
  const int i4 = blockIdx.x * 256 + threadIdx.x;   // 49152 float4s
  const float4 v = ((const float4*)Wp)[i4];
  float vv[4] = {v.x, v.y, v.z, v.w};
  ushort4 hh, ll;
  unsigned short* hp = (unsigned short*)&hh;
  unsigned short* lp = (unsigned short*)&ll;
#pragma unroll
  for (int j = 0; j < 4; j++) {
    const unsigned short h = bf16rn(vv[j]);
    const float hf = __uint_as_float(((unsigned)h) << 16);
    hp[j] = h; lp[j] = bf16rn(vv[j] - hf);
  }
  ((ushort4*)Wphi)[i4] = hh;
  ((ushort4*)Wplo)[i4] = ll;
}

// ---------------------------------------------------------------------------
// K1: y = x@W_in.T + b_in ; LN(72); GELU; ricci einsum + mean over 3 -> q(24)
// ---------------------------------------------------------------------------
__global__ __launch_bounds__(256) void k1_encode(
    const float* __restrict__ x, const float* __restrict__ Wi,
    const float* __restrict__ bi, const float* __restrict__ gi,
    const float* __restrict__ bbi, const float* __restrict__ ricci,
    float* __restrict__ qvec, float* __restrict__ qnorm)
{
  __shared__ float xs[16][132];
  __shared__ float Ws[TD][132];
  __shared__ float zs[16][73];
  __shared__ float zb[16][25];
  const int t = threadIdx.x;
  const int r2 = t >> 4, ks = (t >> 3) & 1, u = t & 7;
  const int row0 = blockIdx.x * 16;

  float acc[9];
#pragma unroll
  for (int j = 0; j < 9; j++) acc[j] = 0.f;

  for (int kc = 0; kc < 6; kc++) {
    __syncthreads();
#pragma unroll
    for (int i = 0; i < 2; i++) {
      int idx = t + 256 * i;
      int rr = idx >> 5, kk = (idx & 31) << 2;
      *(float4*)&xs[rr][kk] = *(const float4*)&x[(size_t)(row0 + rr) * INDIM + kc * 128 + kk];
    }
#pragma unroll
    for (int i = 0; i < 9; i++) {
      int idx = t + 256 * i;
      int rr = idx >> 5, kk = (idx & 31) << 2;
      *(float4*)&Ws[rr][kk] = *(const float4*)&Wi[(size_t)rr * INDIM + kc * 128 + kk];
    }
    __syncthreads();
    const int kb = ks * 64;
#pragma unroll 4
    for (int kq = 0; kq < 16; kq++) {
      const float4 xv = *(const float4*)&xs[r2][kb + kq * 4];
#pragma unroll
      for (int j = 0; j < 9; j++) {
        const float4 wv = *(const float4*)&Ws[u + 8 * j][kb + kq * 4];
        acc[j] = fmaf(xv.x, wv.x, fmaf(xv.y, wv.y, fmaf(xv.z, wv.z, fmaf(xv.w, wv.w, acc[j]))));
      }
    }
  }
#pragma unroll
  for (int j = 0; j < 9; j++) acc[j] += __shfl_xor(acc[j], 8);

  float yv[9];
  float ps = 0.f, pq = 0.f;
#pragma unroll
  for (int j = 0; j < 9; j++) {
    const int o = u + 8 * j;
    yv[j] = acc[j] + bi[o];
    ps += yv[j]; pq += yv[j] * yv[j];
  }
#pragma unroll
  for (int m = 1; m < 8; m <<= 1) { ps += __shfl_xor(ps, m); pq += __shfl_xor(pq, m); }
  const float mean = ps * (1.f / 72.f);
  const float var  = pq * (1.f / 72.f) - mean * mean;
  const float rstd = rsqrtf(var + 1e-5f);
#pragma unroll
  for (int j = 0; j < 9; j++) {
    const int o = u + 8 * j;
    const float z = gelu_exact((yv[j] - mean) * rstd * gi[o] + bbi[o]);
    if (ks == 0) zs[r2][o] = z;
  }
  __syncthreads();
  {
    const int kt = t & 15;
    for (int e = kt; e < 24; e += 16)
      zb[r2][e] = (zs[r2][3 * e] + zs[r2][3 * e + 1] + zs[r2][3 * e + 2]) * (1.f / 3.f);
  }
  __syncthreads();
  {
    const int kt = t & 15;
    float qnp = 0.f;
    for (int d = kt; d < 24; d += 16) {
      float qd = 0.f;
#pragma unroll
      for (int e = 0; e < 24; e++) qd = fmaf(zb[r2][e], ricci[e * 24 + d], qd);
      qvec[(size_t)(row0 + r2) * DM + d] = qd;
      qnp = fmaf(qd, qd, qnp);
    }
#pragma unroll
    for (int m = 1; m < 16; m <<= 1) qnp += __shfl_xor(qnp, m, 16);
    if (kt == 0) qnorm[row0 + r2] = qnp;
  }
}

// ---------------------------------------------------------------------------
// K2: key norms + quantum-phase means + bf16 hi/lo split keys + chunk kn-max
// ---------------------------------------------------------------------------
__global__ __launch_bounds__(256) void k2_prep(
    const float* __restrict__ keys, const float* __restrict__ qp,
    float* __restrict__ kn, float* __restrict__ pm,
    unsigned short* __restrict__ khi, unsigned short* __restrict__ klo,
    float* __restrict__ kmx)
{
  __shared__ float red[256];
  const int t = threadIdx.x;
  const int m = blockIdx.x * 256 + t;
  float kv[24];
#pragma unroll
  for (int d = 0; d < DM; d += 4) {
    const float4 v = *(const float4*)&keys[(size_t)m * DM + d];
    kv[d] = v.x; kv[d + 1] = v.y; kv[d + 2] = v.z; kv[d + 3] = v.w;
  }
  float s = 0.f;
#pragma unroll
  for (int d = 0; d < DM; d++) s = fmaf(kv[d], kv[d], s);
  kn[m] = s;
  float p = 0.f;
#pragma unroll
  for (int q = 0; q < 8; q++) p += tanhf(qp[(size_t)m * 8 + q]);
  pm[m] = p * 0.125f;
#pragma unroll
  for (int d = 0; d < DM; d++) {
    const unsigned short h = bf16rn(kv[d]);
    const float hf = __uint_as_float(((unsigned)h) << 16);
    const unsigned short l = bf16rn(kv[d] - hf);
    khi[(size_t)m * 32 + d] = h;
    klo[(size_t)m * 32 + d] = l;
  }
#pragma unroll
  for (int d = DM; d < 32; d++) { khi[(size_t)m * 32 + d] = 0; klo[(size_t)m * 32 + d] = 0; }
  red[t] = s;
  __syncthreads();
  for (int off = 128; off > 0; off >>= 1) {
    if (t < off) red[t] = fmaxf(red[t], red[t + off]);
    __syncthreads();
  }
  if (t == 0) kmx[blockIdx.x] = red[0];
}

// ---------------------------------------------------------------------------
// K3 v5: MFMA screening + exact fp32 finish. (unchanged)
// ---------------------------------------------------------------------------
__global__ __launch_bounds__(1024, 4) void k3_topk(
    const float* __restrict__ qvec, const float* __restrict__ qnorm,
    const float* __restrict__ keys, const float* __restrict__ kn,
    const unsigned short* __restrict__ khi, const unsigned short* __restrict__ klo,
    const float* __restrict__ kmx,
    const float* __restrict__ fw,  const float* __restrict__ pm,
    float* __restrict__ w_out, int* __restrict__ itop_out, float* __restrict__ gain_out)
{
  __shared__ float qsm[32][25];
  __shared__ float qns[32];
  __shared__ unsigned short qh_l[32][32];
  __shared__ unsigned short ql_l[32][32];
  __shared__ float gmins[64][33];
  __shared__ float Ts[32];
  __shared__ float Tm2s[32];
  __shared__ unsigned glive[2];
  __shared__ int cnt[32];
  __shared__ int      candI[32][K3CAND];
  __shared__ unsigned candV[32][K3CAND];
  __shared__ float wV[32][KSEL];
  __shared__ int   wI[32][KSEL];
  __shared__ float knmax_s;

  const int t = threadIdx.x;
  const int w = t >> 6, lane = t & 63;
  const int colid = lane & 15;
  const int kgrp  = lane >> 4;
  const int row0 = blockIdx.x * 32;

  if (t < 32 * DM) qsm[t / DM][t % DM] = qvec[(size_t)row0 * DM + t];
  if (t < 32) { qns[t] = qnorm[row0 + t]; cnt[t] = 0; }
  if (t < 2) glive[t] = 0u;
  if (t == 0) { float m = 0.f; for (int i = 0; i < 32; i++) m = fmaxf(m, kmx[i]); knmax_s = m; }
  __syncthreads();
  {
    const int r = t >> 5, k = t & 31;
    const float v = (k < DM) ? qsm[r][k] : 0.f;
    const unsigned short h = bf16rn(v);
    const float hf = __uint_as_float(((unsigned)h) << 16);
    qh_l[r][k] = h;
    ql_l[r][k] = bf16rn(v - hf);
  }
  __syncthreads();

  const short8_t ah0 = *(const short8_t*)&qh_l[colid][kgrp * 8];
  const short8_t al0 = *(const short8_t*)&ql_l[colid][kgrp * 8];
  const short8_t ah1 = *(const short8_t*)&qh_l[16 + colid][kgrp * 8];
  const short8_t al1 = *(const short8_t*)&ql_l[16 + colid][kgrp * 8];
  float qn8[8];
#pragma unroll
  for (int reg = 0; reg < 4; reg++) {
    qn8[reg]     = qns[kgrp * 4 + reg];
    qn8[reg + 4] = qns[16 + kgrp * 4 + reg];
  }

  for (int u = 0; u < 4; u++) {
    const int g = w + 16 * u;
    const int nbase = g * 128;
    float mn[8];
#pragma unroll
    for (int j = 0; j < 8; j++) {
      const int key = nbase + j * 16 + colid;
      const short8_t bh = *(const short8_t*)&khi[(size_t)key * 32 + kgrp * 8];
      const short8_t bl = *(const short8_t*)&klo[(size_t)key * 32 + kgrp * 8];
      const float knv = kn[key];
      f32x4 c0 = {0.f, 0.f, 0.f, 0.f}, c1 = {0.f, 0.f, 0.f, 0.f};
      c0 = __builtin_amdgcn_mfma_f32_16x16x32_bf16(ah0, bh, c0, 0, 0, 0);
      c1 = __builtin_amdgcn_mfma_f32_16x16x32_bf16(ah1, bh, c1, 0, 0, 0);
      c0 = __builtin_amdgcn_mfma_f32_16x16x32_bf16(ah0, bl, c0, 0, 0, 0);
      c1 = __builtin_amdgcn_mfma_f32_16x16x32_bf16(ah1, bl, c1, 0, 0, 0);
      c0 = __builtin_amdgcn_mfma_f32_16x16x32_bf16(al0, bh, c0, 0, 0, 0);
      c1 = __builtin_amdgcn_mfma_f32_16x16x32_bf16(al1, bh, c1, 0, 0, 0);
#pragma unroll
      for (int reg = 0; reg < 4; reg++) {
        const float d0 = fmaf(-2.f, c0[reg], qn8[reg] + knv);
        const float d1 = fmaf(-2.f, c1[reg], qn8[reg + 4] + knv);
        if (j == 0) { mn[reg] = d0; mn[reg + 4] = d1; }
        else        { mn[reg] = fminf(mn[reg], d0); mn[reg + 4] = fminf(mn[reg + 4], d1); }
      }
    }
#pragma unroll
    for (int reg = 0; reg < 4; reg++) {
      const float v0 = rowmin16(mn[reg]);
      const float v1 = rowmin16(mn[reg + 4]);
      if (colid == 15) {
        gmins[g][kgrp * 4 + reg] = v0;
        gmins[g][16 + kgrp * 4 + reg] = v1;
      }
    }
  }
  __syncthreads();

  {
    const int r = t & 31, i = t >> 5;
    const float v0 = gmins[i * 2][r], v1 = gmins[i * 2 + 1][r];
    int rk0 = 0, eq0 = 0, rk1 = 0, eq1 = 0;
    for (int g = 0; g < 64; g++) {
      const float gv = gmins[g][r];
      rk0 += (gv < v0); eq0 += (gv == v0);
      rk1 += (gv < v1); eq1 += (gv == v1);
    }
    if (rk0 <= 31 && rk0 + eq0 > 31) Ts[r] = v0;
    if (rk1 <= 31 && rk1 + eq1 > 31) Ts[r] = v1;
  }
  __syncthreads();
  if (t < 32) {
    const float T = Ts[t];
    const float mu = 2e-4f * sqrtf(fmaxf(qns[t], 0.f) * knmax_s) + 1e-6f;
    Tm2s[t] = T + fabsf(T) * 1e-6f + 2.f * mu;
  }
  __syncthreads();
  {
    const int r = t & 31, i = t >> 5;
    const unsigned b0 = (gmins[i * 2][r]     <= Tm2s[r]) ? 1u : 0u;
    const unsigned b1 = (gmins[i * 2 + 1][r] <= Tm2s[r]) ? 2u : 0u;
    const unsigned bits = (b0 | b1) << ((i * 2) & 31);
    if (bits) atomicOr(&glive[i >> 4], bits);
  }
  __syncthreads();

  float tm8[8];
#pragma unroll
  for (int reg = 0; reg < 4; reg++) {
    tm8[reg]     = Tm2s[kgrp * 4 + reg];
    tm8[reg + 4] = Tm2s[16 + kgrp * 4 + reg];
  }

  for (int u = 0; u < 4; u++) {
    const int g = w + 16 * u;
    if (!((glive[g >> 5] >> (g & 31)) & 1u)) continue;
    const int nbase = g * 128;
#pragma unroll
    for (int j = 0; j < 8; j++) {
      const int key = nbase + j * 16 + colid;
      const short8_t bh = *(const short8_t*)&khi[(size_t)key * 32 + kgrp * 8];
      const short8_t bl = *(const short8_t*)&klo[(size_t)key * 32 + kgrp * 8];
      const float knv = kn[key];
      f32x4 c0 = {0.f, 0.f, 0.f, 0.f}, c1 = {0.f, 0.f, 0.f, 0.f};
      c0 = __builtin_amdgcn_mfma_f32_16x16x32_bf16(ah0, bh, c0, 0, 0, 0);
      c1 = __builtin_amdgcn_mfma_f32_16x16x32_bf16(ah1, bh, c1, 0, 0, 0);
      c0 = __builtin_amdgcn_mfma_f32_16x16x32_bf16(ah0, bl, c0, 0, 0, 0);
      c1 = __builtin_amdgcn_mfma_f32_16x16x32_bf16(ah1, bl, c1, 0, 0, 0);
      c0 = __builtin_amdgcn_mfma_f32_16x16x32_bf16(al0, bh, c0, 0, 0, 0);
      c1 = __builtin_amdgcn_mfma_f32_16x16x32_bf16(al1, bh, c1, 0, 0, 0);
#pragma unroll
      for (int reg = 0; reg < 4; reg++) {
        const float d0 = fmaf(-2.f, c0[reg], qn8[reg] + knv);
        if (d0 <= tm8[reg]) {
          const int row = kgrp * 4 + reg;
          const int pos = atomicAdd(&cnt[row], 1);
          if (pos < K3CAND) candI[row][pos] = key;
        }
        const float d1 = fmaf(-2.f, c1[reg], qn8[reg + 4] + knv);
        if (d1 <= tm8[reg + 4]) {
          const int row = 16 + kgrp * 4 + reg;
          const int pos = atomicAdd(&cnt[row], 1);
          if (pos < K3CAND) candI[row][pos] = key;
        }
      }
    }
  }
  for (int idx = t; idx < 32 * KSEL; idx += 1024) { wV[idx >> 5][idx & 31] = 1e30f; wI[idx >> 5][idx & 31] = 0; }
  __syncthreads();

  {
    const int r = t >> 5, kt = t & 31;
    const int C = min(cnt[r], K3CAND);
    const float qnr = qns[r];
    for (int ci = kt; ci < C; ci += 32) {
      const int key = candI[r][ci];
      float kv[24];
#pragma unroll
      for (int d = 0; d < DM; d += 4) {
        const float4 v = *(const float4*)&keys[(size_t)key * DM + d];
        kv[d] = v.x; kv[d + 1] = v.y; kv[d + 2] = v.z; kv[d + 3] = v.w;
      }
      float dot = 0.f;
#pragma unroll
      for (int d = 0; d < DM; d++) dot = fmaf(kv[d], qsm[r][d], dot);
      const float d2 = fmaf(-2.f, dot, qnr + kn[key]);
      candV[r][ci] = __float_as_uint(fmaxf(d2, 0.f));
    }
  }
  __syncthreads();

  {
    const int r = t >> 5, kt = t & 31;
    const int C = min(cnt[r], K3CAND);
    for (int ci = kt; ci < C; ci += 32) {
      const unsigned v = candV[r][ci];
      const unsigned key = (unsigned)candI[r][ci];
      int rk = 0;
      for (int j = 0; j < C; j++) {
        const unsigned vj = candV[r][j];
        rk += (vj < v) || (vj == v && (unsigned)candI[r][j] < key);
      }
      if (rk < KSEL) { wV[r][rk] = __uint_as_float(v); wI[r][rk] = (int)key; }
    }
  }
  __syncthreads();

  float sc;
  {
    const float f0 = fw[0], f1 = fw[1], f2 = fw[2], f3 = fw[3];
    const float mx = fmaxf(fmaxf(f0, f1), fmaxf(f2, f3));
    const float e0 = expf(f0 - mx), e1 = expf(f1 - mx), e2 = expf(f2 - mx), e3 = expf(f3 - mx);
    sc = (e0 + 0.5f * e1 + 0.25f * e2 + 0.125f * e3) / (e0 + e1 + e2 + e3);
  }
  if (t < 512) {
    const int r = t >> 4, kt = t & 15;
    const float dA = sqrtf(wV[r][kt]) * sc;
    const float dB = sqrtf(wV[r][kt + 16]) * sc;
    float mn = fminf(dA, dB);
#pragma unroll
    for (int m = 1; m < 16; m <<= 1) mn = fminf(mn, __shfl_xor(mn, m, 16));
    const float eA = expf(mn - dA), eB = expf(mn - dB);
    float s = eA + eB;
#pragma unroll
    for (int m = 1; m < 16; m <<= 1) s += __shfl_xor(s, m, 16);
    const float w0 = eA / s, w1 = eB / s;
    const int k0 = wI[r][kt], k1 = wI[r][kt + 16];
    float gp = w0 * pm[k0] + w1 * pm[k1];
#pragma unroll
    for (int m = 1; m < 16; m <<= 1) gp += __shfl_xor(gp, m, 16);
    const size_t row = (size_t)(row0 + r);
    w_out[row * KSEL + kt] = w0;      w_out[row * KSEL + kt + 16] = w1;
    itop_out[row * KSEL + kt] = k0;   itop_out[row * KSEL + kt + 16] = k1;
    if (kt == 0) gain_out[row] = 1.f + 0.02f * gp;
  }
}

// ---------------------------------------------------------------------------
// K4a: p = x@Wp.T + bp via MFMA (bf16 hi/lo split, x converted in-register).
// 512 thr (8 waves), 32 rows/block, grid 256. No LDS.
// ---------------------------------------------------------------------------
__global__ __launch_bounds__(512) void k4a_pgemm(
    const float* __restrict__ x, const unsigned short* __restrict__ Wphi,
    const unsigned short* __restrict__ Wplo, const float* __restrict__ bp,
    float* __restrict__ p)
{
  const int t = threadIdx.x;
  const int w = t >> 6, lane = t & 63;
  const int colid = lane & 15, kgrp = lane >> 4;
  const int wm = w >> 2, wn = w & 3;
  const int row0 = blockIdx.x * 32;
  const int arow = row0 + wm * 16 + colid;

  f32x4 acc0 = {0.f, 0.f, 0.f, 0.f};
  f32x4 acc1 = {0.f, 0.f, 0.f, 0.f};
  f32x4 acc2 = {0.f, 0.f, 0.f, 0.f};
  f32x4 acc3 = {0.f, 0.f, 0.f, 0.f};

  for (int kc = 0; kc < 24; kc++) {
    const int kb = kc * 32 + kgrp * 8;
    float xv[8];
    *(float4*)&xv[0] = *(const float4*)&x[(size_t)arow * INDIM + kb];
    *(float4*)&xv[4] = *(const float4*)&x[(size_t)arow * INDIM + kb + 4];
    short8_t ah, al;
#pragma unroll
    for (int i = 0; i < 8; i++) {
      const unsigned short h = bf16rn(xv[i]);
      const float hf = __uint_as_float(((unsigned)h) << 16);
      ah[i] = (short)h;
      al[i] = (short)bf16rn(xv[i] - hf);
    }
#pragma unroll
    for (int ct = 0; ct < 4; ct++) {
      const int col = wn * 64 + ct * 16 + colid;
      const short8_t bh = *(const short8_t*)&Wphi[(size_t)col * INDIM + kb];
      const short8_t bl = *(const short8_t*)&Wplo[(size_t)col * INDIM + kb];
      f32x4* pa = (ct == 0) ? &acc0 : (ct == 1) ? &acc1 : (ct == 2) ? &acc2 : &acc3;
      *pa = __builtin_amdgcn_mfma_f32_16x16x32_bf16(ah, bh, *pa, 0, 0, 0);
      *pa = __builtin_amdgcn_mfma_f32_16x16x32_bf16(al, bh, *pa, 0, 0, 0);
      *pa = __builtin_amdgcn_mfma_f32_16x16x32_bf16(ah, bl, *pa, 0, 0, 0);
    }
  }
#pragma unroll
  for (int ct = 0; ct < 4; ct++) {
    const int col = wn * 64 + ct * 16 + colid;
    const float b = bp[col];
    const f32x4 a = (ct == 0) ? acc0 : (ct == 1) ? acc1 : (ct == 2) ? acc2 : acc3;
#pragma unroll
    for (int reg = 0; reg < 4; reg++) {
      const int row = row0 + wm * 16 + kgrp * 4 + reg;
      p[(size_t)row * HN + col] = a[reg] + b;
    }
  }
}

// ---------------------------------------------------------------------------
// K4b: Kf = FFT(e^{i 2pi sigmoid(p)}) * e^{i ek}. float2 LDS with idx-padding
// (conflict-free bit-reversal + stages), coalesced p/kf I/O.
// ---------------------------------------------------------------------------
__global__ __launch_bounds__(256) void k4b_fft(
    const float* __restrict__ p, const float* __restrict__ ek,
    float* __restrict__ kf_re, float* __restrict__ kf_im)
{
  __shared__ float2 c[16][273];
  __shared__ float twc[HN], tws[HN];
  const int t = threadIdx.x;
  const int row0 = blockIdx.x * 16;
  {
    const float a = (float)t * (TWO_PI_F / 256.f);
    twc[t] = cosf(a); tws[t] = sinf(a);
  }
  // phase 1: load p (coalesced), sigmoid -> phase -> e^{i phase}, bit-rev scatter
  {
    const int hb = __brev((unsigned)t) >> 24;
    const int hbi = hb + (hb >> 5);
#pragma unroll
    for (int i = 0; i < 16; i++) {
      const float pv = p[(size_t)(row0 + i) * HN + t];
      const float sg = 1.f / (1.f + expf(-pv));
      float sn, cs;
      __sincosf(TWO_PI_F * sg, &sn, &cs);
      c[i][hbi] = make_float2(cs, sn);
    }
  }
  __syncthreads();
  const int r = t >> 4, t16 = t & 15;
  for (int s = 0; s < 8; s++) {
    const int half = 1 << s;
#pragma unroll
    for (int pp = 0; pp < 8; pp++) {
      const int bi = t16 + 16 * pp;
      const int jj = bi & (half - 1);
      const int base = (bi >> s) << (s + 1);
      const int i0 = base + jj, i1 = i0 + half;
      const int tw = jj << (7 - s);
      const float wr = twc[tw], wi = -tws[tw];   // forward FFT
      const int p0 = i0 + (i0 >> 5), p1 = i1 + (i1 >> 5);
      const float2 A = c[r][p0];
      const float2 B = c[r][p1];
      const float tr = wr * B.x - wi * B.y, ti = wr * B.y + wi * B.x;
      c[r][p0] = make_float2(A.x + tr, A.y + ti);
      c[r][p1] = make_float2(A.x - tr, A.y - ti);
    }
    __syncthreads();
  }
  // final: multiply e^{i ek[h]} (one sincos per thread), coalesced store
  {
    float esn, ecs;
    __sincosf(ek[t], &esn, &ecs);
    const int ti = t + (t >> 5);
#pragma unroll
    for (int i = 0; i < 16; i++) {
      const float2 v = c[i][ti];
      const size_t o = (size_t)(row0 + i) * HN + t;
      kf_re[o] = v.x * ecs - v.y * esn;
      kf_im[o] = v.x * esn + v.y * ecs;
    }
  }
}

// ---------------------------------------------------------------------------
// K5 v2: gather + Y = conj(Kf)*Hmix, then triplet = rb + (Y . G)/256.
// ---------------------------------------------------------------------------
__global__ __launch_bounds__(256) void k5_holo(
    const float* __restrict__ holo_re, const float* __restrict__ holo_im,
    const float* __restrict__ kf_re, const float* __restrict__ kf_im,
    const float* __restrict__ w_ws, const int* __restrict__ itop_ws,
    const float* __restrict__ Grp, const float* __restrict__ Gip,
    const float* __restrict__ rb, float* __restrict__ triplet)
{
  __shared__ __align__(16) float ysr[8][260];
  __shared__ __align__(16) float ysi[8][260];
  __shared__ float red[4][8][128];
  __shared__ float wsm[8][KSEL];
  __shared__ int   ism[8][KSEL];
  const int t = threadIdx.x;
  const int w = t >> 6, lane = t & 63;
  const int row0 = blockIdx.x * 8;

  {
    const int rr = t >> 5, k2 = t & 31;
    wsm[rr][k2] = w_ws[(size_t)(row0 + rr) * KSEL + k2];
    ism[rr][k2] = itop_ws[(size_t)(row0 + rr) * KSEL + k2];
  }
  __syncthreads();

#pragma unroll
  for (int pass = 0; pass < 2; pass++) {
    const int row = w + 4 * pass;
    float4 hr4 = {0.f, 0.f, 0.f, 0.f};
    float4 hi4 = {0.f, 0.f, 0.f, 0.f};
#pragma unroll 8
    for (int k2 = 0; k2 < KSEL; k2++) {
      const int m = ism[row][k2];
      const float wk = wsm[row][k2];
      const float4 re4 = *(const float4*)&holo_re[(size_t)m * HN + lane * 4];
      const float4 im4 = *(const float4*)&holo_im[(size_t)m * HN + lane * 4];
      hr4.x = fmaf(wk, re4.x, hr4.x); hr4.y = fmaf(wk, re4.y, hr4.y);
      hr4.z = fmaf(wk, re4.z, hr4.z); hr4.w = fmaf(wk, re4.w, hr4.w);
      hi4.x = fmaf(wk, im4.x, hi4.x); hi4.y = fmaf(wk, im4.y, hi4.y);
      hi4.z = fmaf(wk, im4.z, hi4.z); hi4.w = fmaf(wk, im4.w, hi4.w);
    }
    const size_t o = (size_t)(row0 + row) * HN + lane * 4;
    const float4 kr4 = *(const float4*)&kf_re[o];
    const float4 ki4 = *(const float4*)&kf_im[o];
    float4 yr4, yi4;
    yr4.x = kr4.x * hr4.x + ki4.x * hi4.x;  yi4.x = kr4.x * hi4.x - ki4.x * hr4.x;
    yr4.y = kr4.y * hr4.y + ki4.y * hi4.y;  yi4.y = kr4.y * hi4.y - ki4.y * hr4.y;
    yr4.z = kr4.z * hr4.z + ki4.z * hi4.z;  yi4.z = kr4.z * hi4.z - ki4.z * hr4.z;
    yr4.w = kr4.w * hr4.w + ki4.w * hi4.w;  yi4.w = kr4.w * hi4.w - ki4.w * hr4.w;
    *(float4*)&ysr[row][lane * 4] = yr4;
    *(float4*)&ysi[row][lane * 4] = yi4;
  }
  __syncthreads();

  float acc[8][2];
#pragma unroll
  for (int rr = 0; rr < 8; rr++) { acc[rr][0] = 0.f; acc[rr][1] = 0.f; }
#pragma unroll 4
  for (int i = 0; i < 16; i++) {
    const int h4 = w * 16 + i;
    const float4 gra = *(const float4*)&Grp[((size_t)h4 * 128 + lane) * 4];
    const float4 gia = *(const float4*)&Gip[((size_t)h4 * 128 + lane) * 4];
    const float4 grb = *(const float4*)&Grp[((size_t)h4 * 128 + 64 + lane) * 4];
    const float4 gib = *(const float4*)&Gip[((size_t)h4 * 128 + 64 + lane) * 4];
#pragma unroll
    for (int rr = 0; rr < 8; rr++) {
      const float4 yr4 = *(const float4*)&ysr[rr][h4 * 4];
      const float4 yi4 = *(const float4*)&ysi[rr][h4 * 4];
      acc[rr][0] = fmaf(yr4.x, gra.x, fmaf(yr4.y, gra.y, fmaf(yr4.z, gra.z, fmaf(yr4.w, gra.w, acc[rr][0]))));
      acc[rr][0] = fmaf(yi4.x, gia.x, fmaf(yi4.y, gia.y, fmaf(yi4.z, gia.z, fmaf(yi4.w, gia.w, acc[rr][0]))));
      acc[rr][1] = fmaf(yr4.x, grb.x, fmaf(yr4.y, grb.y, fmaf(yr4.z, grb.z, fmaf(yr4.w, grb.w, acc[rr][1]))));
      acc[rr][1] = fmaf(yi4.x, gib.x, fmaf(yi4.y, gib.y, fmaf(yi4.z, gib.z, fmaf(yi4.w, gib.w, acc[rr][1]))));
    }
  }
#pragma unroll
  for (int rr = 0; rr < 8; rr++) {
    red[w][rr][lane] = acc[rr][0];
    red[w][rr][64 + lane] = acc[rr][1];
  }
  __syncthreads();

  for (int idx = t; idx < 8 * 128; idx += 256) {
    const int rr = idx >> 7, o = idx & 127;
    if (o < TD) {
      const float s = red[0][rr][o] + red[1][rr][o] + red[2][rr][o] + red[3][rr][o];
      triplet[(size_t)(row0 + rr) * TD + o] = rb[o] + s * (1.f / 256.f);
    }
  }
}

// ---------------------------------------------------------------------------
// K6: out = gelu(LN(triplet@W_out.T + b_out)) * gain
// ---------------------------------------------------------------------------
__global__ __launch_bounds__(256) void k6_out(
    const float* __restrict__ triplet, const float* __restrict__ Wo,
    const float* __restrict__ bo, const float* __restrict__ go,
    const float* __restrict__ bbo, const float* __restrict__ gain,
    float* __restrict__ out)
{
  __shared__ float ts[16][76];
  __shared__ float ys[16][772];
  const int t = threadIdx.x;
  const int row0 = blockIdx.x * 16;
  for (int idx = t; idx < 16 * TD; idx += 256) ts[idx / TD][idx % TD] = triplet[(size_t)row0 * TD + idx];
  __syncthreads();
  float acc[16][3];
#pragma unroll
  for (int rr = 0; rr < 16; rr++) { acc[rr][0] = 0.f; acc[rr][1] = 0.f; acc[rr][2] = 0.f; }
  for (int e = 0; e < TD; e++) {
    float wv[3];
#pragma unroll
    for (int j = 0; j < 3; j++) wv[j] = Wo[(size_t)(t + 256 * j) * TD + e];
#pragma unroll
    for (int rr = 0; rr < 16; rr++) {
      const float tv = ts[rr][e];
      acc[rr][0] = fmaf(tv, wv[0], acc[rr][0]);
      acc[rr][1] = fmaf(tv, wv[1], acc[rr][1]);
      acc[rr][2] = fmaf(tv, wv[2], acc[rr][2]);
    }
  }
  {
    const float b0 = bo[t], b1 = bo[t + 256], b2 = bo[t + 512];
#pragma unroll
    for (int rr = 0; rr < 16; rr++) {
      ys[rr][t] = acc[rr][0] + b0;
      ys[rr][t + 256] = acc[rr][1] + b1;
      ys[rr][t + 512] = acc[rr][2] + b2;
    }
  }
  __syncthreads();
  const int r = t >> 4, kt = t & 15;
  float s = 0.f, sq = 0.f;
  for (int u = 0; u < 48; u++) {
    const float v = ys[r][kt + 16 * u];
    s += v; sq = fmaf(v, v, sq);
  }
#pragma unroll
  for (int m = 1; m < 16; m <<= 1) { s += __shfl_xor(s, m, 16); sq += __shfl_xor(sq, m, 16); }
  const float mean = s * (1.f / 768.f);
  const float var  = sq * (1.f / 768.f) - mean * mean;
  const float rstd = rsqrtf(var + 1e-5f);
  const float gn = gain[row0 + r];
  for (int u = 0; u < 48; u++) {
    const int e = kt + 16 * u;
    const float v = (ys[r][e] - mean) * rstd * go[e] + bbo[e];
    out[(size_t)(row0 + r) * INDIM + e] = gelu_exact(v) * gn;
  }
}

// ---------------------------------------------------------------------------
extern "C" void kernel_launch(void* const* d_in, const int* in_sizes, int n_in,
                              void* d_out, int out_size, void* d_ws, size_t ws_size,
                              hipStream_t stream)
{
  (void)in_sizes; (void)n_in; (void)out_size; (void)ws_size;
  const float* x     = (const float*)d_in[0];
  const float* Wi    = (const float*)d_in[1];
  const float* bi    = (const float*)d_in[2];
  const float* gi    = (const float*)d_in[3];
  const float* bbi   = (const float*)d_in[4];
  const float* ricci = (const float*)d_in[5];
  const float* fw    = (const float*)d_in[6];
  const float* keys  = (const float*)d_in[7];
  const float* Wp    = (const float*)d_in[8];
  const float* bp    = (const float*)d_in[9];
  const float* ek    = (const float*)d_in[10];
  const float* hre   = (const float*)d_in[11];
  const float* him   = (const float*)d_in[12];
  const float* RW    = (const float*)d_in[13];
  const float* rb    = (const float*)d_in[14];
  const float* Wo    = (const float*)d_in[15];
  const float* bo    = (const float*)d_in[16];
  const float* go    = (const float*)d_in[17];
  const float* bbo   = (const float*)d_in[18];
  const float* qp    = (const float*)d_in[19];
  float* out = (float*)d_out;

  char* ws = (char*)d_ws;
  float* qvec    = (float*)(ws + 0);
  float* qnorm   = (float*)(ws + 786432);
  float* kn      = (float*)(ws + 819200);
  float* pm      = (float*)(ws + 851968);
  float* gain    = (float*)(ws + 884736);
  float* w_ws    = (float*)(ws + 917504);
  int*   itop    = (int*)  (ws + 1966080);
  float* triplet = (float*)(ws + 3014656);
  float* kf_re   = (float*)(ws + 5373952);
  float* kf_im   = (float*)(ws + 13762560);
  unsigned short* khi = (unsigned short*)(ws + 22151168);  // 524288
  unsigned short* klo = (unsigned short*)(ws + 22675456);  // 524288
  float* kmx     = (float*)(ws + 23199744);                // 1 KB
  float* Grp     = (float*)(ws + 23200768);                // 131072
  float* Gip     = (float*)(ws + 23331840);                // 131072
  unsigned short* Wphi = (unsigned short*)(ws + 23462912); // 393216
  unsigned short* Wplo = (unsigned short*)(ws + 23856128); // 393216
  float* pbuf    = (float*)(ws + 24249344);                // 8388608 -> ends 32637952

  k0_gprep<<<dim3(8), dim3(256), 0, stream>>>(RW, Grp, Gip);
  kw_split<<<dim3(192), dim3(256), 0, stream>>>(Wp, Wphi, Wplo);
  k1_encode<<<dim3(NROWS / 16), dim3(256), 0, stream>>>(x, Wi, bi, gi, bbi, ricci, qvec, qnorm);
  k2_prep<<<dim3(MKEYS / 256), dim3(256), 0, stream>>>(keys, qp, kn, pm, khi, klo, kmx);
  k4a_pgemm<<<dim3(NROWS / 32), dim3(512), 0, stream>>>(x, Wphi, Wplo, bp, pbuf);
  k4b_fft<<<dim3(NROWS / 16), dim3(256), 0, stream>>>(pbuf, ek, kf_re, kf_im);
  k3_topk<<<dim3(NROWS / 32), dim3(1024), 0, stream>>>(qvec, qnorm, keys, kn, khi, klo, kmx, fw, pm, w_ws, itop, gain);
  k5_holo<<<dim3(NROWS / 8), dim3(256), 0, stream>>>(hre, him, kf_re, kf_im, w_ws, itop, Grp, Gip, rb, triplet);
  k6_out<<<dim3(NROWS / 16), dim3(256), 0, stream>>>(triplet, Wo, bo, go, bbo, gain, out);
}

// Round 9
// 267.743 us; speedup vs baseline: 2.7637x; 1.1553x over previous
//
#include <hip/hip_runtime.h>
#include <hip/hip_bf16.h>
#include <math.h>

#define NROWS 8192
#define INDIM 768
#define TD    72
#define DM    24
#define MKEYS 8192
#define KSEL  32
#define HN    256
#define K3CAND 128

#define TWO_PI_F 6.283185307179586f

typedef __attribute__((ext_vector_type(8))) short short8_t;
typedef __attribute__((ext_vector_type(4))) float f32x4;

__device__ __forceinline__ float gelu_exact(float v){
  return 0.5f * v * (1.0f + erff(v * 0.7071067811865476f));
}

// round-to-nearest-even f32 -> bf16 bits
__device__ __forceinline__ unsigned short bf16rn(float f){
  unsigned u = __float_as_uint(f);
  unsigned r = u + 0x7FFFu + ((u >> 16) & 1u);
  return (unsigned short)(r >> 16);
}

// min across each 16-lane DPP row; lane 15 (mod 16) holds the row min.
__device__ __forceinline__ float rowmin16(float v){
  int s, p;
  s = __float_as_int(v); p = __builtin_amdgcn_update_dpp(s, s, 0x111, 0xF, 0xF, false);
  v = fminf(v, __int_as_float(p));
  s = __float_as_int(v); p = __builtin_amdgcn_update_dpp(s, s, 0x112, 0xF, 0xF, false);
  v = fminf(v, __int_as_float(p));
  s = __float_as_int(v); p = __builtin_amdgcn_update_dpp(s, s, 0x114, 0xF, 0xF, false);
  v = fminf(v, __int_as_float(p));
  s = __float_as_int(v); p = __builtin_amdgcn_update_dpp(s, s, 0x118, 0xF, 0xF, false);
  v = fminf(v, __int_as_float(p));
  return v;
}

// ---------------------------------------------------------------------------
// K0: G = FFT_256(RW[o][0:256] + i*RW[o][256:512]) panels for k5.
// ---------------------------------------------------------------------------
__global__ __launch_bounds__(256) void k0_gprep(
    const float* __restrict__ RW, float* __restrict__ Grp, float* __restrict__ Gip)
{
  __shared__ float sre[16][260];
  __shared__ float sim_[16][260];
  __shared__ float twc[HN], tws[HN];
  const int t = threadIdx.x;
  const int o0 = blockIdx.x * 16;
  {
    const float a = (float)t * (TWO_PI_F / 256.f);
    twc[t] = cosf(a); tws[t] = sinf(a);
  }
  const int r = t >> 4, cg = t & 15;
  const int o = o0 + r;
#pragma unroll
  for (int j = 0; j < 16; j++) {
    const int n = cg + 16 * j;
    const int hb = __brev((unsigned)n) >> 24;
    float cr = 0.f, ci = 0.f;
    if (o < TD) { cr = RW[(size_t)o * 512 + n]; ci = RW[(size_t)o * 512 + 256 + n]; }
    sre[r][hb] = cr; sim_[r][hb] = ci;
  }
  __syncthreads();
  const int t16 = t & 15;
  for (int s = 0; s < 8; s++) {
    const int half = 1 << s;
#pragma unroll
    for (int p = 0; p < 8; p++) {
      const int bi = t16 + 16 * p;
      const int jj = bi & (half - 1);
      const int base = (bi >> s) << (s + 1);
      const int i0 = base + jj, i1 = i0 + half;
      const int tw = jj << (7 - s);
      const float wr = twc[tw], wi = -tws[tw];
      const float ar = sre[r][i0], ai = sim_[r][i0];
      const float br = sre[r][i1], b2 = sim_[r][i1];
      const float tr = wr * br - wi * b2, ti = wr * b2 + wi * br;
      sre[r][i0] = ar + tr; sim_[r][i0] = ai + ti;
      sre[r][i1] = ar - tr; sim_[r][i1] = ai - ti;
    }
    __syncthreads();
  }
#pragma unroll
  for (int p = 0; p < 16; p++) {
    const int h = t16 + 16 * p;
    const size_t base = ((size_t)(h >> 2) * 128 + o) * 4 + (h & 3);
    Grp[base] = sre[r][h];
    Gip[base] = sim_[r][h];
  }
}

// ---------------------------------------------------------------------------
// KW: split key_phase_W (256x768) into bf16 hi/lo panels.
// ---------------------------------------------------------------------------
__global__ __launch_bounds__(256) void kw_split(
    const float* __restrict__ Wp, unsigned short* __restrict__ Wphi,
    unsigned short* __restrict__ Wplo)
{
  const int i4 = blockIdx.x * 256 + threadIdx.x;
  const float4 v = ((const float4*)Wp)[i4];
  float vv[4] = {v.x, v.y, v.z, v.w};
  ushort4 hh, ll;
  unsigned short* hp = (unsigned short*)&hh;
  unsigned short* lp = (unsigned short*)&ll;
#pragma unroll
  for (int j = 0; j < 4; j++) {
    const unsigned short h = bf16rn(vv[j]);
    const float hf = __uint_as_float(((unsigned)h) << 16);
    hp[j] = h; lp[j] = bf16rn(vv[j] - hf);
  }
  ((ushort4*)Wphi)[i4] = hh;
  ((ushort4*)Wplo)[i4] = ll;
}

// ---------------------------------------------------------------------------
// KWO: split W_out (768x72) into zero-padded 768x96 bf16 hi/lo panels.
// ---------------------------------------------------------------------------
__global__ __launch_bounds__(256) void kwo_split(
    const float* __restrict__ Wo, unsigned short* __restrict__ Wohi,
    unsigned short* __restrict__ Wolo)
{
  const int idx = blockIdx.x * 256 + threadIdx.x;   // 768*96 = 73728, grid 288
  const int row = idx / 96, k = idx % 96;
  const float v = (k < TD) ? Wo[(size_t)row * TD + k] : 0.f;
  const unsigned short h = bf16rn(v);
  const float hf = __uint_as_float(((unsigned)h) << 16);
  Wohi[idx] = h;
  Wolo[idx] = bf16rn(v - hf);
}

// ---------------------------------------------------------------------------
// K1 (fp32, round-7 version — q is SELECTION-CRITICAL: the top-32 boundary
// sits within ~2e-4 of d2 ties, and the output LN amplifies selection flips
// by rstd~250. q must remain on this exact fmaf chain.)
// ---------------------------------------------------------------------------
__global__ __launch_bounds__(256) void k1_encode(
    const float* __restrict__ x, const float* __restrict__ Wi,
    const float* __restrict__ bi, const float* __restrict__ gi,
    const float* __restrict__ bbi, const float* __restrict__ ricci,
    float* __restrict__ qvec, float* __restrict__ qnorm)
{
  __shared__ float xs[16][132];
  __shared__ float Ws[TD][132];
  __shared__ float zs[16][73];
  __shared__ float zb[16][25];
  const int t = threadIdx.x;
  const int r2 = t >> 4, ks = (t >> 3) & 1, u = t & 7;
  const int row0 = blockIdx.x * 16;

  float acc[9];
#pragma unroll
  for (int j = 0; j < 9; j++) acc[j] = 0.f;

  for (int kc = 0; kc < 6; kc++) {
    __syncthreads();
#pragma unroll
    for (int i = 0; i < 2; i++) {
      int idx = t + 256 * i;
      int rr = idx >> 5, kk = (idx & 31) << 2;
      *(float4*)&xs[rr][kk] = *(const float4*)&x[(size_t)(row0 + rr) * INDIM + kc * 128 + kk];
    }
#pragma unroll
    for (int i = 0; i < 9; i++) {
      int idx = t + 256 * i;
      int rr = idx >> 5, kk = (idx & 31) << 2;
      *(float4*)&Ws[rr][kk] = *(const float4*)&Wi[(size_t)rr * INDIM + kc * 128 + kk];
    }
    __syncthreads();
    const int kb = ks * 64;
#pragma unroll 4
    for (int kq = 0; kq < 16; kq++) {
      const float4 xv = *(const float4*)&xs[r2][kb + kq * 4];
#pragma unroll
      for (int j = 0; j < 9; j++) {
        const float4 wv = *(const float4*)&Ws[u + 8 * j][kb + kq * 4];
        acc[j] = fmaf(xv.x, wv.x, fmaf(xv.y, wv.y, fmaf(xv.z, wv.z, fmaf(xv.w, wv.w, acc[j]))));
      }
    }
  }
#pragma unroll
  for (int j = 0; j < 9; j++) acc[j] += __shfl_xor(acc[j], 8);

  float yv[9];
  float ps = 0.f, pq = 0.f;
#pragma unroll
  for (int j = 0; j < 9; j++) {
    const int o = u + 8 * j;
    yv[j] = acc[j] + bi[o];
    ps += yv[j]; pq += yv[j] * yv[j];
  }
#pragma unroll
  for (int m = 1; m < 8; m <<= 1) { ps += __shfl_xor(ps, m); pq += __shfl_xor(pq, m); }
  const float mean = ps * (1.f / 72.f);
  const float var  = pq * (1.f / 72.f) - mean * mean;
  const float rstd = rsqrtf(var + 1e-5f);
#pragma unroll
  for (int j = 0; j < 9; j++) {
    const int o = u + 8 * j;
    const float z = gelu_exact((yv[j] - mean) * rstd * gi[o] + bbi[o]);
    if (ks == 0) zs[r2][o] = z;
  }
  __syncthreads();
  {
    const int kt = t & 15;
    for (int e = kt; e < 24; e += 16)
      zb[r2][e] = (zs[r2][3 * e] + zs[r2][3 * e + 1] + zs[r2][3 * e + 2]) * (1.f / 3.f);
  }
  __syncthreads();
  {
    const int kt = t & 15;
    float qnp = 0.f;
    for (int d = kt; d < 24; d += 16) {
      float qd = 0.f;
#pragma unroll
      for (int e = 0; e < 24; e++) qd = fmaf(zb[r2][e], ricci[e * 24 + d], qd);
      qvec[(size_t)(row0 + r2) * DM + d] = qd;
      qnp = fmaf(qd, qd, qnp);
    }
#pragma unroll
    for (int m = 1; m < 16; m <<= 1) qnp += __shfl_xor(qnp, m, 16);
    if (kt == 0) qnorm[row0 + r2] = qnp;
  }
}

// ---------------------------------------------------------------------------
// K2: key norms + quantum-phase means + bf16 hi/lo split keys + chunk kn-max
// ---------------------------------------------------------------------------
__global__ __launch_bounds__(256) void k2_prep(
    const float* __restrict__ keys, const float* __restrict__ qp,
    float* __restrict__ kn, float* __restrict__ pm,
    unsigned short* __restrict__ khi, unsigned short* __restrict__ klo,
    float* __restrict__ kmx)
{
  __shared__ float red[256];
  const int t = threadIdx.x;
  const int m = blockIdx.x * 256 + t;
  float kv[24];
#pragma unroll
  for (int d = 0; d < DM; d += 4) {
    const float4 v = *(const float4*)&keys[(size_t)m * DM + d];
    kv[d] = v.x; kv[d + 1] = v.y; kv[d + 2] = v.z; kv[d + 3] = v.w;
  }
  float s = 0.f;
#pragma unroll
  for (int d = 0; d < DM; d++) s = fmaf(kv[d], kv[d], s);
  kn[m] = s;
  float p = 0.f;
#pragma unroll
  for (int q = 0; q < 8; q++) p += tanhf(qp[(size_t)m * 8 + q]);
  pm[m] = p * 0.125f;
#pragma unroll
  for (int d = 0; d < DM; d++) {
    const unsigned short h = bf16rn(kv[d]);
    const float hf = __uint_as_float(((unsigned)h) << 16);
    const unsigned short l = bf16rn(kv[d] - hf);
    khi[(size_t)m * 32 + d] = h;
    klo[(size_t)m * 32 + d] = l;
  }
#pragma unroll
  for (int d = DM; d < 32; d++) { khi[(size_t)m * 32 + d] = 0; klo[(size_t)m * 32 + d] = 0; }
  red[t] = s;
  __syncthreads();
  for (int off = 128; off > 0; off >>= 1) {
    if (t < off) red[t] = fmaxf(red[t], red[t + off]);
    __syncthreads();
  }
  if (t == 0) kmx[blockIdx.x] = red[0];
}

// ---------------------------------------------------------------------------
// K3 v5: MFMA screening + exact fp32 finish. (unchanged)
// ---------------------------------------------------------------------------
__global__ __launch_bounds__(1024, 4) void k3_topk(
    const float* __restrict__ qvec, const float* __restrict__ qnorm,
    const float* __restrict__ keys, const float* __restrict__ kn,
    const unsigned short* __restrict__ khi, const unsigned short* __restrict__ klo,
    const float* __restrict__ kmx,
    const float* __restrict__ fw,  const float* __restrict__ pm,
    float* __restrict__ w_out, int* __restrict__ itop_out, float* __restrict__ gain_out)
{
  __shared__ float qsm[32][25];
  __shared__ float qns[32];
  __shared__ unsigned short qh_l[32][32];
  __shared__ unsigned short ql_l[32][32];
  __shared__ float gmins[64][33];
  __shared__ float Ts[32];
  __shared__ float Tm2s[32];
  __shared__ unsigned glive[2];
  __shared__ int cnt[32];
  __shared__ int      candI[32][K3CAND];
  __shared__ unsigned candV[32][K3CAND];
  __shared__ float wV[32][KSEL];
  __shared__ int   wI[32][KSEL];
  __shared__ float knmax_s;

  const int t = threadIdx.x;
  const int w = t >> 6, lane = t & 63;
  const int colid = lane & 15;
  const int kgrp  = lane >> 4;
  const int row0 = blockIdx.x * 32;

  if (t < 32 * DM) qsm[t / DM][t % DM] = qvec[(size_t)row0 * DM + t];
  if (t < 32) { qns[t] = qnorm[row0 + t]; cnt[t] = 0; }
  if (t < 2) glive[t] = 0u;
  if (t == 0) { float m = 0.f; for (int i = 0; i < 32; i++) m = fmaxf(m, kmx[i]); knmax_s = m; }
  __syncthreads();
  {
    const int r = t >> 5, k = t & 31;
    const float v = (k < DM) ? qsm[r][k] : 0.f;
    const unsigned short h = bf16rn(v);
    const float hf = __uint_as_float(((unsigned)h) << 16);
    qh_l[r][k] = h;
    ql_l[r][k] = bf16rn(v - hf);
  }
  __syncthreads();

  const short8_t ah0 = *(const short8_t*)&qh_l[colid][kgrp * 8];
  const short8_t al0 = *(const short8_t*)&ql_l[colid][kgrp * 8];
  const short8_t ah1 = *(const short8_t*)&qh_l[16 + colid][kgrp * 8];
  const short8_t al1 = *(const short8_t*)&ql_l[16 + colid][kgrp * 8];
  float qn8[8];
#pragma unroll
  for (int reg = 0; reg < 4; reg++) {
    qn8[reg]     = qns[kgrp * 4 + reg];
    qn8[reg + 4] = qns[16 + kgrp * 4 + reg];
  }

  for (int u = 0; u < 4; u++) {
    const int g = w + 16 * u;
    const int nbase = g * 128;
    float mn[8];
#pragma unroll
    for (int j = 0; j < 8; j++) {
      const int key = nbase + j * 16 + colid;
      const short8_t bh = *(const short8_t*)&khi[(size_t)key * 32 + kgrp * 8];
      const short8_t bl = *(const short8_t*)&klo[(size_t)key * 32 + kgrp * 8];
      const float knv = kn[key];
      f32x4 c0 = {0.f, 0.f, 0.f, 0.f}, c1 = {0.f, 0.f, 0.f, 0.f};
      c0 = __builtin_amdgcn_mfma_f32_16x16x32_bf16(ah0, bh, c0, 0, 0, 0);
      c1 = __builtin_amdgcn_mfma_f32_16x16x32_bf16(ah1, bh, c1, 0, 0, 0);
      c0 = __builtin_amdgcn_mfma_f32_16x16x32_bf16(ah0, bl, c0, 0, 0, 0);
      c1 = __builtin_amdgcn_mfma_f32_16x16x32_bf16(ah1, bl, c1, 0, 0, 0);
      c0 = __builtin_amdgcn_mfma_f32_16x16x32_bf16(al0, bh, c0, 0, 0, 0);
      c1 = __builtin_amdgcn_mfma_f32_16x16x32_bf16(al1, bh, c1, 0, 0, 0);
#pragma unroll
      for (int reg = 0; reg < 4; reg++) {
        const float d0 = fmaf(-2.f, c0[reg], qn8[reg] + knv);
        const float d1 = fmaf(-2.f, c1[reg], qn8[reg + 4] + knv);
        if (j == 0) { mn[reg] = d0; mn[reg + 4] = d1; }
        else        { mn[reg] = fminf(mn[reg], d0); mn[reg + 4] = fminf(mn[reg + 4], d1); }
      }
    }
#pragma unroll
    for (int reg = 0; reg < 4; reg++) {
      const float v0 = rowmin16(mn[reg]);
      const float v1 = rowmin16(mn[reg + 4]);
      if (colid == 15) {
        gmins[g][kgrp * 4 + reg] = v0;
        gmins[g][16 + kgrp * 4 + reg] = v1;
      }
    }
  }
  __syncthreads();

  {
    const int r = t & 31, i = t >> 5;
    const float v0 = gmins[i * 2][r], v1 = gmins[i * 2 + 1][r];
    int rk0 = 0, eq0 = 0, rk1 = 0, eq1 = 0;
    for (int g = 0; g < 64; g++) {
      const float gv = gmins[g][r];
      rk0 += (gv < v0); eq0 += (gv == v0);
      rk1 += (gv < v1); eq1 += (gv == v1);
    }
    if (rk0 <= 31 && rk0 + eq0 > 31) Ts[r] = v0;
    if (rk1 <= 31 && rk1 + eq1 > 31) Ts[r] = v1;
  }
  __syncthreads();
  if (t < 32) {
    const float T = Ts[t];
    const float mu = 2e-4f * sqrtf(fmaxf(qns[t], 0.f) * knmax_s) + 1e-6f;
    Tm2s[t] = T + fabsf(T) * 1e-6f + 2.f * mu;
  }
  __syncthreads();
  {
    const int r = t & 31, i = t >> 5;
    const unsigned b0 = (gmins[i * 2][r]     <= Tm2s[r]) ? 1u : 0u;
    const unsigned b1 = (gmins[i * 2 + 1][r] <= Tm2s[r]) ? 2u : 0u;
    const unsigned bits = (b0 | b1) << ((i * 2) & 31);
    if (bits) atomicOr(&glive[i >> 4], bits);
  }
  __syncthreads();

  float tm8[8];
#pragma unroll
  for (int reg = 0; reg < 4; reg++) {
    tm8[reg]     = Tm2s[kgrp * 4 + reg];
    tm8[reg + 4] = Tm2s[16 + kgrp * 4 + reg];
  }

  for (int u = 0; u < 4; u++) {
    const int g = w + 16 * u;
    if (!((glive[g >> 5] >> (g & 31)) & 1u)) continue;
    const int nbase = g * 128;
#pragma unroll
    for (int j = 0; j < 8; j++) {
      const int key = nbase + j * 16 + colid;
      const short8_t bh = *(const short8_t*)&khi[(size_t)key * 32 + kgrp * 8];
      const short8_t bl = *(const short8_t*)&klo[(size_t)key * 32 + kgrp * 8];
      const float knv = kn[key];
      f32x4 c0 = {0.f, 0.f, 0.f, 0.f}, c1 = {0.f, 0.f, 0.f, 0.f};
      c0 = __builtin_amdgcn_mfma_f32_16x16x32_bf16(ah0, bh, c0, 0, 0, 0);
      c1 = __builtin_amdgcn_mfma_f32_16x16x32_bf16(ah1, bh, c1, 0, 0, 0);
      c0 = __builtin_amdgcn_mfma_f32_16x16x32_bf16(ah0, bl, c0, 0, 0, 0);
      c1 = __builtin_amdgcn_mfma_f32_16x16x32_bf16(ah1, bl, c1, 0, 0, 0);
      c0 = __builtin_amdgcn_mfma_f32_16x16x32_bf16(al0, bh, c0, 0, 0, 0);
      c1 = __builtin_amdgcn_mfma_f32_16x16x32_bf16(al1, bh, c1, 0, 0, 0);
#pragma unroll
      for (int reg = 0; reg < 4; reg++) {
        const float d0 = fmaf(-2.f, c0[reg], qn8[reg] + knv);
        if (d0 <= tm8[reg]) {
          const int row = kgrp * 4 + reg;
          const int pos = atomicAdd(&cnt[row], 1);
          if (pos < K3CAND) candI[row][pos] = key;
        }
        const float d1 = fmaf(-2.f, c1[reg], qn8[reg + 4] + knv);
        if (d1 <= tm8[reg + 4]) {
          const int row = 16 + kgrp * 4 + reg;
          const int pos = atomicAdd(&cnt[row], 1);
          if (pos < K3CAND) candI[row][pos] = key;
        }
      }
    }
  }
  for (int idx = t; idx < 32 * KSEL; idx += 1024) { wV[idx >> 5][idx & 31] = 1e30f; wI[idx >> 5][idx & 31] = 0; }
  __syncthreads();

  {
    const int r = t >> 5, kt = t & 31;
    const int C = min(cnt[r], K3CAND);
    const float qnr = qns[r];
    for (int ci = kt; ci < C; ci += 32) {
      const int key = candI[r][ci];
      float kv[24];
#pragma unroll
      for (int d = 0; d < DM; d += 4) {
        const float4 v = *(const float4*)&keys[(size_t)key * DM + d];
        kv[d] = v.x; kv[d + 1] = v.y; kv[d + 2] = v.z; kv[d + 3] = v.w;
      }
      float dot = 0.f;
#pragma unroll
      for (int d = 0; d < DM; d++) dot = fmaf(kv[d], qsm[r][d], dot);
      const float d2 = fmaf(-2.f, dot, qnr + kn[key]);
      candV[r][ci] = __float_as_uint(fmaxf(d2, 0.f));
    }
  }
  __syncthreads();

  {
    const int r = t >> 5, kt = t & 31;
    const int C = min(cnt[r], K3CAND);
    for (int ci = kt; ci < C; ci += 32) {
      const unsigned v = candV[r][ci];
      const unsigned key = (unsigned)candI[r][ci];
      int rk = 0;
      for (int j = 0; j < C; j++) {
        const unsigned vj = candV[r][j];
        rk += (vj < v) || (vj == v && (unsigned)candI[r][j] < key);
      }
      if (rk < KSEL) { wV[r][rk] = __uint_as_float(v); wI[r][rk] = (int)key; }
    }
  }
  __syncthreads();

  float sc;
  {
    const float f0 = fw[0], f1 = fw[1], f2 = fw[2], f3 = fw[3];
    const float mx = fmaxf(fmaxf(f0, f1), fmaxf(f2, f3));
    const float e0 = expf(f0 - mx), e1 = expf(f1 - mx), e2 = expf(f2 - mx), e3 = expf(f3 - mx);
    sc = (e0 + 0.5f * e1 + 0.25f * e2 + 0.125f * e3) / (e0 + e1 + e2 + e3);
  }
  if (t < 512) {
    const int r = t >> 4, kt = t & 15;
    const float dA = sqrtf(wV[r][kt]) * sc;
    const float dB = sqrtf(wV[r][kt + 16]) * sc;
    float mn = fminf(dA, dB);
#pragma unroll
    for (int m = 1; m < 16; m <<= 1) mn = fminf(mn, __shfl_xor(mn, m, 16));
    const float eA = expf(mn - dA), eB = expf(mn - dB);
    float s = eA + eB;
#pragma unroll
    for (int m = 1; m < 16; m <<= 1) s += __shfl_xor(s, m, 16);
    const float w0 = eA / s, w1 = eB / s;
    const int k0 = wI[r][kt], k1 = wI[r][kt + 16];
    float gp = w0 * pm[k0] + w1 * pm[k1];
#pragma unroll
    for (int m = 1; m < 16; m <<= 1) gp += __shfl_xor(gp, m, 16);
    const size_t row = (size_t)(row0 + r);
    w_out[row * KSEL + kt] = w0;      w_out[row * KSEL + kt + 16] = w1;
    itop_out[row * KSEL + kt] = k0;   itop_out[row * KSEL + kt + 16] = k1;
    if (kt == 0) gain_out[row] = 1.f + 0.02f * gp;
  }
}

// ---------------------------------------------------------------------------
// K4a: p = x@Wp.T + bp via MFMA. (unchanged)
// ---------------------------------------------------------------------------
__global__ __launch_bounds__(512) void k4a_pgemm(
    const float* __restrict__ x, const unsigned short* __restrict__ Wphi,
    const unsigned short* __restrict__ Wplo, const float* __restrict__ bp,
    float* __restrict__ p)
{
  const int t = threadIdx.x;
  const int w = t >> 6, lane = t & 63;
  const int colid = lane & 15, kgrp = lane >> 4;
  const int wm = w >> 2, wn = w & 3;
  const int row0 = blockIdx.x * 32;
  const int arow = row0 + wm * 16 + colid;

  f32x4 acc0 = {0.f, 0.f, 0.f, 0.f};
  f32x4 acc1 = {0.f, 0.f, 0.f, 0.f};
  f32x4 acc2 = {0.f, 0.f, 0.f, 0.f};
  f32x4 acc3 = {0.f, 0.f, 0.f, 0.f};

  for (int kc = 0; kc < 24; kc++) {
    const int kb = kc * 32 + kgrp * 8;
    float xv[8];
    *(float4*)&xv[0] = *(const float4*)&x[(size_t)arow * INDIM + kb];
    *(float4*)&xv[4] = *(const float4*)&x[(size_t)arow * INDIM + kb + 4];
    short8_t ah, al;
#pragma unroll
    for (int i = 0; i < 8; i++) {
      const unsigned short h = bf16rn(xv[i]);
      const float hf = __uint_as_float(((unsigned)h) << 16);
      ah[i] = (short)h;
      al[i] = (short)bf16rn(xv[i] - hf);
    }
#pragma unroll
    for (int ct = 0; ct < 4; ct++) {
      const int col = wn * 64 + ct * 16 + colid;
      const short8_t bh = *(const short8_t*)&Wphi[(size_t)col * INDIM + kb];
      const short8_t bl = *(const short8_t*)&Wplo[(size_t)col * INDIM + kb];
      f32x4* pa = (ct == 0) ? &acc0 : (ct == 1) ? &acc1 : (ct == 2) ? &acc2 : &acc3;
      *pa = __builtin_amdgcn_mfma_f32_16x16x32_bf16(ah, bh, *pa, 0, 0, 0);
      *pa = __builtin_amdgcn_mfma_f32_16x16x32_bf16(al, bh, *pa, 0, 0, 0);
      *pa = __builtin_amdgcn_mfma_f32_16x16x32_bf16(ah, bl, *pa, 0, 0, 0);
    }
  }
#pragma unroll
  for (int ct = 0; ct < 4; ct++) {
    const int col = wn * 64 + ct * 16 + colid;
    const float b = bp[col];
    const f32x4 a = (ct == 0) ? acc0 : (ct == 1) ? acc1 : (ct == 2) ? acc2 : acc3;
#pragma unroll
    for (int reg = 0; reg < 4; reg++) {
      const int row = row0 + wm * 16 + kgrp * 4 + reg;
      p[(size_t)row * HN + col] = a[reg] + b;
    }
  }
}

// ---------------------------------------------------------------------------
// K4b: Kf = FFT(e^{i 2pi sigmoid(p)}) * e^{i ek}. (unchanged)
// ---------------------------------------------------------------------------
__global__ __launch_bounds__(256) void k4b_fft(
    const float* __restrict__ p, const float* __restrict__ ek,
    float* __restrict__ kf_re, float* __restrict__ kf_im)
{
  __shared__ float2 c[16][273];
  __shared__ float twc[HN], tws[HN];
  const int t = threadIdx.x;
  const int row0 = blockIdx.x * 16;
  {
    const float a = (float)t * (TWO_PI_F / 256.f);
    twc[t] = cosf(a); tws[t] = sinf(a);
  }
  {
    const int hb = __brev((unsigned)t) >> 24;
    const int hbi = hb + (hb >> 5);
#pragma unroll
    for (int i = 0; i < 16; i++) {
      const float pv = p[(size_t)(row0 + i) * HN + t];
      const float sg = 1.f / (1.f + expf(-pv));
      float sn, cs;
      __sincosf(TWO_PI_F * sg, &sn, &cs);
      c[i][hbi] = make_float2(cs, sn);
    }
  }
  __syncthreads();
  const int r = t >> 4, t16 = t & 15;
  for (int s = 0; s < 8; s++) {
    const int half = 1 << s;
#pragma unroll
    for (int pp = 0; pp < 8; pp++) {
      const int bi = t16 + 16 * pp;
      const int jj = bi & (half - 1);
      const int base = (bi >> s) << (s + 1);
      const int i0 = base + jj, i1 = i0 + half;
      const int tw = jj << (7 - s);
      const float wr = twc[tw], wi = -tws[tw];
      const int p0 = i0 + (i0 >> 5), p1 = i1 + (i1 >> 5);
      const float2 A = c[r][p0];
      const float2 B = c[r][p1];
      const float tr = wr * B.x - wi * B.y, ti = wr * B.y + wi * B.x;
      c[r][p0] = make_float2(A.x + tr, A.y + ti);
      c[r][p1] = make_float2(A.x - tr, A.y - ti);
    }
    __syncthreads();
  }
  {
    float esn, ecs;
    __sincosf(ek[t], &esn, &ecs);
    const int ti = t + (t >> 5);
#pragma unroll
    for (int i = 0; i < 16; i++) {
      const float2 v = c[i][ti];
      const size_t o = (size_t)(row0 + i) * HN + t;
      kf_re[o] = v.x * ecs - v.y * esn;
      kf_im[o] = v.x * esn + v.y * ecs;
    }
  }
}

// ---------------------------------------------------------------------------
// K5 v2: gather + Y = conj(Kf)*Hmix, then triplet = rb + (Y . G)/256. (unchanged)
// ---------------------------------------------------------------------------
__global__ __launch_bounds__(256) void k5_holo(
    const float* __restrict__ holo_re, const float* __restrict__ holo_im,
    const float* __restrict__ kf_re, const float* __restrict__ kf_im,
    const float* __restrict__ w_ws, const int* __restrict__ itop_ws,
    const float* __restrict__ Grp, const float* __restrict__ Gip,
    const float* __restrict__ rb, float* __restrict__ triplet)
{
  __shared__ __align__(16) float ysr[8][260];
  __shared__ __align__(16) float ysi[8][260];
  __shared__ float red[4][8][128];
  __shared__ float wsm[8][KSEL];
  __shared__ int   ism[8][KSEL];
  const int t = threadIdx.x;
  const int w = t >> 6, lane = t & 63;
  const int row0 = blockIdx.x * 8;

  {
    const int rr = t >> 5, k2 = t & 31;
    wsm[rr][k2] = w_ws[(size_t)(row0 + rr) * KSEL + k2];
    ism[rr][k2] = itop_ws[(size_t)(row0 + rr) * KSEL + k2];
  }
  __syncthreads();

#pragma unroll
  for (int pass = 0; pass < 2; pass++) {
    const int row = w + 4 * pass;
    float4 hr4 = {0.f, 0.f, 0.f, 0.f};
    float4 hi4 = {0.f, 0.f, 0.f, 0.f};
#pragma unroll 8
    for (int k2 = 0; k2 < KSEL; k2++) {
      const int m = ism[row][k2];
      const float wk = wsm[row][k2];
      const float4 re4 = *(const float4*)&holo_re[(size_t)m * HN + lane * 4];
      const float4 im4 = *(const float4*)&holo_im[(size_t)m * HN + lane * 4];
      hr4.x = fmaf(wk, re4.x, hr4.x); hr4.y = fmaf(wk, re4.y, hr4.y);
      hr4.z = fmaf(wk, re4.z, hr4.z); hr4.w = fmaf(wk, re4.w, hr4.w);
      hi4.x = fmaf(wk, im4.x, hi4.x); hi4.y = fmaf(wk, im4.y, hi4.y);
      hi4.z = fmaf(wk, im4.z, hi4.z); hi4.w = fmaf(wk, im4.w, hi4.w);
    }
    const size_t o = (size_t)(row0 + row) * HN + lane * 4;
    const float4 kr4 = *(const float4*)&kf_re[o];
    const float4 ki4 = *(const float4*)&kf_im[o];
    float4 yr4, yi4;
    yr4.x = kr4.x * hr4.x + ki4.x * hi4.x;  yi4.x = kr4.x * hi4.x - ki4.x * hr4.x;
    yr4.y = kr4.y * hr4.y + ki4.y * hi4.y;  yi4.y = kr4.y * hi4.y - ki4.y * hr4.y;
    yr4.z = kr4.z * hr4.z + ki4.z * hi4.z;  yi4.z = kr4.z * hi4.z - ki4.z * hr4.z;
    yr4.w = kr4.w * hr4.w + ki4.w * hi4.w;  yi4.w = kr4.w * hi4.w - ki4.w * hr4.w;
    *(float4*)&ysr[row][lane * 4] = yr4;
    *(float4*)&ysi[row][lane * 4] = yi4;
  }
  __syncthreads();

  float acc[8][2];
#pragma unroll
  for (int rr = 0; rr < 8; rr++) { acc[rr][0] = 0.f; acc[rr][1] = 0.f; }
#pragma unroll 4
  for (int i = 0; i < 16; i++) {
    const int h4 = w * 16 + i;
    const float4 gra = *(const float4*)&Grp[((size_t)h4 * 128 + lane) * 4];
    const float4 gia = *(const float4*)&Gip[((size_t)h4 * 128 + lane) * 4];
    const float4 grb = *(const float4*)&Grp[((size_t)h4 * 128 + 64 + lane) * 4];
    const float4 gib = *(const float4*)&Gip[((size_t)h4 * 128 + 64 + lane) * 4];
#pragma unroll
    for (int rr = 0; rr < 8; rr++) {
      const float4 yr4 = *(const float4*)&ysr[rr][h4 * 4];
      const float4 yi4 = *(const float4*)&ysi[rr][h4 * 4];
      acc[rr][0] = fmaf(yr4.x, gra.x, fmaf(yr4.y, gra.y, fmaf(yr4.z, gra.z, fmaf(yr4.w, gra.w, acc[rr][0]))));
      acc[rr][0] = fmaf(yi4.x, gia.x, fmaf(yi4.y, gia.y, fmaf(yi4.z, gia.z, fmaf(yi4.w, gia.w, acc[rr][0]))));
      acc[rr][1] = fmaf(yr4.x, grb.x, fmaf(yr4.y, grb.y, fmaf(yr4.z, grb.z, fmaf(yr4.w, grb.w, acc[rr][1]))));
      acc[rr][1] = fmaf(yi4.x, gib.x, fmaf(yi4.y, gib.y, fmaf(yi4.z, gib.z, fmaf(yi4.w, gib.w, acc[rr][1]))));
    }
  }
#pragma unroll
  for (int rr = 0; rr < 8; rr++) {
    red[w][rr][lane] = acc[rr][0];
    red[w][rr][64 + lane] = acc[rr][1];
  }
  __syncthreads();

  for (int idx = t; idx < 8 * 128; idx += 256) {
    const int rr = idx >> 7, o = idx & 127;
    if (o < TD) {
      const float s = red[0][rr][o] + red[1][rr][o] + red[2][rr][o] + red[3][rr][o];
      triplet[(size_t)(row0 + rr) * TD + o] = rb[o] + s * (1.f / 256.f);
    }
  }
}

// ---------------------------------------------------------------------------
// K6 v2 (MFMA): out = gelu(LN(triplet@W_out.T + b_out)) * gain.
// Safe under the output LN amplification: split error in y6 ~1e-7, post-LN
// ~3e-5 << threshold. (Selection is untouched — w/itop/gain from k3.)
// ---------------------------------------------------------------------------
__global__ __launch_bounds__(256) void k6_mfma(
    const float* __restrict__ triplet, const unsigned short* __restrict__ Wohi,
    const unsigned short* __restrict__ Wolo, const float* __restrict__ bo,
    const float* __restrict__ go, const float* __restrict__ bbo,
    const float* __restrict__ gain, float* __restrict__ out)
{
  __shared__ float ys[16][772];
  const int t = threadIdx.x;
  const int w = t >> 6, lane = t & 63;
  const int colid = lane & 15, kgrp = lane >> 4;
  const int row0 = blockIdx.x * 16;
  const int arow = row0 + colid;

  f32x4 acc[12];
#pragma unroll
  for (int ct = 0; ct < 12; ct++) acc[ct] = (f32x4){0.f, 0.f, 0.f, 0.f};

#pragma unroll
  for (int kc = 0; kc < 3; kc++) {
    const int kb = kc * 32 + kgrp * 8;
    float xv[8];
    if (kb < TD) {
      *(float4*)&xv[0] = *(const float4*)&triplet[(size_t)arow * TD + kb];
      *(float4*)&xv[4] = *(const float4*)&triplet[(size_t)arow * TD + kb + 4];
    } else {
#pragma unroll
      for (int i = 0; i < 8; i++) xv[i] = 0.f;
    }
    short8_t ah, al;
#pragma unroll
    for (int i = 0; i < 8; i++) {
      const unsigned short h = bf16rn(xv[i]);
      const float hf = __uint_as_float(((unsigned)h) << 16);
      ah[i] = (short)h; al[i] = (short)bf16rn(xv[i] - hf);
    }
#pragma unroll
    for (int ct = 0; ct < 12; ct++) {
      const int col = w * 192 + ct * 16 + colid;
      const short8_t bh = *(const short8_t*)&Wohi[(size_t)col * 96 + kb];
      const short8_t bl = *(const short8_t*)&Wolo[(size_t)col * 96 + kb];
      acc[ct] = __builtin_amdgcn_mfma_f32_16x16x32_bf16(ah, bh, acc[ct], 0, 0, 0);
      acc[ct] = __builtin_amdgcn_mfma_f32_16x16x32_bf16(al, bh, acc[ct], 0, 0, 0);
      acc[ct] = __builtin_amdgcn_mfma_f32_16x16x32_bf16(ah, bl, acc[ct], 0, 0, 0);
    }
  }
#pragma unroll
  for (int ct = 0; ct < 12; ct++) {
    const int col = w * 192 + ct * 16 + colid;
    const float b = bo[col];
#pragma unroll
    for (int reg = 0; reg < 4; reg++)
      ys[kgrp * 4 + reg][col] = acc[ct][reg] + b;
  }
  __syncthreads();

  const int r = t >> 4, kt = t & 15;
  float s = 0.f, sq = 0.f;
  for (int u = 0; u < 48; u++) {
    const float v = ys[r][kt + 16 * u];
    s += v; sq = fmaf(v, v, sq);
  }
#pragma unroll
  for (int m = 1; m < 16; m <<= 1) { s += __shfl_xor(s, m, 16); sq += __shfl_xor(sq, m, 16); }
  const float mean = s * (1.f / 768.f);
  const float var  = sq * (1.f / 768.f) - mean * mean;
  const float rstd = rsqrtf(var + 1e-5f);
  const float gn = gain[row0 + r];
  for (int u = 0; u < 48; u++) {
    const int e = kt + 16 * u;
    const float v = (ys[r][e] - mean) * rstd * go[e] + bbo[e];
    out[(size_t)(row0 + r) * INDIM + e] = gelu_exact(v) * gn;
  }
}

// ---------------------------------------------------------------------------
extern "C" void kernel_launch(void* const* d_in, const int* in_sizes, int n_in,
                              void* d_out, int out_size, void* d_ws, size_t ws_size,
                              hipStream_t stream)
{
  (void)in_sizes; (void)n_in; (void)out_size; (void)ws_size;
  const float* x     = (const float*)d_in[0];
  const float* Wi    = (const float*)d_in[1];
  const float* bi    = (const float*)d_in[2];
  const float* gi    = (const float*)d_in[3];
  const float* bbi   = (const float*)d_in[4];
  const float* ricci = (const float*)d_in[5];
  const float* fw    = (const float*)d_in[6];
  const float* keys  = (const float*)d_in[7];
  const float* Wp    = (const float*)d_in[8];
  const float* bp    = (const float*)d_in[9];
  const float* ek    = (const float*)d_in[10];
  const float* hre   = (const float*)d_in[11];
  const float* him   = (const float*)d_in[12];
  const float* RW    = (const float*)d_in[13];
  const float* rb    = (const float*)d_in[14];
  const float* Wo    = (const float*)d_in[15];
  const float* bo    = (const float*)d_in[16];
  const float* go    = (const float*)d_in[17];
  const float* bbo   = (const float*)d_in[18];
  const float* qp    = (const float*)d_in[19];
  float* out = (float*)d_out;

  char* ws = (char*)d_ws;
  float* qvec    = (float*)(ws + 0);
  float* qnorm   = (float*)(ws + 786432);
  float* kn      = (float*)(ws + 819200);
  float* pm      = (float*)(ws + 851968);
  float* gain    = (float*)(ws + 884736);
  float* w_ws    = (float*)(ws + 917504);
  int*   itop    = (int*)  (ws + 1966080);
  float* triplet = (float*)(ws + 3014656);
  float* kf_re   = (float*)(ws + 5373952);
  float* kf_im   = (float*)(ws + 13762560);
  unsigned short* khi = (unsigned short*)(ws + 22151168);  // 524288
  unsigned short* klo = (unsigned short*)(ws + 22675456);  // 524288
  float* kmx     = (float*)(ws + 23199744);                // 1 KB
  float* Grp     = (float*)(ws + 23200768);                // 131072
  float* Gip     = (float*)(ws + 23331840);                // 131072
  unsigned short* Wphi = (unsigned short*)(ws + 23462912); // 393216
  unsigned short* Wplo = (unsigned short*)(ws + 23856128); // 393216
  float* pbuf    = (float*)(ws + 24249344);                // 8388608
  unsigned short* Wohi = (unsigned short*)(ws + 32637952); // 147456
  unsigned short* Wolo = (unsigned short*)(ws + 32785408); // 147456 -> ends 32932864

  k0_gprep<<<dim3(8), dim3(256), 0, stream>>>(RW, Grp, Gip);
  kw_split<<<dim3(192), dim3(256), 0, stream>>>(Wp, Wphi, Wplo);
  kwo_split<<<dim3(288), dim3(256), 0, stream>>>(Wo, Wohi, Wolo);
  k2_prep<<<dim3(MKEYS / 256), dim3(256), 0, stream>>>(keys, qp, kn, pm, khi, klo, kmx);
  k1_encode<<<dim3(NROWS / 16), dim3(256), 0, stream>>>(x, Wi, bi, gi, bbi, ricci, qvec, qnorm);
  k4a_pgemm<<<dim3(NROWS / 32), dim3(512), 0, stream>>>(x, Wphi, Wplo, bp, pbuf);
  k4b_fft<<<dim3(NROWS / 16), dim3(256), 0, stream>>>(pbuf, ek, kf_re, kf_im);
  k3_topk<<<dim3(NROWS / 32), dim3(1024), 0, stream>>>(qvec, qnorm, keys, kn, khi, klo, kmx, fw, pm, w_ws, itop, gain);
  k5_holo<<<dim3(NROWS / 8), dim3(256), 0, stream>>>(hre, him, kf_re, kf_im, w_ws, itop, Grp, Gip, rb, triplet);
  k6_mfma<<<dim3(NROWS / 16), dim3(256), 0, stream>>>(triplet, Wohi, Wolo, bo, go, bbo, gain, out);
}